// Round 11
// baseline (612.925 us; speedup 1.0000x reference)
//
#include <hip/hip_runtime.h>
#include <hip/hip_bf16.h>
#include <math.h>

#define N_NODES 100000
#define N_EDGES 800000

typedef float f32x4 __attribute__((ext_vector_type(4)));
typedef short bf16x8 __attribute__((ext_vector_type(8)));

__device__ inline unsigned short bf16_of(float f) {
    union { __hip_bfloat16 b; unsigned short u; } cv;
    cv.b = __float2bfloat16(f);
    return cv.u;
}
__device__ inline float f32_of(unsigned short u) {
    union { __hip_bfloat16 b; unsigned short u; } cv;
    cv.u = u;
    return __bfloat162float(cv.b);
}

// ================= degree / CSR build =================
__global__ void k_zero_deg(int* __restrict__ deg) {
    int i = blockIdx.x * blockDim.x + threadIdx.x;
    if (i < N_NODES) deg[i] = 0;
}

__global__ void k_hist(const int* __restrict__ edst, int* __restrict__ deg) {
    int e = blockIdx.x * blockDim.x + threadIdx.x;
    if (e < N_EDGES) atomicAdd(&deg[edst[e]], 1);
}

// exclusive scan + dinv fused, 256/block
__global__ void k_scan1(const int* __restrict__ deg, int* __restrict__ off,
                        int* __restrict__ bsum, float* __restrict__ dinv, int n) {
    __shared__ int s[256];
    int t = threadIdx.x;
    int i = blockIdx.x * 256 + t;
    int v = (i < n) ? deg[i] : 0;
    if (i < n) dinv[i] = rsqrtf((float)(v + 1));   // +1 self-loop
    s[t] = v;
    __syncthreads();
    #pragma unroll
    for (int d = 1; d < 256; d <<= 1) {
        int x = (t >= d) ? s[t - d] : 0;
        __syncthreads();
        s[t] += x;
        __syncthreads();
    }
    if (i < n) off[i] = s[t] - v;            // exclusive within block
    if (t == 255) bsum[blockIdx.x] = s[255];
}

__global__ void k_scan2(int* __restrict__ bsum, int nb) {
    __shared__ int s[512];
    int t = threadIdx.x;
    int v = (t < nb) ? bsum[t] : 0;
    s[t] = v;
    __syncthreads();
    #pragma unroll
    for (int d = 1; d < 512; d <<= 1) {
        int x = (t >= d) ? s[t - d] : 0;
        __syncthreads();
        s[t] += x;
        __syncthreads();
    }
    if (t < nb) bsum[t] = s[t] - v;          // exclusive block offsets
}

__global__ void k_scan3(int* __restrict__ off, const int* __restrict__ bsum,
                        int* __restrict__ cur, int n) {
    int i = blockIdx.x * blockDim.x + threadIdx.x;
    if (i < n) {
        int o = off[i] + bsum[i >> 8];
        off[i] = o;
        cur[i] = o;
    }
    if (i == n) off[n] = N_EDGES;
}

// scatter edges into dst-grouped CSR: ONE packed int4 {src, dst, w_bits, eid} per edge
__global__ void k_scatter(const int* __restrict__ esrc, const int* __restrict__ edst,
                          const float* __restrict__ dinv,
                          int* __restrict__ cur, int4* __restrict__ csr_pack) {
    int e = blockIdx.x * blockDim.x + threadIdx.x;
    if (e >= N_EDGES) return;
    int s = esrc[e], d = edst[e];
    int pos = atomicAdd(&cur[d], 1);
    float w = dinv[s] * dinv[d];
    csr_pack[pos] = make_int4(s, d, __float_as_int(w), e);
}

// ================= bf16 hi/lo split of 5 x (128x128) W into MFMA fragment layout ====
// frag index for (k, c): lane = ((k>>3)&3)*16 + (c&15), elem = k&7, tile = (k>>5)*8 + (c>>4)
struct SplitArgs {
    const float* W[5];
    unsigned short* Wh[5];
    unsigned short* Wl[5];
};
__global__ void k_split_all(SplitArgs a) {
    int which = blockIdx.x >> 6;                    // 64 blocks per matrix
    int idx = (blockIdx.x & 63) * 256 + threadIdx.x;
    if (idx >= 128 * 128) return;
    int k = idx >> 7, c = idx & 127;
    float wv = a.W[which][idx];
    unsigned short h = bf16_of(wv);
    unsigned short lo = bf16_of(wv - f32_of(h));
    int fi = (((k >> 5) * 8 + (c >> 4)) * 64 + (((k >> 3) & 3) * 16 + (c & 15))) * 8 + (k & 7);
    a.Wh[which][fi] = h;
    a.Wl[which][fi] = lo;
}

// ================= MFMA node GEMM: out = (relu?)in[N,128] @ W[128,128] =================
// bf16x3 error-compensated. 512 threads = 8 waves x 16 rows; R row-tiles per block.
// In-place safe (out==in): each wave reads only its own 16 rows (regs) before writing them.
template<bool RELU>
__global__ __launch_bounds__(512) void k_gemm_mfma(
    const float* __restrict__ in,
    const unsigned short* __restrict__ Whf, const unsigned short* __restrict__ Wlf,
    float* __restrict__ outp, int nrows, int rtiles)
{
    __shared__ __align__(16) unsigned short sWh[16384];
    __shared__ __align__(16) unsigned short sWl[16384];
    const int t = threadIdx.x;

    #pragma unroll
    for (int i = 0; i < 4; ++i) {
        ((float4*)sWh)[t + 512 * i] = ((const float4*)Whf)[t + 512 * i];
        ((float4*)sWl)[t + 512 * i] = ((const float4*)Wlf)[t + 512 * i];
    }
    __syncthreads();

    const int w = t >> 6, l = t & 63;
    const int lr = l & 15, lk = l >> 4;

    for (int r = 0; r < rtiles; ++r) {
        const int row0 = (blockIdx.x * rtiles + r) * 128;
        int arow = row0 + w * 16 + lr;
        if (arow >= nrows) arow = nrows - 1;     // clamp (stores are guarded)
        const float* inrow = in + (size_t)arow * 128 + lk * 8;

        bf16x8 ah[4], al[4];
        #pragma unroll
        for (int ks = 0; ks < 4; ++ks) {
            float4 p0 = *(const float4*)(inrow + ks * 32);
            float4 p1 = *(const float4*)(inrow + ks * 32 + 4);
            float z[8] = {p0.x, p0.y, p0.z, p0.w, p1.x, p1.y, p1.z, p1.w};
            #pragma unroll
            for (int e = 0; e < 8; ++e) {
                float zv = RELU ? fmaxf(z[e], 0.f) : z[e];
                unsigned short hu = bf16_of(zv);
                ah[ks][e] = (short)hu;
                al[ks][e] = (short)bf16_of(zv - f32_of(hu));
            }
        }

        f32x4 acc[8];
        #pragma unroll
        for (int ct = 0; ct < 8; ++ct) { f32x4 zz = {0.f, 0.f, 0.f, 0.f}; acc[ct] = zz; }

        #pragma unroll
        for (int ct = 0; ct < 8; ++ct) {
            #pragma unroll
            for (int ks = 0; ks < 4; ++ks) {
                const bf16x8 bh = *(const bf16x8*)(sWh + ((ks * 8 + ct) * 64 + l) * 8);
                const bf16x8 bl = *(const bf16x8*)(sWl + ((ks * 8 + ct) * 64 + l) * 8);
                acc[ct] = __builtin_amdgcn_mfma_f32_16x16x32_bf16(ah[ks], bh, acc[ct], 0, 0, 0);
                acc[ct] = __builtin_amdgcn_mfma_f32_16x16x32_bf16(ah[ks], bl, acc[ct], 0, 0, 0);
                acc[ct] = __builtin_amdgcn_mfma_f32_16x16x32_bf16(al[ks], bh, acc[ct], 0, 0, 0);
            }
        }

        // D: row m = lk*4 + j (within wave tile), col = ct*16 + lr
        #pragma unroll
        for (int j = 0; j < 4; ++j) {
            int m = row0 + w * 16 + lk * 4 + j;
            if (m < nrows) {
                #pragma unroll
                for (int ct = 0; ct < 8; ++ct)
                    outp[(size_t)m * 128 + ct * 16 + lr] = acc[ct][j];
            }
        }
    }
}

// ================= MFMA P/Q GEMM: P = relu(in)@Wm1_top, Q = relu(in)@Wm1_bot ==========
// Two passes sharing one LDS region; in-place safe for Q==in (input re-read each pass).
__global__ __launch_bounds__(512) void k_gemm_pq_mfma(
    const float* __restrict__ in,
    const unsigned short* __restrict__ Wh0, const unsigned short* __restrict__ Wl0,
    const unsigned short* __restrict__ Wh1, const unsigned short* __restrict__ Wl1,
    float* __restrict__ P, float* __restrict__ Q, int nrows, int rtiles)
{
    __shared__ __align__(16) unsigned short sWh[16384];
    __shared__ __align__(16) unsigned short sWl[16384];
    const int t = threadIdx.x;
    const int w = t >> 6, l = t & 63;
    const int lr = l & 15, lk = l >> 4;

    #pragma unroll
    for (int half = 0; half < 2; ++half) {
        const unsigned short* Whf = half ? Wh1 : Wh0;
        const unsigned short* Wlf = half ? Wl1 : Wl0;
        float* outp = half ? Q : P;
        if (half) __syncthreads();     // all waves done reading previous sW
        #pragma unroll
        for (int i = 0; i < 4; ++i) {
            ((float4*)sWh)[t + 512 * i] = ((const float4*)Whf)[t + 512 * i];
            ((float4*)sWl)[t + 512 * i] = ((const float4*)Wlf)[t + 512 * i];
        }
        __syncthreads();

        for (int r = 0; r < rtiles; ++r) {
            const int row0 = (blockIdx.x * rtiles + r) * 128;
            int arow = row0 + w * 16 + lr;
            if (arow >= nrows) arow = nrows - 1;
            const float* inrow = in + (size_t)arow * 128 + lk * 8;

            bf16x8 ah[4], al[4];
            #pragma unroll
            for (int ks = 0; ks < 4; ++ks) {
                float4 p0 = *(const float4*)(inrow + ks * 32);
                float4 p1 = *(const float4*)(inrow + ks * 32 + 4);
                float z[8] = {p0.x, p0.y, p0.z, p0.w, p1.x, p1.y, p1.z, p1.w};
                #pragma unroll
                for (int e = 0; e < 8; ++e) {
                    float zv = fmaxf(z[e], 0.f);
                    unsigned short hu = bf16_of(zv);
                    ah[ks][e] = (short)hu;
                    al[ks][e] = (short)bf16_of(zv - f32_of(hu));
                }
            }

            f32x4 acc[8];
            #pragma unroll
            for (int ct = 0; ct < 8; ++ct) { f32x4 zz = {0.f, 0.f, 0.f, 0.f}; acc[ct] = zz; }

            #pragma unroll
            for (int ct = 0; ct < 8; ++ct) {
                #pragma unroll
                for (int ks = 0; ks < 4; ++ks) {
                    const bf16x8 bh = *(const bf16x8*)(sWh + ((ks * 8 + ct) * 64 + l) * 8);
                    const bf16x8 bl = *(const bf16x8*)(sWl + ((ks * 8 + ct) * 64 + l) * 8);
                    acc[ct] = __builtin_amdgcn_mfma_f32_16x16x32_bf16(ah[ks], bh, acc[ct], 0, 0, 0);
                    acc[ct] = __builtin_amdgcn_mfma_f32_16x16x32_bf16(ah[ks], bl, acc[ct], 0, 0, 0);
                    acc[ct] = __builtin_amdgcn_mfma_f32_16x16x32_bf16(al[ks], bh, acc[ct], 0, 0, 0);
                }
            }

            #pragma unroll
            for (int j = 0; j < 4; ++j) {
                int m = row0 + w * 16 + lk * 4 + j;
                if (m < nrows) {
                    #pragma unroll
                    for (int ct = 0; ct < 8; ++ct)
                        outp[(size_t)m * 128 + ct * 16 + lr] = acc[ct][j];
                }
            }
        }
    }
}

// ================= CSR aggregation (packed records) =================
// out[i][:] = bias[:] + dinv[i]^2 * raw[i][:] + sum_{e: dst=i} w_e * raw[src_e][:]
__global__ __launch_bounds__(256) void k_agg_csr(
    const float* __restrict__ raw, const float* __restrict__ dinv,
    const int* __restrict__ off, const int4* __restrict__ csr_pack,
    const float* __restrict__ bias, float* __restrict__ outp)
{
    const int t = threadIdx.x;
    const int node = blockIdx.x * 8 + (t >> 5);
    const int lane = t & 31;
    if (node >= N_NODES) return;

    float di = dinv[node];
    float w0 = di * di;
    float4 acc = ((const float4*)bias)[lane];
    float4 v = ((const float4*)raw)[(size_t)node * 32 + lane];
    acc.x += w0 * v.x; acc.y += w0 * v.y; acc.z += w0 * v.z; acc.w += w0 * v.w;

    const int beg = off[node], end = off[node + 1];
    for (int base = beg; base < end; base += 32) {
        int cnt = end - base;
        if (cnt > 32) cnt = 32;
        int sj = 0;
        float wj = 0.f;
        if (lane < cnt) {
            int4 p = csr_pack[base + lane];
            sj = p.x;
            wj = __int_as_float(p.z);
        }
        for (int j = 0; j < cnt; ++j) {
            int s = __shfl(sj, j, 32);
            float w = __shfl(wj, j, 32);
            float4 u = ((const float4*)raw)[(size_t)s * 32 + lane];
            acc.x += w * u.x; acc.y += w * u.y; acc.z += w * u.z; acc.w += w * u.w;
        }
    }
    ((float4*)outp)[(size_t)node * 32 + lane] = acc;
}

// ================= fused edge MLP (MFMA bf16x3, CSR order, Wl from L2) =================
// Wh staged in LDS (32 KB); Wl read per-fragment from global (L2-resident 32 KB)
// -> LDS ~34 KB -> 4 blocks/CU = 32 waves/CU for latency hiding on the P gathers.
__global__ __launch_bounds__(512) void k_edge_mlp_mfma(
    const int4* __restrict__ csr_pack,
    const float* __restrict__ P, const float* __restrict__ Q,
    const float* __restrict__ bm1,
    const unsigned short* __restrict__ Whf, const unsigned short* __restrict__ Wlf,
    const float* __restrict__ bm2,
    const float* __restrict__ Wm3, const float* __restrict__ bm3,
    float* __restrict__ outp)
{
    __shared__ __align__(16) unsigned short sWh[16384];   // 32 KB, fragment layout
    __shared__ int sIdx[3][128];

    const int t = threadIdx.x;
    const int e0 = blockIdx.x * 128;

    // linear stage of Wh fragments (2048 float4, 512 threads)
    #pragma unroll
    for (int i = 0; i < 4; ++i)
        ((float4*)sWh)[t + 512 * i] = ((const float4*)Whf)[t + 512 * i];
    if (t < 128) {
        int4 p = csr_pack[e0 + t];
        sIdx[0][t] = p.x;
        sIdx[1][t] = p.y;
        sIdx[2][t] = p.w;
    }
    __syncthreads();

    const int w = t >> 6;          // wave id 0..7: rows w*16 .. w*16+15
    const int l = t & 63;
    const int lr = l & 15;         // A row within tile / D col
    const int lk = l >> 4;         // k-block
    const int row = w * 16 + lr;
    const int s = sIdx[0][row], d = sIdx[1][row];
    const float* prow = P + (size_t)s * 128 + lk * 8;
    const float* qrow = Q + (size_t)d * 128 + lk * 8;
    const float* brow = bm1 + lk * 8;

    // build A-fragments (z1 hi/lo) in registers
    bf16x8 ah[4], al[4];
    #pragma unroll
    for (int ks = 0; ks < 4; ++ks) {
        float4 p0 = *(const float4*)(prow + ks * 32);
        float4 p1 = *(const float4*)(prow + ks * 32 + 4);
        float4 q0 = *(const float4*)(qrow + ks * 32);
        float4 q1 = *(const float4*)(qrow + ks * 32 + 4);
        float4 b0 = *(const float4*)(brow + ks * 32);
        float4 b1 = *(const float4*)(brow + ks * 32 + 4);
        float z[8];
        z[0] = fmaxf(p0.x + q0.x + b0.x, 0.f);
        z[1] = fmaxf(p0.y + q0.y + b0.y, 0.f);
        z[2] = fmaxf(p0.z + q0.z + b0.z, 0.f);
        z[3] = fmaxf(p0.w + q0.w + b0.w, 0.f);
        z[4] = fmaxf(p1.x + q1.x + b1.x, 0.f);
        z[5] = fmaxf(p1.y + q1.y + b1.y, 0.f);
        z[6] = fmaxf(p1.z + q1.z + b1.z, 0.f);
        z[7] = fmaxf(p1.w + q1.w + b1.w, 0.f);
        #pragma unroll
        for (int e = 0; e < 8; ++e) {
            unsigned short hu = bf16_of(z[e]);
            ah[ks][e] = (short)hu;
            al[ks][e] = (short)bf16_of(z[e] - f32_of(hu));
        }
    }

    // C = z1 @ Wm2 + bm2  (8 col tiles of 16); bl fragments stream from L2
    f32x4 acc[8];
    #pragma unroll
    for (int ct = 0; ct < 8; ++ct) {
        float bv = bm2[ct * 16 + lr];
        f32x4 a = {bv, bv, bv, bv};
        acc[ct] = a;
    }

    #pragma unroll
    for (int ct = 0; ct < 8; ++ct) {
        #pragma unroll
        for (int ks = 0; ks < 4; ++ks) {
            const bf16x8 bh = *(const bf16x8*)(sWh + ((ks * 8 + ct) * 64 + l) * 8);
            const bf16x8 bl = *(const bf16x8*)(Wlf + ((size_t)(ks * 8 + ct) * 64 + l) * 8);
            acc[ct] = __builtin_amdgcn_mfma_f32_16x16x32_bf16(ah[ks], bh, acc[ct], 0, 0, 0);
            acc[ct] = __builtin_amdgcn_mfma_f32_16x16x32_bf16(ah[ks], bl, acc[ct], 0, 0, 0);
            acc[ct] = __builtin_amdgcn_mfma_f32_16x16x32_bf16(al[ks], bh, acc[ct], 0, 0, 0);
        }
    }

    // out = sigmoid(relu(C) @ Wm3 + bm3); D layout: col = lr, row = lk*4 + reg
    float w3v[8];
    #pragma unroll
    for (int ct = 0; ct < 8; ++ct) w3v[ct] = Wm3[ct * 16 + lr];
    float b3 = bm3[0];
    #pragma unroll
    for (int j = 0; j < 4; ++j) {
        float pj = 0.f;
        #pragma unroll
        for (int ct = 0; ct < 8; ++ct) pj += fmaxf(acc[ct][j], 0.f) * w3v[ct];
        pj += __shfl_xor(pj, 1);
        pj += __shfl_xor(pj, 2);
        pj += __shfl_xor(pj, 4);
        pj += __shfl_xor(pj, 8);
        if (lr == 0)
            outp[sIdx[2][w * 16 + lk * 4 + j]] = 1.f / (1.f + expf(-(pj + b3)));
    }
}

// ================= launch =================
extern "C" void kernel_launch(void* const* d_in, const int* in_sizes, int n_in,
                              void* d_out, int out_size, void* d_ws, size_t ws_size,
                              hipStream_t stream) {
    const float* x   = (const float*)d_in[0];
    const int*   ei  = (const int*)d_in[1];
    const float* W1  = (const float*)d_in[2];
    const float* b1  = (const float*)d_in[3];
    const float* W2  = (const float*)d_in[4];
    const float* b2  = (const float*)d_in[5];
    const float* Wm1 = (const float*)d_in[6];
    const float* bm1 = (const float*)d_in[7];
    const float* Wm2 = (const float*)d_in[8];
    const float* bm2 = (const float*)d_in[9];
    const float* Wm3 = (const float*)d_in[10];
    const float* bm3 = (const float*)d_in[11];
    const int* esrc = ei;
    const int* edst = ei + N_EDGES;
    float* outp = (float*)d_out;

    // workspace layout
    float* ws = (float*)d_ws;
    float* dinv = ws;                                   // 100096 floats
    float* A = ws + 100096;                             // N*128
    float* B = A + (size_t)N_NODES * 128;               // N*128
    int* deg     = (int*)(B + (size_t)N_NODES * 128);   // N
    int* off     = deg + N_NODES;                       // N+1
    int* cur     = off + N_NODES + 1;                   // N
    int* bsum    = cur + N_NODES;                       // 512
    // align to 16 B for int4
    size_t ioff = (size_t)(bsum + 512 - (int*)d_ws);
    ioff = (ioff + 3) & ~(size_t)3;
    int4* csr_pack = (int4*)((int*)d_ws + ioff);        // E int4
    unsigned short* frag = (unsigned short*)(csr_pack + N_EDGES);
    unsigned short* W1h   = frag;                 unsigned short* W1l   = frag + 16384;
    unsigned short* W2h   = frag + 2 * 16384;     unsigned short* W2l   = frag + 3 * 16384;
    unsigned short* Wm1ah = frag + 4 * 16384;     unsigned short* Wm1al = frag + 5 * 16384;
    unsigned short* Wm1bh = frag + 6 * 16384;     unsigned short* Wm1bl = frag + 7 * 16384;
    unsigned short* Wm2h  = frag + 8 * 16384;     unsigned short* Wm2l  = frag + 9 * 16384;

    const int nb = (N_NODES + 255) / 256;               // 391 scan blocks

    // ---- CSR build + W splits ----
    k_zero_deg<<<nb, 256, 0, stream>>>(deg);
    k_hist<<<(N_EDGES + 255) / 256, 256, 0, stream>>>(edst, deg);
    k_scan1<<<nb, 256, 0, stream>>>(deg, off, bsum, dinv, N_NODES);
    k_scan2<<<1, 512, 0, stream>>>(bsum, nb);
    k_scan3<<<(N_NODES + 256) / 256, 256, 0, stream>>>(off, bsum, cur, N_NODES);
    k_scatter<<<(N_EDGES + 255) / 256, 256, 0, stream>>>(esrc, edst, dinv, cur, csr_pack);

    SplitArgs sa;
    sa.W[0] = W1;  sa.Wh[0] = W1h;   sa.Wl[0] = W1l;
    sa.W[1] = W2;  sa.Wh[1] = W2h;   sa.Wl[1] = W2l;
    sa.W[2] = Wm1; sa.Wh[2] = Wm1ah; sa.Wl[2] = Wm1al;
    sa.W[3] = Wm1 + 128 * 128; sa.Wh[3] = Wm1bh; sa.Wl[3] = Wm1bl;
    sa.W[4] = Wm2; sa.Wh[4] = Wm2h;  sa.Wl[4] = Wm2l;
    k_split_all<<<5 * 64, 256, 0, stream>>>(sa);

    const int RT = 2;                                   // row tiles per block (128 rows each)
    const int gemm_blocks = (N_NODES + 128 * RT - 1) / (128 * RT);   // 391
    const int agg_blocks = (N_NODES + 7) / 8;

    // ---- layer 1: A = x @ W1 ; B = b1 + norm-agg(A) ----
    k_gemm_mfma<false><<<gemm_blocks, 512, 0, stream>>>(x, W1h, W1l, A, N_NODES, RT);
    k_agg_csr<<<agg_blocks, 256, 0, stream>>>(A, dinv, off, csr_pack, b1, B);

    // ---- layer 2: A = relu(B) @ W2 ; B = b2 + norm-agg(A) ----
    k_gemm_mfma<true><<<gemm_blocks, 512, 0, stream>>>(B, W2h, W2l, A, N_NODES, RT);
    k_agg_csr<<<agg_blocks, 256, 0, stream>>>(A, dinv, off, csr_pack, b2, B);

    // ---- edge-MLP layer-1 decomposition: P -> A, Q -> B (in-place safe) ----
    k_gemm_pq_mfma<<<gemm_blocks, 512, 0, stream>>>(B, Wm1ah, Wm1al, Wm1bh, Wm1bl,
                                                    A, B, N_NODES, RT);

    // ---- fused edge MLP on MFMA, CSR order, 4 blocks/CU ----
    k_edge_mlp_mfma<<<N_EDGES / 128, 512, 0, stream>>>(csr_pack, A, B, bm1,
                                                       Wm2h, Wm2l, bm2, Wm3, bm3, outp);
}

// Round 12
// 536.856 us; speedup vs baseline: 1.1417x; 1.1417x over previous
//
#include <hip/hip_runtime.h>
#include <hip/hip_bf16.h>
#include <math.h>

#define N_NODES 100000
#define N_EDGES 800000

typedef float f32x4 __attribute__((ext_vector_type(4)));
typedef short bf16x8 __attribute__((ext_vector_type(8)));

__device__ inline unsigned short bf16_of(float f) {
    union { __hip_bfloat16 b; unsigned short u; } cv;
    cv.b = __float2bfloat16(f);
    return cv.u;
}
__device__ inline float f32_of(unsigned short u) {
    union { __hip_bfloat16 b; unsigned short u; } cv;
    cv.u = u;
    return __bfloat162float(cv.b);
}

// ================= degree / CSR build =================
__global__ void k_zero_deg(int* __restrict__ deg) {
    int i = blockIdx.x * blockDim.x + threadIdx.x;
    if (i < N_NODES) deg[i] = 0;
}

__global__ void k_hist(const int* __restrict__ edst, int* __restrict__ deg) {
    int e = blockIdx.x * blockDim.x + threadIdx.x;
    if (e < N_EDGES) atomicAdd(&deg[edst[e]], 1);
}

// exclusive scan + dinv fused, 256/block
__global__ void k_scan1(const int* __restrict__ deg, int* __restrict__ off,
                        int* __restrict__ bsum, float* __restrict__ dinv, int n) {
    __shared__ int s[256];
    int t = threadIdx.x;
    int i = blockIdx.x * 256 + t;
    int v = (i < n) ? deg[i] : 0;
    if (i < n) dinv[i] = rsqrtf((float)(v + 1));   // +1 self-loop
    s[t] = v;
    __syncthreads();
    #pragma unroll
    for (int d = 1; d < 256; d <<= 1) {
        int x = (t >= d) ? s[t - d] : 0;
        __syncthreads();
        s[t] += x;
        __syncthreads();
    }
    if (i < n) off[i] = s[t] - v;            // exclusive within block
    if (t == 255) bsum[blockIdx.x] = s[255];
}

__global__ void k_scan2(int* __restrict__ bsum, int nb) {
    __shared__ int s[512];
    int t = threadIdx.x;
    int v = (t < nb) ? bsum[t] : 0;
    s[t] = v;
    __syncthreads();
    #pragma unroll
    for (int d = 1; d < 512; d <<= 1) {
        int x = (t >= d) ? s[t - d] : 0;
        __syncthreads();
        s[t] += x;
        __syncthreads();
    }
    if (t < nb) bsum[t] = s[t] - v;          // exclusive block offsets
}

__global__ void k_scan3(int* __restrict__ off, const int* __restrict__ bsum,
                        int* __restrict__ cur, int n) {
    int i = blockIdx.x * blockDim.x + threadIdx.x;
    if (i < n) {
        int o = off[i] + bsum[i >> 8];
        off[i] = o;
        cur[i] = o;
    }
    if (i == n) off[n] = N_EDGES;
}

// scatter edges into dst-grouped CSR: ONE packed int4 {src, dst, w_bits, eid} per edge
__global__ void k_scatter(const int* __restrict__ esrc, const int* __restrict__ edst,
                          const float* __restrict__ dinv,
                          int* __restrict__ cur, int4* __restrict__ csr_pack) {
    int e = blockIdx.x * blockDim.x + threadIdx.x;
    if (e >= N_EDGES) return;
    int s = esrc[e], d = edst[e];
    int pos = atomicAdd(&cur[d], 1);
    float w = dinv[s] * dinv[d];
    csr_pack[pos] = make_int4(s, d, __float_as_int(w), e);
}

// ================= bf16 hi/lo split of 5 x (128x128) W into MFMA fragment layout ====
// frag index for (k, c): lane = ((k>>3)&3)*16 + (c&15), elem = k&7, tile = (k>>5)*8 + (c>>4)
struct SplitArgs {
    const float* W[5];
    unsigned short* Wh[5];
    unsigned short* Wl[5];
};
__global__ void k_split_all(SplitArgs a) {
    int which = blockIdx.x >> 6;                    // 64 blocks per matrix
    int idx = (blockIdx.x & 63) * 256 + threadIdx.x;
    if (idx >= 128 * 128) return;
    int k = idx >> 7, c = idx & 127;
    float wv = a.W[which][idx];
    unsigned short h = bf16_of(wv);
    unsigned short lo = bf16_of(wv - f32_of(h));
    int fi = (((k >> 5) * 8 + (c >> 4)) * 64 + (((k >> 3) & 3) * 16 + (c & 15))) * 8 + (k & 7);
    a.Wh[which][fi] = h;
    a.Wl[which][fi] = lo;
}

// ================= MFMA node GEMM: out = (relu?)in[N,128] @ W[128,128] =================
// bf16x3 error-compensated. 512 threads = 8 waves x 16 rows; R row-tiles per block.
// In-place safe (out==in): each wave reads only its own 16 rows (regs) before writing them.
template<bool RELU>
__global__ __launch_bounds__(512) void k_gemm_mfma(
    const float* __restrict__ in,
    const unsigned short* __restrict__ Whf, const unsigned short* __restrict__ Wlf,
    float* __restrict__ outp, int nrows, int rtiles)
{
    __shared__ __align__(16) unsigned short sWh[16384];
    __shared__ __align__(16) unsigned short sWl[16384];
    const int t = threadIdx.x;

    #pragma unroll
    for (int i = 0; i < 4; ++i) {
        ((float4*)sWh)[t + 512 * i] = ((const float4*)Whf)[t + 512 * i];
        ((float4*)sWl)[t + 512 * i] = ((const float4*)Wlf)[t + 512 * i];
    }
    __syncthreads();

    const int w = t >> 6, l = t & 63;
    const int lr = l & 15, lk = l >> 4;

    for (int r = 0; r < rtiles; ++r) {
        const int row0 = (blockIdx.x * rtiles + r) * 128;
        int arow = row0 + w * 16 + lr;
        if (arow >= nrows) arow = nrows - 1;     // clamp (stores are guarded)
        const float* inrow = in + (size_t)arow * 128 + lk * 8;

        bf16x8 ah[4], al[4];
        #pragma unroll
        for (int ks = 0; ks < 4; ++ks) {
            float4 p0 = *(const float4*)(inrow + ks * 32);
            float4 p1 = *(const float4*)(inrow + ks * 32 + 4);
            float z[8] = {p0.x, p0.y, p0.z, p0.w, p1.x, p1.y, p1.z, p1.w};
            #pragma unroll
            for (int e = 0; e < 8; ++e) {
                float zv = RELU ? fmaxf(z[e], 0.f) : z[e];
                unsigned short hu = bf16_of(zv);
                ah[ks][e] = (short)hu;
                al[ks][e] = (short)bf16_of(zv - f32_of(hu));
            }
        }

        f32x4 acc[8];
        #pragma unroll
        for (int ct = 0; ct < 8; ++ct) { f32x4 zz = {0.f, 0.f, 0.f, 0.f}; acc[ct] = zz; }

        #pragma unroll
        for (int ct = 0; ct < 8; ++ct) {
            #pragma unroll
            for (int ks = 0; ks < 4; ++ks) {
                const bf16x8 bh = *(const bf16x8*)(sWh + ((ks * 8 + ct) * 64 + l) * 8);
                const bf16x8 bl = *(const bf16x8*)(sWl + ((ks * 8 + ct) * 64 + l) * 8);
                acc[ct] = __builtin_amdgcn_mfma_f32_16x16x32_bf16(ah[ks], bh, acc[ct], 0, 0, 0);
                acc[ct] = __builtin_amdgcn_mfma_f32_16x16x32_bf16(ah[ks], bl, acc[ct], 0, 0, 0);
                acc[ct] = __builtin_amdgcn_mfma_f32_16x16x32_bf16(al[ks], bh, acc[ct], 0, 0, 0);
            }
        }

        // D: row m = lk*4 + j (within wave tile), col = ct*16 + lr
        #pragma unroll
        for (int j = 0; j < 4; ++j) {
            int m = row0 + w * 16 + lk * 4 + j;
            if (m < nrows) {
                #pragma unroll
                for (int ct = 0; ct < 8; ++ct)
                    outp[(size_t)m * 128 + ct * 16 + lr] = acc[ct][j];
            }
        }
    }
}

// ================= MFMA P/Q GEMM: P = relu(in)@Wm1_top, Q = relu(in)@Wm1_bot ==========
// Two passes sharing one LDS region; in-place safe for Q==in (input re-read each pass).
__global__ __launch_bounds__(512) void k_gemm_pq_mfma(
    const float* __restrict__ in,
    const unsigned short* __restrict__ Wh0, const unsigned short* __restrict__ Wl0,
    const unsigned short* __restrict__ Wh1, const unsigned short* __restrict__ Wl1,
    float* __restrict__ P, float* __restrict__ Q, int nrows, int rtiles)
{
    __shared__ __align__(16) unsigned short sWh[16384];
    __shared__ __align__(16) unsigned short sWl[16384];
    const int t = threadIdx.x;
    const int w = t >> 6, l = t & 63;
    const int lr = l & 15, lk = l >> 4;

    #pragma unroll
    for (int half = 0; half < 2; ++half) {
        const unsigned short* Whf = half ? Wh1 : Wh0;
        const unsigned short* Wlf = half ? Wl1 : Wl0;
        float* outp = half ? Q : P;
        if (half) __syncthreads();     // all waves done reading previous sW
        #pragma unroll
        for (int i = 0; i < 4; ++i) {
            ((float4*)sWh)[t + 512 * i] = ((const float4*)Whf)[t + 512 * i];
            ((float4*)sWl)[t + 512 * i] = ((const float4*)Wlf)[t + 512 * i];
        }
        __syncthreads();

        for (int r = 0; r < rtiles; ++r) {
            const int row0 = (blockIdx.x * rtiles + r) * 128;
            int arow = row0 + w * 16 + lr;
            if (arow >= nrows) arow = nrows - 1;
            const float* inrow = in + (size_t)arow * 128 + lk * 8;

            bf16x8 ah[4], al[4];
            #pragma unroll
            for (int ks = 0; ks < 4; ++ks) {
                float4 p0 = *(const float4*)(inrow + ks * 32);
                float4 p1 = *(const float4*)(inrow + ks * 32 + 4);
                float z[8] = {p0.x, p0.y, p0.z, p0.w, p1.x, p1.y, p1.z, p1.w};
                #pragma unroll
                for (int e = 0; e < 8; ++e) {
                    float zv = fmaxf(z[e], 0.f);
                    unsigned short hu = bf16_of(zv);
                    ah[ks][e] = (short)hu;
                    al[ks][e] = (short)bf16_of(zv - f32_of(hu));
                }
            }

            f32x4 acc[8];
            #pragma unroll
            for (int ct = 0; ct < 8; ++ct) { f32x4 zz = {0.f, 0.f, 0.f, 0.f}; acc[ct] = zz; }

            #pragma unroll
            for (int ct = 0; ct < 8; ++ct) {
                #pragma unroll
                for (int ks = 0; ks < 4; ++ks) {
                    const bf16x8 bh = *(const bf16x8*)(sWh + ((ks * 8 + ct) * 64 + l) * 8);
                    const bf16x8 bl = *(const bf16x8*)(sWl + ((ks * 8 + ct) * 64 + l) * 8);
                    acc[ct] = __builtin_amdgcn_mfma_f32_16x16x32_bf16(ah[ks], bh, acc[ct], 0, 0, 0);
                    acc[ct] = __builtin_amdgcn_mfma_f32_16x16x32_bf16(ah[ks], bl, acc[ct], 0, 0, 0);
                    acc[ct] = __builtin_amdgcn_mfma_f32_16x16x32_bf16(al[ks], bh, acc[ct], 0, 0, 0);
                }
            }

            #pragma unroll
            for (int j = 0; j < 4; ++j) {
                int m = row0 + w * 16 + lk * 4 + j;
                if (m < nrows) {
                    #pragma unroll
                    for (int ct = 0; ct < 8; ++ct)
                        outp[(size_t)m * 128 + ct * 16 + lr] = acc[ct][j];
                }
            }
        }
    }
}

// ================= CSR aggregation (packed records) =================
// out[i][:] = bias[:] + dinv[i]^2 * raw[i][:] + sum_{e: dst=i} w_e * raw[src_e][:]
__global__ __launch_bounds__(256) void k_agg_csr(
    const float* __restrict__ raw, const float* __restrict__ dinv,
    const int* __restrict__ off, const int4* __restrict__ csr_pack,
    const float* __restrict__ bias, float* __restrict__ outp)
{
    const int t = threadIdx.x;
    const int node = blockIdx.x * 8 + (t >> 5);
    const int lane = t & 31;
    if (node >= N_NODES) return;

    float di = dinv[node];
    float w0 = di * di;
    float4 acc = ((const float4*)bias)[lane];
    float4 v = ((const float4*)raw)[(size_t)node * 32 + lane];
    acc.x += w0 * v.x; acc.y += w0 * v.y; acc.z += w0 * v.z; acc.w += w0 * v.w;

    const int beg = off[node], end = off[node + 1];
    for (int base = beg; base < end; base += 32) {
        int cnt = end - base;
        if (cnt > 32) cnt = 32;
        int sj = 0;
        float wj = 0.f;
        if (lane < cnt) {
            int4 p = csr_pack[base + lane];
            sj = p.x;
            wj = __int_as_float(p.z);
        }
        for (int j = 0; j < cnt; ++j) {
            int s = __shfl(sj, j, 32);
            float w = __shfl(wj, j, 32);
            float4 u = ((const float4*)raw)[(size_t)s * 32 + lane];
            acc.x += w * u.x; acc.y += w * u.y; acc.z += w * u.z; acc.w += w * u.w;
        }
    }
    ((float4*)outp)[(size_t)node * 32 + lane] = acc;
}

// ================= fused edge MLP (MFMA bf16x3, CSR dst-grouped order) =================
// Round-10 proven shape: Wh+Wl both in LDS (66 KB), 512 threads / 128 edges.
// csr_pack read directly per-lane (no sIdx LDS round-trip) so P/Q gathers issue early.
__global__ __launch_bounds__(512) void k_edge_mlp_mfma(
    const int4* __restrict__ csr_pack,
    const float* __restrict__ P, const float* __restrict__ Q,
    const float* __restrict__ bm1,
    const unsigned short* __restrict__ Whf, const unsigned short* __restrict__ Wlf,
    const float* __restrict__ bm2,
    const float* __restrict__ Wm3, const float* __restrict__ bm3,
    float* __restrict__ outp)
{
    __shared__ __align__(16) unsigned short sWh[16384];   // 32 KB, fragment layout
    __shared__ __align__(16) unsigned short sWl[16384];   // 32 KB

    const int t = threadIdx.x;
    const int e0 = blockIdx.x * 128;
    const int w = t >> 6;          // wave id 0..7: rows w*16 .. w*16+15
    const int l = t & 63;
    const int lr = l & 15;         // A row within tile / D col
    const int lk = l >> 4;         // k-block
    const int row = w * 16 + lr;

    // per-lane packed record read (4 lanes share a record; L2-resident)
    const int4 pk = csr_pack[e0 + row];
    const int s = pk.x, d = pk.y;
    const float* prow = P + (size_t)s * 128 + lk * 8;
    const float* qrow = Q + (size_t)d * 128 + lk * 8;
    const float* brow = bm1 + lk * 8;

    // build A-fragments (z1 hi/lo) in registers — loads overlap W staging below
    bf16x8 ah[4], al[4];
    #pragma unroll
    for (int ks = 0; ks < 4; ++ks) {
        float4 p0 = *(const float4*)(prow + ks * 32);
        float4 p1 = *(const float4*)(prow + ks * 32 + 4);
        float4 q0 = *(const float4*)(qrow + ks * 32);
        float4 q1 = *(const float4*)(qrow + ks * 32 + 4);
        float4 b0 = *(const float4*)(brow + ks * 32);
        float4 b1 = *(const float4*)(brow + ks * 32 + 4);
        float z[8];
        z[0] = fmaxf(p0.x + q0.x + b0.x, 0.f);
        z[1] = fmaxf(p0.y + q0.y + b0.y, 0.f);
        z[2] = fmaxf(p0.z + q0.z + b0.z, 0.f);
        z[3] = fmaxf(p0.w + q0.w + b0.w, 0.f);
        z[4] = fmaxf(p1.x + q1.x + b1.x, 0.f);
        z[5] = fmaxf(p1.y + q1.y + b1.y, 0.f);
        z[6] = fmaxf(p1.z + q1.z + b1.z, 0.f);
        z[7] = fmaxf(p1.w + q1.w + b1.w, 0.f);
        #pragma unroll
        for (int e = 0; e < 8; ++e) {
            unsigned short hu = bf16_of(z[e]);
            ah[ks][e] = (short)hu;
            al[ks][e] = (short)bf16_of(z[e] - f32_of(hu));
        }
    }

    // stage W fragments to LDS (2048 float4 each, 512 threads)
    #pragma unroll
    for (int i = 0; i < 4; ++i) {
        ((float4*)sWh)[t + 512 * i] = ((const float4*)Whf)[t + 512 * i];
        ((float4*)sWl)[t + 512 * i] = ((const float4*)Wlf)[t + 512 * i];
    }
    __syncthreads();

    // C = z1 @ Wm2 + bm2  (8 col tiles of 16)
    f32x4 acc[8];
    #pragma unroll
    for (int ct = 0; ct < 8; ++ct) {
        float bv = bm2[ct * 16 + lr];
        f32x4 a = {bv, bv, bv, bv};
        acc[ct] = a;
    }

    #pragma unroll
    for (int ct = 0; ct < 8; ++ct) {
        #pragma unroll
        for (int ks = 0; ks < 4; ++ks) {
            const bf16x8 bh = *(const bf16x8*)(sWh + ((ks * 8 + ct) * 64 + l) * 8);
            const bf16x8 bl = *(const bf16x8*)(sWl + ((ks * 8 + ct) * 64 + l) * 8);
            acc[ct] = __builtin_amdgcn_mfma_f32_16x16x32_bf16(ah[ks], bh, acc[ct], 0, 0, 0);
            acc[ct] = __builtin_amdgcn_mfma_f32_16x16x32_bf16(ah[ks], bl, acc[ct], 0, 0, 0);
            acc[ct] = __builtin_amdgcn_mfma_f32_16x16x32_bf16(al[ks], bh, acc[ct], 0, 0, 0);
        }
    }

    // out = sigmoid(relu(C) @ Wm3 + bm3); D layout: col = lr, row = lk*4 + reg
    float w3v[8];
    #pragma unroll
    for (int ct = 0; ct < 8; ++ct) w3v[ct] = Wm3[ct * 16 + lr];
    float b3 = bm3[0];
    #pragma unroll
    for (int j = 0; j < 4; ++j) {
        float pj = 0.f;
        #pragma unroll
        for (int ct = 0; ct < 8; ++ct) pj += fmaxf(acc[ct][j], 0.f) * w3v[ct];
        pj += __shfl_xor(pj, 1);
        pj += __shfl_xor(pj, 2);
        pj += __shfl_xor(pj, 4);
        pj += __shfl_xor(pj, 8);
        if (lr == 0) {
            int eid = csr_pack[e0 + w * 16 + lk * 4 + j].w;   // L2-hot re-read
            outp[eid] = 1.f / (1.f + expf(-(pj + b3)));
        }
    }
}

// ================= launch =================
extern "C" void kernel_launch(void* const* d_in, const int* in_sizes, int n_in,
                              void* d_out, int out_size, void* d_ws, size_t ws_size,
                              hipStream_t stream) {
    const float* x   = (const float*)d_in[0];
    const int*   ei  = (const int*)d_in[1];
    const float* W1  = (const float*)d_in[2];
    const float* b1  = (const float*)d_in[3];
    const float* W2  = (const float*)d_in[4];
    const float* b2  = (const float*)d_in[5];
    const float* Wm1 = (const float*)d_in[6];
    const float* bm1 = (const float*)d_in[7];
    const float* Wm2 = (const float*)d_in[8];
    const float* bm2 = (const float*)d_in[9];
    const float* Wm3 = (const float*)d_in[10];
    const float* bm3 = (const float*)d_in[11];
    const int* esrc = ei;
    const int* edst = ei + N_EDGES;
    float* outp = (float*)d_out;

    // workspace layout
    float* ws = (float*)d_ws;
    float* dinv = ws;                                   // 100096 floats
    float* A = ws + 100096;                             // N*128
    float* B = A + (size_t)N_NODES * 128;               // N*128
    int* deg     = (int*)(B + (size_t)N_NODES * 128);   // N
    int* off     = deg + N_NODES;                       // N+1
    int* cur     = off + N_NODES + 1;                   // N
    int* bsum    = cur + N_NODES;                       // 512
    // align to 16 B for int4
    size_t ioff = (size_t)(bsum + 512 - (int*)d_ws);
    ioff = (ioff + 3) & ~(size_t)3;
    int4* csr_pack = (int4*)((int*)d_ws + ioff);        // E int4
    unsigned short* frag = (unsigned short*)(csr_pack + N_EDGES);
    unsigned short* W1h   = frag;                 unsigned short* W1l   = frag + 16384;
    unsigned short* W2h   = frag + 2 * 16384;     unsigned short* W2l   = frag + 3 * 16384;
    unsigned short* Wm1ah = frag + 4 * 16384;     unsigned short* Wm1al = frag + 5 * 16384;
    unsigned short* Wm1bh = frag + 6 * 16384;     unsigned short* Wm1bl = frag + 7 * 16384;
    unsigned short* Wm2h  = frag + 8 * 16384;     unsigned short* Wm2l  = frag + 9 * 16384;

    const int nb = (N_NODES + 255) / 256;               // 391 scan blocks

    // ---- CSR build + W splits ----
    k_zero_deg<<<nb, 256, 0, stream>>>(deg);
    k_hist<<<(N_EDGES + 255) / 256, 256, 0, stream>>>(edst, deg);
    k_scan1<<<nb, 256, 0, stream>>>(deg, off, bsum, dinv, N_NODES);
    k_scan2<<<1, 512, 0, stream>>>(bsum, nb);
    k_scan3<<<(N_NODES + 256) / 256, 256, 0, stream>>>(off, bsum, cur, N_NODES);
    k_scatter<<<(N_EDGES + 255) / 256, 256, 0, stream>>>(esrc, edst, dinv, cur, csr_pack);

    SplitArgs sa;
    sa.W[0] = W1;  sa.Wh[0] = W1h;   sa.Wl[0] = W1l;
    sa.W[1] = W2;  sa.Wh[1] = W2h;   sa.Wl[1] = W2l;
    sa.W[2] = Wm1; sa.Wh[2] = Wm1ah; sa.Wl[2] = Wm1al;
    sa.W[3] = Wm1 + 128 * 128; sa.Wh[3] = Wm1bh; sa.Wl[3] = Wm1bl;
    sa.W[4] = Wm2; sa.Wh[4] = Wm2h;  sa.Wl[4] = Wm2l;
    k_split_all<<<5 * 64, 256, 0, stream>>>(sa);

    const int RT = 4;                                   // row tiles per block (128 rows each)
    const int gemm_blocks = (N_NODES + 128 * RT - 1) / (128 * RT);   // 196
    const int agg_blocks = (N_NODES + 7) / 8;

    // ---- layer 1: A = x @ W1 ; B = b1 + norm-agg(A) ----
    k_gemm_mfma<false><<<gemm_blocks, 512, 0, stream>>>(x, W1h, W1l, A, N_NODES, RT);
    k_agg_csr<<<agg_blocks, 256, 0, stream>>>(A, dinv, off, csr_pack, b1, B);

    // ---- layer 2: A = relu(B) @ W2 ; B = b2 + norm-agg(A) ----
    k_gemm_mfma<true><<<gemm_blocks, 512, 0, stream>>>(B, W2h, W2l, A, N_NODES, RT);
    k_agg_csr<<<agg_blocks, 256, 0, stream>>>(A, dinv, off, csr_pack, b2, B);

    // ---- edge-MLP layer-1 decomposition: P -> A, Q -> B (in-place safe) ----
    k_gemm_pq_mfma<<<gemm_blocks, 512, 0, stream>>>(B, Wm1ah, Wm1al, Wm1bh, Wm1bl,
                                                    A, B, N_NODES, RT);

    // ---- fused edge MLP on MFMA, CSR order ----
    k_edge_mlp_mfma<<<N_EDGES / 128, 512, 0, stream>>>(csr_pack, A, B, bm1,
                                                       Wm2h, Wm2l, bm2, Wm3, bm3, outp);
}

// Round 13
// 503.823 us; speedup vs baseline: 1.2165x; 1.0656x over previous
//
#include <hip/hip_runtime.h>
#include <hip/hip_bf16.h>
#include <math.h>

#define N_NODES 100000
#define N_EDGES 800000

typedef float f32x4 __attribute__((ext_vector_type(4)));
typedef short bf16x8 __attribute__((ext_vector_type(8)));

__device__ inline unsigned short bf16_of(float f) {
    union { __hip_bfloat16 b; unsigned short u; } cv;
    cv.b = __float2bfloat16(f);
    return cv.u;
}
__device__ inline float f32_of(unsigned short u) {
    union { __hip_bfloat16 b; unsigned short u; } cv;
    cv.u = u;
    return __bfloat162float(cv.b);
}

// ================= degree / CSR build =================
__global__ void k_zero_deg(int* __restrict__ deg) {
    int i = blockIdx.x * blockDim.x + threadIdx.x;
    if (i < N_NODES) deg[i] = 0;
}

__global__ void k_hist(const int* __restrict__ edst, int* __restrict__ deg) {
    int e = blockIdx.x * blockDim.x + threadIdx.x;
    if (e < N_EDGES) atomicAdd(&deg[edst[e]], 1);
}

// exclusive scan + dinv fused, 256/block
__global__ void k_scan1(const int* __restrict__ deg, int* __restrict__ off,
                        int* __restrict__ bsum, float* __restrict__ dinv, int n) {
    __shared__ int s[256];
    int t = threadIdx.x;
    int i = blockIdx.x * 256 + t;
    int v = (i < n) ? deg[i] : 0;
    if (i < n) dinv[i] = rsqrtf((float)(v + 1));   // +1 self-loop
    s[t] = v;
    __syncthreads();
    #pragma unroll
    for (int d = 1; d < 256; d <<= 1) {
        int x = (t >= d) ? s[t - d] : 0;
        __syncthreads();
        s[t] += x;
        __syncthreads();
    }
    if (i < n) off[i] = s[t] - v;            // exclusive within block
    if (t == 255) bsum[blockIdx.x] = s[255];
}

__global__ void k_scan2(int* __restrict__ bsum, int nb) {
    __shared__ int s[512];
    int t = threadIdx.x;
    int v = (t < nb) ? bsum[t] : 0;
    s[t] = v;
    __syncthreads();
    #pragma unroll
    for (int d = 1; d < 512; d <<= 1) {
        int x = (t >= d) ? s[t - d] : 0;
        __syncthreads();
        s[t] += x;
        __syncthreads();
    }
    if (t < nb) bsum[t] = s[t] - v;          // exclusive block offsets
}

__global__ void k_scan3(int* __restrict__ off, const int* __restrict__ bsum,
                        int* __restrict__ cur, int n) {
    int i = blockIdx.x * blockDim.x + threadIdx.x;
    if (i < n) {
        int o = off[i] + bsum[i >> 8];
        off[i] = o;
        cur[i] = o;
    }
    if (i == n) off[n] = N_EDGES;
}

// scatter edges into dst-grouped CSR: ONE packed int4 {src, dst, w_bits, eid} per edge
__global__ void k_scatter(const int* __restrict__ esrc, const int* __restrict__ edst,
                          const float* __restrict__ dinv,
                          int* __restrict__ cur, int4* __restrict__ csr_pack) {
    int e = blockIdx.x * blockDim.x + threadIdx.x;
    if (e >= N_EDGES) return;
    int s = esrc[e], d = edst[e];
    int pos = atomicAdd(&cur[d], 1);
    float w = dinv[s] * dinv[d];
    csr_pack[pos] = make_int4(s, d, __float_as_int(w), e);
}

// ================= bf16 hi/lo split of 5 x (128x128) W into MFMA fragment layout ====
// frag index for (k, c): lane = ((k>>3)&3)*16 + (c&15), elem = k&7, tile = (k>>5)*8 + (c>>4)
struct SplitArgs {
    const float* W[5];
    unsigned short* Wh[5];
    unsigned short* Wl[5];
};
__global__ void k_split_all(SplitArgs a) {
    int which = blockIdx.x >> 6;                    // 64 blocks per matrix
    int idx = (blockIdx.x & 63) * 256 + threadIdx.x;
    if (idx >= 128 * 128) return;
    int k = idx >> 7, c = idx & 127;
    float wv = a.W[which][idx];
    unsigned short h = bf16_of(wv);
    unsigned short lo = bf16_of(wv - f32_of(h));
    int fi = (((k >> 5) * 8 + (c >> 4)) * 64 + (((k >> 3) & 3) * 16 + (c & 15))) * 8 + (k & 7);
    a.Wh[which][fi] = h;
    a.Wl[which][fi] = lo;
}

// ================= MFMA node GEMM: out = (relu?)in[N,128] @ W[128,128] =================
// bf16x3 error-compensated. 512 threads = 8 waves x 16 rows; R row-tiles per block.
// In-place safe (out==in): each wave reads only its own 16 rows (regs) before writing them.
template<bool RELU>
__global__ __launch_bounds__(512) void k_gemm_mfma(
    const float* __restrict__ in,
    const unsigned short* __restrict__ Whf, const unsigned short* __restrict__ Wlf,
    float* __restrict__ outp, int nrows, int rtiles)
{
    __shared__ __align__(16) unsigned short sWh[16384];
    __shared__ __align__(16) unsigned short sWl[16384];
    const int t = threadIdx.x;

    #pragma unroll
    for (int i = 0; i < 4; ++i) {
        ((float4*)sWh)[t + 512 * i] = ((const float4*)Whf)[t + 512 * i];
        ((float4*)sWl)[t + 512 * i] = ((const float4*)Wlf)[t + 512 * i];
    }
    __syncthreads();

    const int w = t >> 6, l = t & 63;
    const int lr = l & 15, lk = l >> 4;

    for (int r = 0; r < rtiles; ++r) {
        const int row0 = (blockIdx.x * rtiles + r) * 128;
        int arow = row0 + w * 16 + lr;
        if (arow >= nrows) arow = nrows - 1;     // clamp (stores are guarded)
        const float* inrow = in + (size_t)arow * 128 + lk * 8;

        bf16x8 ah[4], al[4];
        #pragma unroll
        for (int ks = 0; ks < 4; ++ks) {
            float4 p0 = *(const float4*)(inrow + ks * 32);
            float4 p1 = *(const float4*)(inrow + ks * 32 + 4);
            float z[8] = {p0.x, p0.y, p0.z, p0.w, p1.x, p1.y, p1.z, p1.w};
            #pragma unroll
            for (int e = 0; e < 8; ++e) {
                float zv = RELU ? fmaxf(z[e], 0.f) : z[e];
                unsigned short hu = bf16_of(zv);
                ah[ks][e] = (short)hu;
                al[ks][e] = (short)bf16_of(zv - f32_of(hu));
            }
        }

        f32x4 acc[8];
        #pragma unroll
        for (int ct = 0; ct < 8; ++ct) { f32x4 zz = {0.f, 0.f, 0.f, 0.f}; acc[ct] = zz; }

        #pragma unroll
        for (int ct = 0; ct < 8; ++ct) {
            #pragma unroll
            for (int ks = 0; ks < 4; ++ks) {
                const bf16x8 bh = *(const bf16x8*)(sWh + ((ks * 8 + ct) * 64 + l) * 8);
                const bf16x8 bl = *(const bf16x8*)(sWl + ((ks * 8 + ct) * 64 + l) * 8);
                acc[ct] = __builtin_amdgcn_mfma_f32_16x16x32_bf16(ah[ks], bh, acc[ct], 0, 0, 0);
                acc[ct] = __builtin_amdgcn_mfma_f32_16x16x32_bf16(ah[ks], bl, acc[ct], 0, 0, 0);
                acc[ct] = __builtin_amdgcn_mfma_f32_16x16x32_bf16(al[ks], bh, acc[ct], 0, 0, 0);
            }
        }

        // D: row m = lk*4 + j (within wave tile), col = ct*16 + lr
        #pragma unroll
        for (int j = 0; j < 4; ++j) {
            int m = row0 + w * 16 + lk * 4 + j;
            if (m < nrows) {
                #pragma unroll
                for (int ct = 0; ct < 8; ++ct)
                    outp[(size_t)m * 128 + ct * 16 + lr] = acc[ct][j];
            }
        }
    }
}

// ================= MFMA P/Q GEMM -> bf16 outputs =================
// P = bf16(relu(in)@Wm1_top), Q = bf16(relu(in)@Wm1_bot). Reads f32 in (B), writes
// ushort P/Q (disjoint storage). Two passes sharing one LDS region.
__global__ __launch_bounds__(512) void k_gemm_pq_mfma(
    const float* __restrict__ in,
    const unsigned short* __restrict__ Wh0, const unsigned short* __restrict__ Wl0,
    const unsigned short* __restrict__ Wh1, const unsigned short* __restrict__ Wl1,
    unsigned short* __restrict__ P, unsigned short* __restrict__ Q, int nrows, int rtiles)
{
    __shared__ __align__(16) unsigned short sWh[16384];
    __shared__ __align__(16) unsigned short sWl[16384];
    const int t = threadIdx.x;
    const int w = t >> 6, l = t & 63;
    const int lr = l & 15, lk = l >> 4;

    #pragma unroll
    for (int half = 0; half < 2; ++half) {
        const unsigned short* Whf = half ? Wh1 : Wh0;
        const unsigned short* Wlf = half ? Wl1 : Wl0;
        unsigned short* outp = half ? Q : P;
        if (half) __syncthreads();     // all waves done reading previous sW
        #pragma unroll
        for (int i = 0; i < 4; ++i) {
            ((float4*)sWh)[t + 512 * i] = ((const float4*)Whf)[t + 512 * i];
            ((float4*)sWl)[t + 512 * i] = ((const float4*)Wlf)[t + 512 * i];
        }
        __syncthreads();

        for (int r = 0; r < rtiles; ++r) {
            const int row0 = (blockIdx.x * rtiles + r) * 128;
            int arow = row0 + w * 16 + lr;
            if (arow >= nrows) arow = nrows - 1;
            const float* inrow = in + (size_t)arow * 128 + lk * 8;

            bf16x8 ah[4], al[4];
            #pragma unroll
            for (int ks = 0; ks < 4; ++ks) {
                float4 p0 = *(const float4*)(inrow + ks * 32);
                float4 p1 = *(const float4*)(inrow + ks * 32 + 4);
                float z[8] = {p0.x, p0.y, p0.z, p0.w, p1.x, p1.y, p1.z, p1.w};
                #pragma unroll
                for (int e = 0; e < 8; ++e) {
                    float zv = fmaxf(z[e], 0.f);
                    unsigned short hu = bf16_of(zv);
                    ah[ks][e] = (short)hu;
                    al[ks][e] = (short)bf16_of(zv - f32_of(hu));
                }
            }

            f32x4 acc[8];
            #pragma unroll
            for (int ct = 0; ct < 8; ++ct) { f32x4 zz = {0.f, 0.f, 0.f, 0.f}; acc[ct] = zz; }

            #pragma unroll
            for (int ct = 0; ct < 8; ++ct) {
                #pragma unroll
                for (int ks = 0; ks < 4; ++ks) {
                    const bf16x8 bh = *(const bf16x8*)(sWh + ((ks * 8 + ct) * 64 + l) * 8);
                    const bf16x8 bl = *(const bf16x8*)(sWl + ((ks * 8 + ct) * 64 + l) * 8);
                    acc[ct] = __builtin_amdgcn_mfma_f32_16x16x32_bf16(ah[ks], bh, acc[ct], 0, 0, 0);
                    acc[ct] = __builtin_amdgcn_mfma_f32_16x16x32_bf16(ah[ks], bl, acc[ct], 0, 0, 0);
                    acc[ct] = __builtin_amdgcn_mfma_f32_16x16x32_bf16(al[ks], bh, acc[ct], 0, 0, 0);
                }
            }

            #pragma unroll
            for (int j = 0; j < 4; ++j) {
                int m = row0 + w * 16 + lk * 4 + j;
                if (m < nrows) {
                    #pragma unroll
                    for (int ct = 0; ct < 8; ++ct)
                        outp[(size_t)m * 128 + ct * 16 + lr] = bf16_of(acc[ct][j]);
                }
            }
        }
    }
}

// ================= CSR aggregation (packed records) =================
// out[i][:] = bias[:] + dinv[i]^2 * raw[i][:] + sum_{e: dst=i} w_e * raw[src_e][:]
__global__ __launch_bounds__(256) void k_agg_csr(
    const float* __restrict__ raw, const float* __restrict__ dinv,
    const int* __restrict__ off, const int4* __restrict__ csr_pack,
    const float* __restrict__ bias, float* __restrict__ outp)
{
    const int t = threadIdx.x;
    const int node = blockIdx.x * 8 + (t >> 5);
    const int lane = t & 31;
    if (node >= N_NODES) return;

    float di = dinv[node];
    float w0 = di * di;
    float4 acc = ((const float4*)bias)[lane];
    float4 v = ((const float4*)raw)[(size_t)node * 32 + lane];
    acc.x += w0 * v.x; acc.y += w0 * v.y; acc.z += w0 * v.z; acc.w += w0 * v.w;

    const int beg = off[node], end = off[node + 1];
    for (int base = beg; base < end; base += 32) {
        int cnt = end - base;
        if (cnt > 32) cnt = 32;
        int sj = 0;
        float wj = 0.f;
        if (lane < cnt) {
            int4 p = csr_pack[base + lane];
            sj = p.x;
            wj = __int_as_float(p.z);
        }
        for (int j = 0; j < cnt; ++j) {
            int s = __shfl(sj, j, 32);
            float w = __shfl(wj, j, 32);
            float4 u = ((const float4*)raw)[(size_t)s * 32 + lane];
            acc.x += w * u.x; acc.y += w * u.y; acc.z += w * u.z; acc.w += w * u.w;
        }
    }
    ((float4*)outp)[(size_t)node * 32 + lane] = acc;
}

// ================= fused edge MLP (MFMA bf16x3, CSR order, bf16 P/Q gathers) ===========
// Round-10 proven structure (sIdx LDS staging, Wh+Wl in LDS); P/Q rows now bf16
// (256 B/row) halving the random-gather bytes.
__global__ __launch_bounds__(512) void k_edge_mlp_mfma(
    const int4* __restrict__ csr_pack,
    const unsigned short* __restrict__ P, const unsigned short* __restrict__ Q,
    const float* __restrict__ bm1,
    const unsigned short* __restrict__ Whf, const unsigned short* __restrict__ Wlf,
    const float* __restrict__ bm2,
    const float* __restrict__ Wm3, const float* __restrict__ bm3,
    float* __restrict__ outp)
{
    __shared__ __align__(16) unsigned short sWh[16384];   // 32 KB, fragment layout
    __shared__ __align__(16) unsigned short sWl[16384];   // 32 KB
    __shared__ int sIdx[3][128];

    const int t = threadIdx.x;
    const int e0 = blockIdx.x * 128;

    // linear stage of W fragments + packed index records
    #pragma unroll
    for (int i = 0; i < 4; ++i) {
        ((float4*)sWh)[t + 512 * i] = ((const float4*)Whf)[t + 512 * i];
        ((float4*)sWl)[t + 512 * i] = ((const float4*)Wlf)[t + 512 * i];
    }
    if (t < 128) {
        int4 p = csr_pack[e0 + t];
        sIdx[0][t] = p.x;
        sIdx[1][t] = p.y;
        sIdx[2][t] = p.w;
    }
    __syncthreads();

    const int w = t >> 6;          // wave id 0..7: rows w*16 .. w*16+15
    const int l = t & 63;
    const int lr = l & 15;         // A row within tile / D col
    const int lk = l >> 4;         // k-block
    const int row = w * 16 + lr;
    const int s = sIdx[0][row], d = sIdx[1][row];
    const unsigned short* prow = P + (size_t)s * 128 + lk * 8;
    const unsigned short* qrow = Q + (size_t)d * 128 + lk * 8;
    const float* brow = bm1 + lk * 8;

    // build A-fragments (z1 hi/lo) in registers from bf16 P/Q
    bf16x8 ah[4], al[4];
    #pragma unroll
    for (int ks = 0; ks < 4; ++ks) {
        bf16x8 pv = *(const bf16x8*)(prow + ks * 32);
        bf16x8 qv = *(const bf16x8*)(qrow + ks * 32);
        float4 b0 = *(const float4*)(brow + ks * 32);
        float4 b1 = *(const float4*)(brow + ks * 32 + 4);
        float bb[8] = {b0.x, b0.y, b0.z, b0.w, b1.x, b1.y, b1.z, b1.w};
        #pragma unroll
        for (int e = 0; e < 8; ++e) {
            float zv = fmaxf(f32_of((unsigned short)pv[e]) +
                             f32_of((unsigned short)qv[e]) + bb[e], 0.f);
            unsigned short hu = bf16_of(zv);
            ah[ks][e] = (short)hu;
            al[ks][e] = (short)bf16_of(zv - f32_of(hu));
        }
    }

    // C = z1 @ Wm2 + bm2  (8 col tiles of 16)
    f32x4 acc[8];
    #pragma unroll
    for (int ct = 0; ct < 8; ++ct) {
        float bv = bm2[ct * 16 + lr];
        f32x4 a = {bv, bv, bv, bv};
        acc[ct] = a;
    }

    #pragma unroll
    for (int ct = 0; ct < 8; ++ct) {
        #pragma unroll
        for (int ks = 0; ks < 4; ++ks) {
            const bf16x8 bh = *(const bf16x8*)(sWh + ((ks * 8 + ct) * 64 + l) * 8);
            const bf16x8 bl = *(const bf16x8*)(sWl + ((ks * 8 + ct) * 64 + l) * 8);
            acc[ct] = __builtin_amdgcn_mfma_f32_16x16x32_bf16(ah[ks], bh, acc[ct], 0, 0, 0);
            acc[ct] = __builtin_amdgcn_mfma_f32_16x16x32_bf16(ah[ks], bl, acc[ct], 0, 0, 0);
            acc[ct] = __builtin_amdgcn_mfma_f32_16x16x32_bf16(al[ks], bh, acc[ct], 0, 0, 0);
        }
    }

    // out = sigmoid(relu(C) @ Wm3 + bm3); D layout: col = lr, row = lk*4 + reg
    float w3v[8];
    #pragma unroll
    for (int ct = 0; ct < 8; ++ct) w3v[ct] = Wm3[ct * 16 + lr];
    float b3 = bm3[0];
    #pragma unroll
    for (int j = 0; j < 4; ++j) {
        float pj = 0.f;
        #pragma unroll
        for (int ct = 0; ct < 8; ++ct) pj += fmaxf(acc[ct][j], 0.f) * w3v[ct];
        pj += __shfl_xor(pj, 1);
        pj += __shfl_xor(pj, 2);
        pj += __shfl_xor(pj, 4);
        pj += __shfl_xor(pj, 8);
        if (lr == 0)
            outp[sIdx[2][w * 16 + lk * 4 + j]] = 1.f / (1.f + expf(-(pj + b3)));
    }
}

// ================= launch =================
extern "C" void kernel_launch(void* const* d_in, const int* in_sizes, int n_in,
                              void* d_out, int out_size, void* d_ws, size_t ws_size,
                              hipStream_t stream) {
    const float* x   = (const float*)d_in[0];
    const int*   ei  = (const int*)d_in[1];
    const float* W1  = (const float*)d_in[2];
    const float* b1  = (const float*)d_in[3];
    const float* W2  = (const float*)d_in[4];
    const float* b2  = (const float*)d_in[5];
    const float* Wm1 = (const float*)d_in[6];
    const float* bm1 = (const float*)d_in[7];
    const float* Wm2 = (const float*)d_in[8];
    const float* bm2 = (const float*)d_in[9];
    const float* Wm3 = (const float*)d_in[10];
    const float* bm3 = (const float*)d_in[11];
    const int* esrc = ei;
    const int* edst = ei + N_EDGES;
    float* outp = (float*)d_out;

    // workspace layout
    float* ws = (float*)d_ws;
    float* dinv = ws;                                   // 100096 floats
    float* A = ws + 100096;                             // N*128 f32
    float* B = A + (size_t)N_NODES * 128;               // N*128 f32
    int* deg     = (int*)(B + (size_t)N_NODES * 128);   // N
    int* off     = deg + N_NODES;                       // N+1
    int* cur     = off + N_NODES + 1;                   // N
    int* bsum    = cur + N_NODES;                       // 512
    // align to 16 B for int4
    size_t ioff = (size_t)(bsum + 512 - (int*)d_ws);
    ioff = (ioff + 3) & ~(size_t)3;
    int4* csr_pack = (int4*)((int*)d_ws + ioff);        // E int4
    unsigned short* frag = (unsigned short*)(csr_pack + N_EDGES);
    unsigned short* W1h   = frag;                 unsigned short* W1l   = frag + 16384;
    unsigned short* W2h   = frag + 2 * 16384;     unsigned short* W2l   = frag + 3 * 16384;
    unsigned short* Wm1ah = frag + 4 * 16384;     unsigned short* Wm1al = frag + 5 * 16384;
    unsigned short* Wm1bh = frag + 6 * 16384;     unsigned short* Wm1bl = frag + 7 * 16384;
    unsigned short* Wm2h  = frag + 8 * 16384;     unsigned short* Wm2l  = frag + 9 * 16384;
    // bf16 P/Q live in A's storage (A dead after layer-2 aggregation)
    unsigned short* Pb = (unsigned short*)A;                         // N*128 ushort
    unsigned short* Qb = (unsigned short*)A + (size_t)N_NODES * 128; // N*128 ushort

    const int nb = (N_NODES + 255) / 256;               // 391 scan blocks

    // ---- CSR build + W splits ----
    k_zero_deg<<<nb, 256, 0, stream>>>(deg);
    k_hist<<<(N_EDGES + 255) / 256, 256, 0, stream>>>(edst, deg);
    k_scan1<<<nb, 256, 0, stream>>>(deg, off, bsum, dinv, N_NODES);
    k_scan2<<<1, 512, 0, stream>>>(bsum, nb);
    k_scan3<<<(N_NODES + 256) / 256, 256, 0, stream>>>(off, bsum, cur, N_NODES);
    k_scatter<<<(N_EDGES + 255) / 256, 256, 0, stream>>>(esrc, edst, dinv, cur, csr_pack);

    SplitArgs sa;
    sa.W[0] = W1;  sa.Wh[0] = W1h;   sa.Wl[0] = W1l;
    sa.W[1] = W2;  sa.Wh[1] = W2h;   sa.Wl[1] = W2l;
    sa.W[2] = Wm1; sa.Wh[2] = Wm1ah; sa.Wl[2] = Wm1al;
    sa.W[3] = Wm1 + 128 * 128; sa.Wh[3] = Wm1bh; sa.Wl[3] = Wm1bl;
    sa.W[4] = Wm2; sa.Wh[4] = Wm2h;  sa.Wl[4] = Wm2l;
    k_split_all<<<5 * 64, 256, 0, stream>>>(sa);

    const int RT = 4;                                   // row tiles per block (128 rows each)
    const int gemm_blocks = (N_NODES + 128 * RT - 1) / (128 * RT);   // 196
    const int agg_blocks = (N_NODES + 7) / 8;

    // ---- layer 1: A = x @ W1 ; B = b1 + norm-agg(A) ----
    k_gemm_mfma<false><<<gemm_blocks, 512, 0, stream>>>(x, W1h, W1l, A, N_NODES, RT);
    k_agg_csr<<<agg_blocks, 256, 0, stream>>>(A, dinv, off, csr_pack, b1, B);

    // ---- layer 2: A = relu(B) @ W2 ; B = b2 + norm-agg(A) ----
    k_gemm_mfma<true><<<gemm_blocks, 512, 0, stream>>>(B, W2h, W2l, A, N_NODES, RT);
    k_agg_csr<<<agg_blocks, 256, 0, stream>>>(A, dinv, off, csr_pack, b2, B);

    // ---- edge-MLP layer-1 decomposition: Pb/Qb (bf16) from relu(B) ----
    k_gemm_pq_mfma<<<gemm_blocks, 512, 0, stream>>>(B, Wm1ah, Wm1al, Wm1bh, Wm1bl,
                                                    Pb, Qb, N_NODES, RT);

    // ---- fused edge MLP on MFMA, CSR order, bf16 gathers ----
    k_edge_mlp_mfma<<<N_EDGES / 128, 512, 0, stream>>>(csr_pack, Pb, Qb, bm1,
                                                       Wm2h, Wm2l, bm2, Wm3, bm3, outp);
}

// Round 14
// 451.074 us; speedup vs baseline: 1.3588x; 1.1169x over previous
//
#include <hip/hip_runtime.h>
#include <hip/hip_bf16.h>
#include <math.h>

#define N_NODES 100000
#define N_EDGES 800000

typedef float f32x4 __attribute__((ext_vector_type(4)));
typedef short bf16x8 __attribute__((ext_vector_type(8)));

__device__ inline unsigned short bf16_of(float f) {
    union { __hip_bfloat16 b; unsigned short u; } cv;
    cv.b = __float2bfloat16(f);
    return cv.u;
}
__device__ inline float f32_of(unsigned short u) {
    union { __hip_bfloat16 b; unsigned short u; } cv;
    cv.u = u;
    return __bfloat162float(cv.b);
}

// ================= degree / CSR build =================
__global__ void k_zero_deg(int* __restrict__ deg) {
    int i = blockIdx.x * blockDim.x + threadIdx.x;
    if (i < N_NODES) deg[i] = 0;
}

__global__ void k_hist(const int* __restrict__ edst, int* __restrict__ deg) {
    int e = blockIdx.x * blockDim.x + threadIdx.x;
    if (e < N_EDGES) atomicAdd(&deg[edst[e]], 1);
}

// exclusive scan + dinv fused, 256/block
__global__ void k_scan1(const int* __restrict__ deg, int* __restrict__ off,
                        int* __restrict__ bsum, float* __restrict__ dinv, int n) {
    __shared__ int s[256];
    int t = threadIdx.x;
    int i = blockIdx.x * 256 + t;
    int v = (i < n) ? deg[i] : 0;
    if (i < n) dinv[i] = rsqrtf((float)(v + 1));   // +1 self-loop
    s[t] = v;
    __syncthreads();
    #pragma unroll
    for (int d = 1; d < 256; d <<= 1) {
        int x = (t >= d) ? s[t - d] : 0;
        __syncthreads();
        s[t] += x;
        __syncthreads();
    }
    if (i < n) off[i] = s[t] - v;            // exclusive within block
    if (t == 255) bsum[blockIdx.x] = s[255];
}

__global__ void k_scan2(int* __restrict__ bsum, int nb) {
    __shared__ int s[512];
    int t = threadIdx.x;
    int v = (t < nb) ? bsum[t] : 0;
    s[t] = v;
    __syncthreads();
    #pragma unroll
    for (int d = 1; d < 512; d <<= 1) {
        int x = (t >= d) ? s[t - d] : 0;
        __syncthreads();
        s[t] += x;
        __syncthreads();
    }
    if (t < nb) bsum[t] = s[t] - v;          // exclusive block offsets
}

__global__ void k_scan3(int* __restrict__ off, const int* __restrict__ bsum,
                        int* __restrict__ cur, int n) {
    int i = blockIdx.x * blockDim.x + threadIdx.x;
    if (i < n) {
        int o = off[i] + bsum[i >> 8];
        off[i] = o;
        cur[i] = o;
    }
    if (i == n) off[n] = N_EDGES;
}

// scatter edges into dst-grouped CSR: ONE packed int4 {src, dst, w_bits, eid} per edge
__global__ void k_scatter(const int* __restrict__ esrc, const int* __restrict__ edst,
                          const float* __restrict__ dinv,
                          int* __restrict__ cur, int4* __restrict__ csr_pack) {
    int e = blockIdx.x * blockDim.x + threadIdx.x;
    if (e >= N_EDGES) return;
    int s = esrc[e], d = edst[e];
    int pos = atomicAdd(&cur[d], 1);
    float w = dinv[s] * dinv[d];
    csr_pack[pos] = make_int4(s, d, __float_as_int(w), e);
}

// ================= bf16 hi/lo split of 5 x (128x128) W into MFMA fragment layout ====
// frag index for (k, c): lane = ((k>>3)&3)*16 + (c&15), elem = k&7, tile = (k>>5)*8 + (c>>4)
struct SplitArgs {
    const float* W[5];
    unsigned short* Wh[5];
    unsigned short* Wl[5];
};
__global__ void k_split_all(SplitArgs a) {
    int which = blockIdx.x >> 6;                    // 64 blocks per matrix
    int idx = (blockIdx.x & 63) * 256 + threadIdx.x;
    if (idx >= 128 * 128) return;
    int k = idx >> 7, c = idx & 127;
    float wv = a.W[which][idx];
    unsigned short h = bf16_of(wv);
    unsigned short lo = bf16_of(wv - f32_of(h));
    int fi = (((k >> 5) * 8 + (c >> 4)) * 64 + (((k >> 3) & 3) * 16 + (c & 15))) * 8 + (k & 7);
    a.Wh[which][fi] = h;
    a.Wl[which][fi] = lo;
}

// ================= MFMA node GEMM: out_bf16 = (relu?)in[N,128] @ W[128,128] ============
// bf16x3 error-compensated; OUTPUT STORED AS BF16 (feeds aggregation gathers).
template<bool RELU>
__global__ __launch_bounds__(512) void k_gemm_mfma(
    const float* __restrict__ in,
    const unsigned short* __restrict__ Whf, const unsigned short* __restrict__ Wlf,
    unsigned short* __restrict__ outp, int nrows, int rtiles)
{
    __shared__ __align__(16) unsigned short sWh[16384];
    __shared__ __align__(16) unsigned short sWl[16384];
    const int t = threadIdx.x;

    #pragma unroll
    for (int i = 0; i < 4; ++i) {
        ((float4*)sWh)[t + 512 * i] = ((const float4*)Whf)[t + 512 * i];
        ((float4*)sWl)[t + 512 * i] = ((const float4*)Wlf)[t + 512 * i];
    }
    __syncthreads();

    const int w = t >> 6, l = t & 63;
    const int lr = l & 15, lk = l >> 4;

    for (int r = 0; r < rtiles; ++r) {
        const int row0 = (blockIdx.x * rtiles + r) * 128;
        int arow = row0 + w * 16 + lr;
        if (arow >= nrows) arow = nrows - 1;     // clamp (stores are guarded)
        const float* inrow = in + (size_t)arow * 128 + lk * 8;

        bf16x8 ah[4], al[4];
        #pragma unroll
        for (int ks = 0; ks < 4; ++ks) {
            float4 p0 = *(const float4*)(inrow + ks * 32);
            float4 p1 = *(const float4*)(inrow + ks * 32 + 4);
            float z[8] = {p0.x, p0.y, p0.z, p0.w, p1.x, p1.y, p1.z, p1.w};
            #pragma unroll
            for (int e = 0; e < 8; ++e) {
                float zv = RELU ? fmaxf(z[e], 0.f) : z[e];
                unsigned short hu = bf16_of(zv);
                ah[ks][e] = (short)hu;
                al[ks][e] = (short)bf16_of(zv - f32_of(hu));
            }
        }

        f32x4 acc[8];
        #pragma unroll
        for (int ct = 0; ct < 8; ++ct) { f32x4 zz = {0.f, 0.f, 0.f, 0.f}; acc[ct] = zz; }

        #pragma unroll
        for (int ct = 0; ct < 8; ++ct) {
            #pragma unroll
            for (int ks = 0; ks < 4; ++ks) {
                const bf16x8 bh = *(const bf16x8*)(sWh + ((ks * 8 + ct) * 64 + l) * 8);
                const bf16x8 bl = *(const bf16x8*)(sWl + ((ks * 8 + ct) * 64 + l) * 8);
                acc[ct] = __builtin_amdgcn_mfma_f32_16x16x32_bf16(ah[ks], bh, acc[ct], 0, 0, 0);
                acc[ct] = __builtin_amdgcn_mfma_f32_16x16x32_bf16(ah[ks], bl, acc[ct], 0, 0, 0);
                acc[ct] = __builtin_amdgcn_mfma_f32_16x16x32_bf16(al[ks], bh, acc[ct], 0, 0, 0);
            }
        }

        // D: row m = lk*4 + j (within wave tile), col = ct*16 + lr
        #pragma unroll
        for (int j = 0; j < 4; ++j) {
            int m = row0 + w * 16 + lk * 4 + j;
            if (m < nrows) {
                #pragma unroll
                for (int ct = 0; ct < 8; ++ct)
                    outp[(size_t)m * 128 + ct * 16 + lr] = bf16_of(acc[ct][j]);
            }
        }
    }
}

// ================= MFMA P/Q GEMM -> bf16 outputs =================
// P = bf16(relu(in)@Wm1_top), Q = bf16(relu(in)@Wm1_bot). Reads f32 in (B), writes
// ushort P/Q (disjoint storage). Two passes sharing one LDS region.
__global__ __launch_bounds__(512) void k_gemm_pq_mfma(
    const float* __restrict__ in,
    const unsigned short* __restrict__ Wh0, const unsigned short* __restrict__ Wl0,
    const unsigned short* __restrict__ Wh1, const unsigned short* __restrict__ Wl1,
    unsigned short* __restrict__ P, unsigned short* __restrict__ Q, int nrows, int rtiles)
{
    __shared__ __align__(16) unsigned short sWh[16384];
    __shared__ __align__(16) unsigned short sWl[16384];
    const int t = threadIdx.x;
    const int w = t >> 6, l = t & 63;
    const int lr = l & 15, lk = l >> 4;

    #pragma unroll
    for (int half = 0; half < 2; ++half) {
        const unsigned short* Whf = half ? Wh1 : Wh0;
        const unsigned short* Wlf = half ? Wl1 : Wl0;
        unsigned short* outp = half ? Q : P;
        if (half) __syncthreads();     // all waves done reading previous sW
        #pragma unroll
        for (int i = 0; i < 4; ++i) {
            ((float4*)sWh)[t + 512 * i] = ((const float4*)Whf)[t + 512 * i];
            ((float4*)sWl)[t + 512 * i] = ((const float4*)Wlf)[t + 512 * i];
        }
        __syncthreads();

        for (int r = 0; r < rtiles; ++r) {
            const int row0 = (blockIdx.x * rtiles + r) * 128;
            int arow = row0 + w * 16 + lr;
            if (arow >= nrows) arow = nrows - 1;
            const float* inrow = in + (size_t)arow * 128 + lk * 8;

            bf16x8 ah[4], al[4];
            #pragma unroll
            for (int ks = 0; ks < 4; ++ks) {
                float4 p0 = *(const float4*)(inrow + ks * 32);
                float4 p1 = *(const float4*)(inrow + ks * 32 + 4);
                float z[8] = {p0.x, p0.y, p0.z, p0.w, p1.x, p1.y, p1.z, p1.w};
                #pragma unroll
                for (int e = 0; e < 8; ++e) {
                    float zv = fmaxf(z[e], 0.f);
                    unsigned short hu = bf16_of(zv);
                    ah[ks][e] = (short)hu;
                    al[ks][e] = (short)bf16_of(zv - f32_of(hu));
                }
            }

            f32x4 acc[8];
            #pragma unroll
            for (int ct = 0; ct < 8; ++ct) { f32x4 zz = {0.f, 0.f, 0.f, 0.f}; acc[ct] = zz; }

            #pragma unroll
            for (int ct = 0; ct < 8; ++ct) {
                #pragma unroll
                for (int ks = 0; ks < 4; ++ks) {
                    const bf16x8 bh = *(const bf16x8*)(sWh + ((ks * 8 + ct) * 64 + l) * 8);
                    const bf16x8 bl = *(const bf16x8*)(sWl + ((ks * 8 + ct) * 64 + l) * 8);
                    acc[ct] = __builtin_amdgcn_mfma_f32_16x16x32_bf16(ah[ks], bh, acc[ct], 0, 0, 0);
                    acc[ct] = __builtin_amdgcn_mfma_f32_16x16x32_bf16(ah[ks], bl, acc[ct], 0, 0, 0);
                    acc[ct] = __builtin_amdgcn_mfma_f32_16x16x32_bf16(al[ks], bh, acc[ct], 0, 0, 0);
                }
            }

            #pragma unroll
            for (int j = 0; j < 4; ++j) {
                int m = row0 + w * 16 + lk * 4 + j;
                if (m < nrows) {
                    #pragma unroll
                    for (int ct = 0; ct < 8; ++ct)
                        outp[(size_t)m * 128 + ct * 16 + lr] = bf16_of(acc[ct][j]);
                }
            }
        }
    }
}

// ================= CSR aggregation (bf16 raw rows, packed records) =================
// out[i][:] = bias[:] + dinv[i]^2 * raw[i][:] + sum_{e: dst=i} w_e * raw[src_e][:]
// raw is bf16 (256 B/row) -> half the stream + gather bytes; accumulate f32.
__global__ __launch_bounds__(256) void k_agg_csr(
    const unsigned short* __restrict__ raw, const float* __restrict__ dinv,
    const int* __restrict__ off, const int4* __restrict__ csr_pack,
    const float* __restrict__ bias, float* __restrict__ outp)
{
    const int t = threadIdx.x;
    const int node = blockIdx.x * 8 + (t >> 5);
    const int lane = t & 31;
    if (node >= N_NODES) return;

    float di = dinv[node];
    float w0 = di * di;
    float4 acc = ((const float4*)bias)[lane];
    {
        ushort4 v = ((const ushort4*)raw)[(size_t)node * 32 + lane];
        acc.x += w0 * f32_of(v.x); acc.y += w0 * f32_of(v.y);
        acc.z += w0 * f32_of(v.z); acc.w += w0 * f32_of(v.w);
    }

    const int beg = off[node], end = off[node + 1];
    for (int base = beg; base < end; base += 32) {
        int cnt = end - base;
        if (cnt > 32) cnt = 32;
        int sj = 0;
        float wj = 0.f;
        if (lane < cnt) {
            int4 p = csr_pack[base + lane];
            sj = p.x;
            wj = __int_as_float(p.z);
        }
        for (int j = 0; j < cnt; ++j) {
            int s = __shfl(sj, j, 32);
            float w = __shfl(wj, j, 32);
            ushort4 u = ((const ushort4*)raw)[(size_t)s * 32 + lane];
            acc.x += w * f32_of(u.x); acc.y += w * f32_of(u.y);
            acc.z += w * f32_of(u.z); acc.w += w * f32_of(u.w);
        }
    }
    ((float4*)outp)[(size_t)node * 32 + lane] = acc;
}

// ================= fused edge MLP (MFMA bf16x3, CSR order, bf16 P/Q gathers) ===========
__global__ __launch_bounds__(512) void k_edge_mlp_mfma(
    const int4* __restrict__ csr_pack,
    const unsigned short* __restrict__ P, const unsigned short* __restrict__ Q,
    const float* __restrict__ bm1,
    const unsigned short* __restrict__ Whf, const unsigned short* __restrict__ Wlf,
    const float* __restrict__ bm2,
    const float* __restrict__ Wm3, const float* __restrict__ bm3,
    float* __restrict__ outp)
{
    __shared__ __align__(16) unsigned short sWh[16384];   // 32 KB, fragment layout
    __shared__ __align__(16) unsigned short sWl[16384];   // 32 KB
    __shared__ int sIdx[3][128];

    const int t = threadIdx.x;
    const int e0 = blockIdx.x * 128;

    // linear stage of W fragments + packed index records
    #pragma unroll
    for (int i = 0; i < 4; ++i) {
        ((float4*)sWh)[t + 512 * i] = ((const float4*)Whf)[t + 512 * i];
        ((float4*)sWl)[t + 512 * i] = ((const float4*)Wlf)[t + 512 * i];
    }
    if (t < 128) {
        int4 p = csr_pack[e0 + t];
        sIdx[0][t] = p.x;
        sIdx[1][t] = p.y;
        sIdx[2][t] = p.w;
    }
    __syncthreads();

    const int w = t >> 6;          // wave id 0..7: rows w*16 .. w*16+15
    const int l = t & 63;
    const int lr = l & 15;         // A row within tile / D col
    const int lk = l >> 4;         // k-block
    const int row = w * 16 + lr;
    const int s = sIdx[0][row], d = sIdx[1][row];
    const unsigned short* prow = P + (size_t)s * 128 + lk * 8;
    const unsigned short* qrow = Q + (size_t)d * 128 + lk * 8;
    const float* brow = bm1 + lk * 8;

    // build A-fragments (z1 hi/lo) in registers from bf16 P/Q
    bf16x8 ah[4], al[4];
    #pragma unroll
    for (int ks = 0; ks < 4; ++ks) {
        bf16x8 pv = *(const bf16x8*)(prow + ks * 32);
        bf16x8 qv = *(const bf16x8*)(qrow + ks * 32);
        float4 b0 = *(const float4*)(brow + ks * 32);
        float4 b1 = *(const float4*)(brow + ks * 32 + 4);
        float bb[8] = {b0.x, b0.y, b0.z, b0.w, b1.x, b1.y, b1.z, b1.w};
        #pragma unroll
        for (int e = 0; e < 8; ++e) {
            float zv = fmaxf(f32_of((unsigned short)pv[e]) +
                             f32_of((unsigned short)qv[e]) + bb[e], 0.f);
            unsigned short hu = bf16_of(zv);
            ah[ks][e] = (short)hu;
            al[ks][e] = (short)bf16_of(zv - f32_of(hu));
        }
    }

    // C = z1 @ Wm2 + bm2  (8 col tiles of 16)
    f32x4 acc[8];
    #pragma unroll
    for (int ct = 0; ct < 8; ++ct) {
        float bv = bm2[ct * 16 + lr];
        f32x4 a = {bv, bv, bv, bv};
        acc[ct] = a;
    }

    #pragma unroll
    for (int ct = 0; ct < 8; ++ct) {
        #pragma unroll
        for (int ks = 0; ks < 4; ++ks) {
            const bf16x8 bh = *(const bf16x8*)(sWh + ((ks * 8 + ct) * 64 + l) * 8);
            const bf16x8 bl = *(const bf16x8*)(sWl + ((ks * 8 + ct) * 64 + l) * 8);
            acc[ct] = __builtin_amdgcn_mfma_f32_16x16x32_bf16(ah[ks], bh, acc[ct], 0, 0, 0);
            acc[ct] = __builtin_amdgcn_mfma_f32_16x16x32_bf16(ah[ks], bl, acc[ct], 0, 0, 0);
            acc[ct] = __builtin_amdgcn_mfma_f32_16x16x32_bf16(al[ks], bh, acc[ct], 0, 0, 0);
        }
    }

    // out = sigmoid(relu(C) @ Wm3 + bm3); D layout: col = lr, row = lk*4 + reg
    float w3v[8];
    #pragma unroll
    for (int ct = 0; ct < 8; ++ct) w3v[ct] = Wm3[ct * 16 + lr];
    float b3 = bm3[0];
    #pragma unroll
    for (int j = 0; j < 4; ++j) {
        float pj = 0.f;
        #pragma unroll
        for (int ct = 0; ct < 8; ++ct) pj += fmaxf(acc[ct][j], 0.f) * w3v[ct];
        pj += __shfl_xor(pj, 1);
        pj += __shfl_xor(pj, 2);
        pj += __shfl_xor(pj, 4);
        pj += __shfl_xor(pj, 8);
        if (lr == 0)
            outp[sIdx[2][w * 16 + lk * 4 + j]] = 1.f / (1.f + expf(-(pj + b3)));
    }
}

// ================= launch =================
extern "C" void kernel_launch(void* const* d_in, const int* in_sizes, int n_in,
                              void* d_out, int out_size, void* d_ws, size_t ws_size,
                              hipStream_t stream) {
    const float* x   = (const float*)d_in[0];
    const int*   ei  = (const int*)d_in[1];
    const float* W1  = (const float*)d_in[2];
    const float* b1  = (const float*)d_in[3];
    const float* W2  = (const float*)d_in[4];
    const float* b2  = (const float*)d_in[5];
    const float* Wm1 = (const float*)d_in[6];
    const float* bm1 = (const float*)d_in[7];
    const float* Wm2 = (const float*)d_in[8];
    const float* bm2 = (const float*)d_in[9];
    const float* Wm3 = (const float*)d_in[10];
    const float* bm3 = (const float*)d_in[11];
    const int* esrc = ei;
    const int* edst = ei + N_EDGES;
    float* outp = (float*)d_out;

    // workspace layout
    float* ws = (float*)d_ws;
    float* dinv = ws;                                   // 100096 floats
    float* A = ws + 100096;                             // N*128 f32 region
    float* B = A + (size_t)N_NODES * 128;               // N*128 f32
    int* deg     = (int*)(B + (size_t)N_NODES * 128);   // N
    int* off     = deg + N_NODES;                       // N+1
    int* cur     = off + N_NODES + 1;                   // N
    int* bsum    = cur + N_NODES;                       // 512
    // align to 16 B for int4
    size_t ioff = (size_t)(bsum + 512 - (int*)d_ws);
    ioff = (ioff + 3) & ~(size_t)3;
    int4* csr_pack = (int4*)((int*)d_ws + ioff);        // E int4
    unsigned short* frag = (unsigned short*)(csr_pack + N_EDGES);
    unsigned short* W1h   = frag;                 unsigned short* W1l   = frag + 16384;
    unsigned short* W2h   = frag + 2 * 16384;     unsigned short* W2l   = frag + 3 * 16384;
    unsigned short* Wm1ah = frag + 4 * 16384;     unsigned short* Wm1al = frag + 5 * 16384;
    unsigned short* Wm1bh = frag + 6 * 16384;     unsigned short* Wm1bl = frag + 7 * 16384;
    unsigned short* Wm2h  = frag + 8 * 16384;     unsigned short* Wm2l  = frag + 9 * 16384;
    // bf16 views of A's storage: Ab (agg operand) first half; Pb/Qb for edge phase
    unsigned short* Ab = (unsigned short*)A;                         // N*128 ushort
    unsigned short* Pb = (unsigned short*)A;                         // N*128 ushort
    unsigned short* Qb = (unsigned short*)A + (size_t)N_NODES * 128; // N*128 ushort

    const int nb = (N_NODES + 255) / 256;               // 391 scan blocks

    // ---- CSR build + W splits ----
    k_zero_deg<<<nb, 256, 0, stream>>>(deg);
    k_hist<<<(N_EDGES + 255) / 256, 256, 0, stream>>>(edst, deg);
    k_scan1<<<nb, 256, 0, stream>>>(deg, off, bsum, dinv, N_NODES);
    k_scan2<<<1, 512, 0, stream>>>(bsum, nb);
    k_scan3<<<(N_NODES + 256) / 256, 256, 0, stream>>>(off, bsum, cur, N_NODES);
    k_scatter<<<(N_EDGES + 255) / 256, 256, 0, stream>>>(esrc, edst, dinv, cur, csr_pack);

    SplitArgs sa;
    sa.W[0] = W1;  sa.Wh[0] = W1h;   sa.Wl[0] = W1l;
    sa.W[1] = W2;  sa.Wh[1] = W2h;   sa.Wl[1] = W2l;
    sa.W[2] = Wm1; sa.Wh[2] = Wm1ah; sa.Wl[2] = Wm1al;
    sa.W[3] = Wm1 + 128 * 128; sa.Wh[3] = Wm1bh; sa.Wl[3] = Wm1bl;
    sa.W[4] = Wm2; sa.Wh[4] = Wm2h;  sa.Wl[4] = Wm2l;
    k_split_all<<<5 * 64, 256, 0, stream>>>(sa);

    const int RT = 4;                                   // row tiles per block (128 rows each)
    const int gemm_blocks = (N_NODES + 128 * RT - 1) / (128 * RT);   // 196
    const int agg_blocks = (N_NODES + 7) / 8;

    // ---- layer 1: Ab = bf16(x @ W1) ; B = b1 + norm-agg(Ab) ----
    k_gemm_mfma<false><<<gemm_blocks, 512, 0, stream>>>(x, W1h, W1l, Ab, N_NODES, RT);
    k_agg_csr<<<agg_blocks, 256, 0, stream>>>(Ab, dinv, off, csr_pack, b1, B);

    // ---- layer 2: Ab = bf16(relu(B) @ W2) ; B = b2 + norm-agg(Ab) ----
    k_gemm_mfma<true><<<gemm_blocks, 512, 0, stream>>>(B, W2h, W2l, Ab, N_NODES, RT);
    k_agg_csr<<<agg_blocks, 256, 0, stream>>>(Ab, dinv, off, csr_pack, b2, B);

    // ---- edge-MLP layer-1 decomposition: Pb/Qb (bf16) from relu(B) ----
    k_gemm_pq_mfma<<<gemm_blocks, 512, 0, stream>>>(B, Wm1ah, Wm1al, Wm1bh, Wm1bl,
                                                    Pb, Qb, N_NODES, RT);

    // ---- fused edge MLP on MFMA, CSR order, bf16 gathers ----
    k_edge_mlp_mfma<<<N_EDGES / 128, 512, 0, stream>>>(csr_pack, Pb, Qb, bm1,
                                                       Wm2h, Wm2l, bm2, Wm3, bm3, outp);
}

// Round 15
// 418.858 us; speedup vs baseline: 1.4633x; 1.0769x over previous
//
#include <hip/hip_runtime.h>
#include <hip/hip_bf16.h>
#include <math.h>

#define N_NODES 100000
#define N_EDGES 800000

typedef float f32x4 __attribute__((ext_vector_type(4)));
typedef short bf16x8 __attribute__((ext_vector_type(8)));

__device__ inline unsigned short bf16_of(float f) {
    union { __hip_bfloat16 b; unsigned short u; } cv;
    cv.b = __float2bfloat16(f);
    return cv.u;
}
__device__ inline float f32_of(unsigned short u) {
    union { __hip_bfloat16 b; unsigned short u; } cv;
    cv.u = u;
    return __bfloat162float(cv.b);
}

// ================= degree / CSR build =================
__global__ void k_zero_deg(int* __restrict__ deg) {
    int i = blockIdx.x * blockDim.x + threadIdx.x;
    if (i < N_NODES) deg[i] = 0;
}

__global__ void k_hist(const int* __restrict__ edst, int* __restrict__ deg) {
    int e = blockIdx.x * blockDim.x + threadIdx.x;
    if (e < N_EDGES) atomicAdd(&deg[edst[e]], 1);
}

// exclusive scan + dinv fused, 256/block
__global__ void k_scan1(const int* __restrict__ deg, int* __restrict__ off,
                        int* __restrict__ bsum, float* __restrict__ dinv, int n) {
    __shared__ int s[256];
    int t = threadIdx.x;
    int i = blockIdx.x * 256 + t;
    int v = (i < n) ? deg[i] : 0;
    if (i < n) dinv[i] = rsqrtf((float)(v + 1));   // +1 self-loop
    s[t] = v;
    __syncthreads();
    #pragma unroll
    for (int d = 1; d < 256; d <<= 1) {
        int x = (t >= d) ? s[t - d] : 0;
        __syncthreads();
        s[t] += x;
        __syncthreads();
    }
    if (i < n) off[i] = s[t] - v;            // exclusive within block
    if (t == 255) bsum[blockIdx.x] = s[255];
}

__global__ void k_scan2(int* __restrict__ bsum, int nb) {
    __shared__ int s[512];
    int t = threadIdx.x;
    int v = (t < nb) ? bsum[t] : 0;
    s[t] = v;
    __syncthreads();
    #pragma unroll
    for (int d = 1; d < 512; d <<= 1) {
        int x = (t >= d) ? s[t - d] : 0;
        __syncthreads();
        s[t] += x;
        __syncthreads();
    }
    if (t < nb) bsum[t] = s[t] - v;          // exclusive block offsets
}

__global__ void k_scan3(int* __restrict__ off, const int* __restrict__ bsum,
                        int* __restrict__ cur, int n) {
    int i = blockIdx.x * blockDim.x + threadIdx.x;
    if (i < n) {
        int o = off[i] + bsum[i >> 8];
        off[i] = o;
        cur[i] = o;
    }
    if (i == n) off[n] = N_EDGES;
}

// scatter edges into dst-grouped CSR: ONE packed int4 {src, dst, w_bits, eid} per edge
__global__ void k_scatter(const int* __restrict__ esrc, const int* __restrict__ edst,
                          const float* __restrict__ dinv,
                          int* __restrict__ cur, int4* __restrict__ csr_pack) {
    int e = blockIdx.x * blockDim.x + threadIdx.x;
    if (e >= N_EDGES) return;
    int s = esrc[e], d = edst[e];
    int pos = atomicAdd(&cur[d], 1);
    float w = dinv[s] * dinv[d];
    csr_pack[pos] = make_int4(s, d, __float_as_int(w), e);
}

// ================= bf16 hi/lo split of 5 x (128x128) W into MFMA fragment layout ====
// frag index for (k, c): lane = ((k>>3)&3)*16 + (c&15), elem = k&7, tile = (k>>5)*8 + (c>>4)
struct SplitArgs {
    const float* W[5];
    unsigned short* Wh[5];
    unsigned short* Wl[5];
};
__global__ void k_split_all(SplitArgs a) {
    int which = blockIdx.x >> 6;                    // 64 blocks per matrix
    int idx = (blockIdx.x & 63) * 256 + threadIdx.x;
    if (idx >= 128 * 128) return;
    int k = idx >> 7, c = idx & 127;
    float wv = a.W[which][idx];
    unsigned short h = bf16_of(wv);
    unsigned short lo = bf16_of(wv - f32_of(h));
    int fi = (((k >> 5) * 8 + (c >> 4)) * 64 + (((k >> 3) & 3) * 16 + (c & 15))) * 8 + (k & 7);
    a.Wh[which][fi] = h;
    a.Wl[which][fi] = lo;
}

// ================= MFMA node GEMM (f32 input, 3-term): out_bf16 = in @ W ==============
__global__ __launch_bounds__(512) void k_gemm_mfma_f32(
    const float* __restrict__ in,
    const unsigned short* __restrict__ Whf, const unsigned short* __restrict__ Wlf,
    unsigned short* __restrict__ outp, int nrows, int rtiles)
{
    __shared__ __align__(16) unsigned short sWh[16384];
    __shared__ __align__(16) unsigned short sWl[16384];
    const int t = threadIdx.x;

    #pragma unroll
    for (int i = 0; i < 4; ++i) {
        ((float4*)sWh)[t + 512 * i] = ((const float4*)Whf)[t + 512 * i];
        ((float4*)sWl)[t + 512 * i] = ((const float4*)Wlf)[t + 512 * i];
    }
    __syncthreads();

    const int w = t >> 6, l = t & 63;
    const int lr = l & 15, lk = l >> 4;

    for (int r = 0; r < rtiles; ++r) {
        const int row0 = (blockIdx.x * rtiles + r) * 128;
        int arow = row0 + w * 16 + lr;
        if (arow >= nrows) arow = nrows - 1;
        const float* inrow = in + (size_t)arow * 128 + lk * 8;

        bf16x8 ah[4], al[4];
        #pragma unroll
        for (int ks = 0; ks < 4; ++ks) {
            float4 p0 = *(const float4*)(inrow + ks * 32);
            float4 p1 = *(const float4*)(inrow + ks * 32 + 4);
            float z[8] = {p0.x, p0.y, p0.z, p0.w, p1.x, p1.y, p1.z, p1.w};
            #pragma unroll
            for (int e = 0; e < 8; ++e) {
                unsigned short hu = bf16_of(z[e]);
                ah[ks][e] = (short)hu;
                al[ks][e] = (short)bf16_of(z[e] - f32_of(hu));
            }
        }

        f32x4 acc[8];
        #pragma unroll
        for (int ct = 0; ct < 8; ++ct) { f32x4 zz = {0.f, 0.f, 0.f, 0.f}; acc[ct] = zz; }

        #pragma unroll
        for (int ct = 0; ct < 8; ++ct) {
            #pragma unroll
            for (int ks = 0; ks < 4; ++ks) {
                const bf16x8 bh = *(const bf16x8*)(sWh + ((ks * 8 + ct) * 64 + l) * 8);
                const bf16x8 bl = *(const bf16x8*)(sWl + ((ks * 8 + ct) * 64 + l) * 8);
                acc[ct] = __builtin_amdgcn_mfma_f32_16x16x32_bf16(ah[ks], bh, acc[ct], 0, 0, 0);
                acc[ct] = __builtin_amdgcn_mfma_f32_16x16x32_bf16(ah[ks], bl, acc[ct], 0, 0, 0);
                acc[ct] = __builtin_amdgcn_mfma_f32_16x16x32_bf16(al[ks], bh, acc[ct], 0, 0, 0);
            }
        }

        #pragma unroll
        for (int j = 0; j < 4; ++j) {
            int m = row0 + w * 16 + lk * 4 + j;
            if (m < nrows) {
                #pragma unroll
                for (int ct = 0; ct < 8; ++ct)
                    outp[(size_t)m * 128 + ct * 16 + lr] = bf16_of(acc[ct][j]);
            }
        }
    }
}

// ================= MFMA node GEMM (bf16 input + relu, 2-term): out_bf16 = relu(in)@W ===
// Input lo is exactly zero (bf16 storage) -> only ah@bh + ah@bl needed.
__global__ __launch_bounds__(512) void k_gemm_mfma_bf16(
    const unsigned short* __restrict__ in,
    const unsigned short* __restrict__ Whf, const unsigned short* __restrict__ Wlf,
    unsigned short* __restrict__ outp, int nrows, int rtiles)
{
    __shared__ __align__(16) unsigned short sWh[16384];
    __shared__ __align__(16) unsigned short sWl[16384];
    const int t = threadIdx.x;

    #pragma unroll
    for (int i = 0; i < 4; ++i) {
        ((float4*)sWh)[t + 512 * i] = ((const float4*)Whf)[t + 512 * i];
        ((float4*)sWl)[t + 512 * i] = ((const float4*)Wlf)[t + 512 * i];
    }
    __syncthreads();

    const int w = t >> 6, l = t & 63;
    const int lr = l & 15, lk = l >> 4;

    for (int r = 0; r < rtiles; ++r) {
        const int row0 = (blockIdx.x * rtiles + r) * 128;
        int arow = row0 + w * 16 + lr;
        if (arow >= nrows) arow = nrows - 1;
        const unsigned short* inrow = in + (size_t)arow * 128 + lk * 8;

        bf16x8 ah[4];
        #pragma unroll
        for (int ks = 0; ks < 4; ++ks) {
            bf16x8 v = *(const bf16x8*)(inrow + ks * 32);
            #pragma unroll
            for (int e = 0; e < 8; ++e) {
                unsigned short u = (unsigned short)v[e];
                ah[ks][e] = (short)((u & 0x8000) ? 0 : u);   // relu on bf16 bits
            }
        }

        f32x4 acc[8];
        #pragma unroll
        for (int ct = 0; ct < 8; ++ct) { f32x4 zz = {0.f, 0.f, 0.f, 0.f}; acc[ct] = zz; }

        #pragma unroll
        for (int ct = 0; ct < 8; ++ct) {
            #pragma unroll
            for (int ks = 0; ks < 4; ++ks) {
                const bf16x8 bh = *(const bf16x8*)(sWh + ((ks * 8 + ct) * 64 + l) * 8);
                const bf16x8 bl = *(const bf16x8*)(sWl + ((ks * 8 + ct) * 64 + l) * 8);
                acc[ct] = __builtin_amdgcn_mfma_f32_16x16x32_bf16(ah[ks], bh, acc[ct], 0, 0, 0);
                acc[ct] = __builtin_amdgcn_mfma_f32_16x16x32_bf16(ah[ks], bl, acc[ct], 0, 0, 0);
            }
        }

        #pragma unroll
        for (int j = 0; j < 4; ++j) {
            int m = row0 + w * 16 + lk * 4 + j;
            if (m < nrows) {
                #pragma unroll
                for (int ct = 0; ct < 8; ++ct)
                    outp[(size_t)m * 128 + ct * 16 + lr] = bf16_of(acc[ct][j]);
            }
        }
    }
}

// ================= MFMA P/Q GEMM (bf16 input + relu, 2-term) -> bf16 P,Q ==============
__global__ __launch_bounds__(512) void k_gemm_pq_mfma(
    const unsigned short* __restrict__ in,
    const unsigned short* __restrict__ Wh0, const unsigned short* __restrict__ Wl0,
    const unsigned short* __restrict__ Wh1, const unsigned short* __restrict__ Wl1,
    unsigned short* __restrict__ P, unsigned short* __restrict__ Q, int nrows, int rtiles)
{
    __shared__ __align__(16) unsigned short sWh[16384];
    __shared__ __align__(16) unsigned short sWl[16384];
    const int t = threadIdx.x;
    const int w = t >> 6, l = t & 63;
    const int lr = l & 15, lk = l >> 4;

    #pragma unroll
    for (int half = 0; half < 2; ++half) {
        const unsigned short* Whf = half ? Wh1 : Wh0;
        const unsigned short* Wlf = half ? Wl1 : Wl0;
        unsigned short* outp = half ? Q : P;
        if (half) __syncthreads();
        #pragma unroll
        for (int i = 0; i < 4; ++i) {
            ((float4*)sWh)[t + 512 * i] = ((const float4*)Whf)[t + 512 * i];
            ((float4*)sWl)[t + 512 * i] = ((const float4*)Wlf)[t + 512 * i];
        }
        __syncthreads();

        for (int r = 0; r < rtiles; ++r) {
            const int row0 = (blockIdx.x * rtiles + r) * 128;
            int arow = row0 + w * 16 + lr;
            if (arow >= nrows) arow = nrows - 1;
            const unsigned short* inrow = in + (size_t)arow * 128 + lk * 8;

            bf16x8 ah[4];
            #pragma unroll
            for (int ks = 0; ks < 4; ++ks) {
                bf16x8 v = *(const bf16x8*)(inrow + ks * 32);
                #pragma unroll
                for (int e = 0; e < 8; ++e) {
                    unsigned short u = (unsigned short)v[e];
                    ah[ks][e] = (short)((u & 0x8000) ? 0 : u);
                }
            }

            f32x4 acc[8];
            #pragma unroll
            for (int ct = 0; ct < 8; ++ct) { f32x4 zz = {0.f, 0.f, 0.f, 0.f}; acc[ct] = zz; }

            #pragma unroll
            for (int ct = 0; ct < 8; ++ct) {
                #pragma unroll
                for (int ks = 0; ks < 4; ++ks) {
                    const bf16x8 bh = *(const bf16x8*)(sWh + ((ks * 8 + ct) * 64 + l) * 8);
                    const bf16x8 bl = *(const bf16x8*)(sWl + ((ks * 8 + ct) * 64 + l) * 8);
                    acc[ct] = __builtin_amdgcn_mfma_f32_16x16x32_bf16(ah[ks], bh, acc[ct], 0, 0, 0);
                    acc[ct] = __builtin_amdgcn_mfma_f32_16x16x32_bf16(ah[ks], bl, acc[ct], 0, 0, 0);
                }
            }

            #pragma unroll
            for (int j = 0; j < 4; ++j) {
                int m = row0 + w * 16 + lk * 4 + j;
                if (m < nrows) {
                    #pragma unroll
                    for (int ct = 0; ct < 8; ++ct)
                        outp[(size_t)m * 128 + ct * 16 + lr] = bf16_of(acc[ct][j]);
                }
            }
        }
    }
}

// ================= CSR aggregation (bf16 in, bf16 out, f32 accumulate) =================
// out[i][:] = bf16( bias[:] + dinv[i]^2 * raw[i][:] + sum_{e: dst=i} w_e * raw[src_e][:] )
__global__ __launch_bounds__(256) void k_agg_csr(
    const unsigned short* __restrict__ raw, const float* __restrict__ dinv,
    const int* __restrict__ off, const int4* __restrict__ csr_pack,
    const float* __restrict__ bias, unsigned short* __restrict__ outp)
{
    const int t = threadIdx.x;
    const int node = blockIdx.x * 8 + (t >> 5);
    const int lane = t & 31;
    if (node >= N_NODES) return;

    float di = dinv[node];
    float w0 = di * di;
    float4 acc = ((const float4*)bias)[lane];
    {
        ushort4 v = ((const ushort4*)raw)[(size_t)node * 32 + lane];
        acc.x += w0 * f32_of(v.x); acc.y += w0 * f32_of(v.y);
        acc.z += w0 * f32_of(v.z); acc.w += w0 * f32_of(v.w);
    }

    const int beg = off[node], end = off[node + 1];
    for (int base = beg; base < end; base += 32) {
        int cnt = end - base;
        if (cnt > 32) cnt = 32;
        int sj = 0;
        float wj = 0.f;
        if (lane < cnt) {
            int4 p = csr_pack[base + lane];
            sj = p.x;
            wj = __int_as_float(p.z);
        }
        for (int j = 0; j < cnt; ++j) {
            int s = __shfl(sj, j, 32);
            float w = __shfl(wj, j, 32);
            ushort4 u = ((const ushort4*)raw)[(size_t)s * 32 + lane];
            acc.x += w * f32_of(u.x); acc.y += w * f32_of(u.y);
            acc.z += w * f32_of(u.z); acc.w += w * f32_of(u.w);
        }
    }
    ushort4 o;
    o.x = bf16_of(acc.x); o.y = bf16_of(acc.y);
    o.z = bf16_of(acc.z); o.w = bf16_of(acc.w);
    ((ushort4*)outp)[(size_t)node * 32 + lane] = o;
}

// ================= fused edge MLP (MFMA 2-term, CSR order, bf16 P/Q gathers) ===========
__global__ __launch_bounds__(512) void k_edge_mlp_mfma(
    const int4* __restrict__ csr_pack,
    const unsigned short* __restrict__ P, const unsigned short* __restrict__ Q,
    const float* __restrict__ bm1,
    const unsigned short* __restrict__ Whf, const unsigned short* __restrict__ Wlf,
    const float* __restrict__ bm2,
    const float* __restrict__ Wm3, const float* __restrict__ bm3,
    float* __restrict__ outp)
{
    __shared__ __align__(16) unsigned short sWh[16384];   // 32 KB, fragment layout
    __shared__ __align__(16) unsigned short sWl[16384];   // 32 KB
    __shared__ int sIdx[3][128];

    const int t = threadIdx.x;
    const int e0 = blockIdx.x * 128;

    #pragma unroll
    for (int i = 0; i < 4; ++i) {
        ((float4*)sWh)[t + 512 * i] = ((const float4*)Whf)[t + 512 * i];
        ((float4*)sWl)[t + 512 * i] = ((const float4*)Wlf)[t + 512 * i];
    }
    if (t < 128) {
        int4 p = csr_pack[e0 + t];
        sIdx[0][t] = p.x;
        sIdx[1][t] = p.y;
        sIdx[2][t] = p.w;
    }
    __syncthreads();

    const int w = t >> 6;          // wave id 0..7: rows w*16 .. w*16+15
    const int l = t & 63;
    const int lr = l & 15;         // A row within tile / D col
    const int lk = l >> 4;         // k-block
    const int row = w * 16 + lr;
    const int s = sIdx[0][row], d = sIdx[1][row];
    const unsigned short* prow = P + (size_t)s * 128 + lk * 8;
    const unsigned short* qrow = Q + (size_t)d * 128 + lk * 8;
    const float* brow = bm1 + lk * 8;

    // build A-fragments z1 = bf16(relu(P+Q+bm1)) in registers
    bf16x8 ah[4];
    #pragma unroll
    for (int ks = 0; ks < 4; ++ks) {
        bf16x8 pv = *(const bf16x8*)(prow + ks * 32);
        bf16x8 qv = *(const bf16x8*)(qrow + ks * 32);
        float4 b0 = *(const float4*)(brow + ks * 32);
        float4 b1 = *(const float4*)(brow + ks * 32 + 4);
        float bb[8] = {b0.x, b0.y, b0.z, b0.w, b1.x, b1.y, b1.z, b1.w};
        #pragma unroll
        for (int e = 0; e < 8; ++e) {
            float zv = fmaxf(f32_of((unsigned short)pv[e]) +
                             f32_of((unsigned short)qv[e]) + bb[e], 0.f);
            ah[ks][e] = (short)bf16_of(zv);
        }
    }

    // C = z1 @ Wm2 + bm2  (8 col tiles of 16), 2 MFMAs per (ct,ks)
    f32x4 acc[8];
    #pragma unroll
    for (int ct = 0; ct < 8; ++ct) {
        float bv = bm2[ct * 16 + lr];
        f32x4 a = {bv, bv, bv, bv};
        acc[ct] = a;
    }

    #pragma unroll
    for (int ct = 0; ct < 8; ++ct) {
        #pragma unroll
        for (int ks = 0; ks < 4; ++ks) {
            const bf16x8 bh = *(const bf16x8*)(sWh + ((ks * 8 + ct) * 64 + l) * 8);
            const bf16x8 bl = *(const bf16x8*)(sWl + ((ks * 8 + ct) * 64 + l) * 8);
            acc[ct] = __builtin_amdgcn_mfma_f32_16x16x32_bf16(ah[ks], bh, acc[ct], 0, 0, 0);
            acc[ct] = __builtin_amdgcn_mfma_f32_16x16x32_bf16(ah[ks], bl, acc[ct], 0, 0, 0);
        }
    }

    // out = sigmoid(relu(C) @ Wm3 + bm3); D layout: col = lr, row = lk*4 + reg
    float w3v[8];
    #pragma unroll
    for (int ct = 0; ct < 8; ++ct) w3v[ct] = Wm3[ct * 16 + lr];
    float b3 = bm3[0];
    #pragma unroll
    for (int j = 0; j < 4; ++j) {
        float pj = 0.f;
        #pragma unroll
        for (int ct = 0; ct < 8; ++ct) pj += fmaxf(acc[ct][j], 0.f) * w3v[ct];
        pj += __shfl_xor(pj, 1);
        pj += __shfl_xor(pj, 2);
        pj += __shfl_xor(pj, 4);
        pj += __shfl_xor(pj, 8);
        if (lr == 0)
            outp[sIdx[2][w * 16 + lk * 4 + j]] = 1.f / (1.f + expf(-(pj + b3)));
    }
}

// ================= launch =================
extern "C" void kernel_launch(void* const* d_in, const int* in_sizes, int n_in,
                              void* d_out, int out_size, void* d_ws, size_t ws_size,
                              hipStream_t stream) {
    const float* x   = (const float*)d_in[0];
    const int*   ei  = (const int*)d_in[1];
    const float* W1  = (const float*)d_in[2];
    const float* b1  = (const float*)d_in[3];
    const float* W2  = (const float*)d_in[4];
    const float* b2  = (const float*)d_in[5];
    const float* Wm1 = (const float*)d_in[6];
    const float* bm1 = (const float*)d_in[7];
    const float* Wm2 = (const float*)d_in[8];
    const float* bm2 = (const float*)d_in[9];
    const float* Wm3 = (const float*)d_in[10];
    const float* bm3 = (const float*)d_in[11];
    const int* esrc = ei;
    const int* edst = ei + N_EDGES;
    float* outp = (float*)d_out;

    // workspace layout
    float* ws = (float*)d_ws;
    float* dinv = ws;                                   // 100096 floats
    float* A = ws + 100096;                             // N*128 f32 region
    float* B = A + (size_t)N_NODES * 128;               // N*128 f32 region
    int* deg     = (int*)(B + (size_t)N_NODES * 128);   // N
    int* off     = deg + N_NODES;                       // N+1
    int* cur     = off + N_NODES + 1;                   // N
    int* bsum    = cur + N_NODES;                       // 512
    // align to 16 B for int4
    size_t ioff = (size_t)(bsum + 512 - (int*)d_ws);
    ioff = (ioff + 3) & ~(size_t)3;
    int4* csr_pack = (int4*)((int*)d_ws + ioff);        // E int4
    unsigned short* frag = (unsigned short*)(csr_pack + N_EDGES);
    unsigned short* W1h   = frag;                 unsigned short* W1l   = frag + 16384;
    unsigned short* W2h   = frag + 2 * 16384;     unsigned short* W2l   = frag + 3 * 16384;
    unsigned short* Wm1ah = frag + 4 * 16384;     unsigned short* Wm1al = frag + 5 * 16384;
    unsigned short* Wm1bh = frag + 6 * 16384;     unsigned short* Wm1bl = frag + 7 * 16384;
    unsigned short* Wm2h  = frag + 8 * 16384;     unsigned short* Wm2l  = frag + 9 * 16384;
    // bf16 views: Ab (GEMM out / agg in) in A region; Bb (agg out / GEMM in) in B region;
    // Pb/Qb reuse A region for the edge phase (A dead after layer-2 agg).
    unsigned short* Ab = (unsigned short*)A;
    unsigned short* Bb = (unsigned short*)B;
    unsigned short* Pb = (unsigned short*)A;
    unsigned short* Qb = (unsigned short*)A + (size_t)N_NODES * 128;

    const int nb = (N_NODES + 255) / 256;               // 391 scan blocks

    // ---- CSR build + W splits ----
    k_zero_deg<<<nb, 256, 0, stream>>>(deg);
    k_hist<<<(N_EDGES + 255) / 256, 256, 0, stream>>>(edst, deg);
    k_scan1<<<nb, 256, 0, stream>>>(deg, off, bsum, dinv, N_NODES);
    k_scan2<<<1, 512, 0, stream>>>(bsum, nb);
    k_scan3<<<(N_NODES + 256) / 256, 256, 0, stream>>>(off, bsum, cur, N_NODES);
    k_scatter<<<(N_EDGES + 255) / 256, 256, 0, stream>>>(esrc, edst, dinv, cur, csr_pack);

    SplitArgs sa;
    sa.W[0] = W1;  sa.Wh[0] = W1h;   sa.Wl[0] = W1l;
    sa.W[1] = W2;  sa.Wh[1] = W2h;   sa.Wl[1] = W2l;
    sa.W[2] = Wm1; sa.Wh[2] = Wm1ah; sa.Wl[2] = Wm1al;
    sa.W[3] = Wm1 + 128 * 128; sa.Wh[3] = Wm1bh; sa.Wl[3] = Wm1bl;
    sa.W[4] = Wm2; sa.Wh[4] = Wm2h;  sa.Wl[4] = Wm2l;
    k_split_all<<<5 * 64, 256, 0, stream>>>(sa);

    const int RT = 4;                                   // row tiles per block (128 rows each)
    const int gemm_blocks = (N_NODES + 128 * RT - 1) / (128 * RT);   // 196
    const int agg_blocks = (N_NODES + 7) / 8;

    // ---- layer 1: Ab = bf16(x @ W1) ; Bb = bf16(b1 + norm-agg(Ab)) ----
    k_gemm_mfma_f32<<<gemm_blocks, 512, 0, stream>>>(x, W1h, W1l, Ab, N_NODES, RT);
    k_agg_csr<<<agg_blocks, 256, 0, stream>>>(Ab, dinv, off, csr_pack, b1, Bb);

    // ---- layer 2: Ab = bf16(relu(Bb) @ W2) ; Bb = bf16(b2 + norm-agg(Ab)) ----
    k_gemm_mfma_bf16<<<gemm_blocks, 512, 0, stream>>>(Bb, W2h, W2l, Ab, N_NODES, RT);
    k_agg_csr<<<agg_blocks, 256, 0, stream>>>(Ab, dinv, off, csr_pack, b2, Bb);

    // ---- edge-MLP layer-1 decomposition: Pb/Qb (bf16) from relu(Bb) ----
    k_gemm_pq_mfma<<<gemm_blocks, 512, 0, stream>>>(Bb, Wm1ah, Wm1al, Wm1bh, Wm1bl,
                                                    Pb, Qb, N_NODES, RT);

    // ---- fused edge MLP on MFMA, CSR order, bf16 gathers, 2-term ----
    k_edge_mlp_mfma<<<N_EDGES / 128, 512, 0, stream>>>(csr_pack, Pb, Qb, bm1,
                                                       Wm2h, Wm2l, bm2, Wm3, bm3, outp);
}

// Round 16
// 412.258 us; speedup vs baseline: 1.4868x; 1.0160x over previous
//
#include <hip/hip_runtime.h>
#include <hip/hip_bf16.h>
#include <math.h>

#define N_NODES 100000
#define N_EDGES 800000

typedef float f32x4 __attribute__((ext_vector_type(4)));
typedef short bf16x8 __attribute__((ext_vector_type(8)));

__device__ inline unsigned short bf16_of(float f) {
    union { __hip_bfloat16 b; unsigned short u; } cv;
    cv.b = __float2bfloat16(f);
    return cv.u;
}
__device__ inline float f32_of(unsigned short u) {
    union { __hip_bfloat16 b; unsigned short u; } cv;
    cv.u = u;
    return __bfloat162float(cv.b);
}

// ================= degree / CSR build =================
__global__ void k_zero_deg(int* __restrict__ deg) {
    int i = blockIdx.x * blockDim.x + threadIdx.x;
    if (i < N_NODES) deg[i] = 0;
}

__global__ void k_hist(const int* __restrict__ edst, int* __restrict__ deg) {
    int e = blockIdx.x * blockDim.x + threadIdx.x;
    if (e < N_EDGES) atomicAdd(&deg[edst[e]], 1);
}

// exclusive scan + dinv fused, 256/block
__global__ void k_scan1(const int* __restrict__ deg, int* __restrict__ off,
                        int* __restrict__ bsum, float* __restrict__ dinv, int n) {
    __shared__ int s[256];
    int t = threadIdx.x;
    int i = blockIdx.x * 256 + t;
    int v = (i < n) ? deg[i] : 0;
    if (i < n) dinv[i] = rsqrtf((float)(v + 1));   // +1 self-loop
    s[t] = v;
    __syncthreads();
    #pragma unroll
    for (int d = 1; d < 256; d <<= 1) {
        int x = (t >= d) ? s[t - d] : 0;
        __syncthreads();
        s[t] += x;
        __syncthreads();
    }
    if (i < n) off[i] = s[t] - v;            // exclusive within block
    if (t == 255) bsum[blockIdx.x] = s[255];
}

__global__ void k_scan2(int* __restrict__ bsum, int nb) {
    __shared__ int s[512];
    int t = threadIdx.x;
    int v = (t < nb) ? bsum[t] : 0;
    s[t] = v;
    __syncthreads();
    #pragma unroll
    for (int d = 1; d < 512; d <<= 1) {
        int x = (t >= d) ? s[t - d] : 0;
        __syncthreads();
        s[t] += x;
        __syncthreads();
    }
    if (t < nb) bsum[t] = s[t] - v;          // exclusive block offsets
}

__global__ void k_scan3(int* __restrict__ off, const int* __restrict__ bsum,
                        int* __restrict__ cur, int n) {
    int i = blockIdx.x * blockDim.x + threadIdx.x;
    if (i < n) {
        int o = off[i] + bsum[i >> 8];
        off[i] = o;
        cur[i] = o;
    }
    if (i == n) off[n] = N_EDGES;
}

// scatter edges into dst-grouped CSR: ONE packed int4 {src, dst, w_bits, eid} per edge
__global__ void k_scatter(const int* __restrict__ esrc, const int* __restrict__ edst,
                          const float* __restrict__ dinv,
                          int* __restrict__ cur, int4* __restrict__ csr_pack) {
    int e = blockIdx.x * blockDim.x + threadIdx.x;
    if (e >= N_EDGES) return;
    int s = esrc[e], d = edst[e];
    int pos = atomicAdd(&cur[d], 1);
    float w = dinv[s] * dinv[d];
    csr_pack[pos] = make_int4(s, d, __float_as_int(w), e);
}

// ================= bf16 hi/lo split of 5 x (128x128) W into MFMA fragment layout ====
// frag index for (k, c): lane = ((k>>3)&3)*16 + (c&15), elem = k&7, tile = (k>>5)*8 + (c>>4)
struct SplitArgs {
    const float* W[5];
    unsigned short* Wh[5];
    unsigned short* Wl[5];
};
__global__ void k_split_all(SplitArgs a) {
    int which = blockIdx.x >> 6;                    // 64 blocks per matrix
    int idx = (blockIdx.x & 63) * 256 + threadIdx.x;
    if (idx >= 128 * 128) return;
    int k = idx >> 7, c = idx & 127;
    float wv = a.W[which][idx];
    unsigned short h = bf16_of(wv);
    unsigned short lo = bf16_of(wv - f32_of(h));
    int fi = (((k >> 5) * 8 + (c >> 4)) * 64 + (((k >> 3) & 3) * 16 + (c & 15))) * 8 + (k & 7);
    a.Wh[which][fi] = h;
    a.Wl[which][fi] = lo;
}

// ================= MFMA node GEMM (f32 input, 3-term): out_bf16 = in @ W ==============
__global__ __launch_bounds__(512) void k_gemm_mfma_f32(
    const float* __restrict__ in,
    const unsigned short* __restrict__ Whf, const unsigned short* __restrict__ Wlf,
    unsigned short* __restrict__ outp, int nrows, int rtiles)
{
    __shared__ __align__(16) unsigned short sWh[16384];
    __shared__ __align__(16) unsigned short sWl[16384];
    const int t = threadIdx.x;

    #pragma unroll
    for (int i = 0; i < 4; ++i) {
        ((float4*)sWh)[t + 512 * i] = ((const float4*)Whf)[t + 512 * i];
        ((float4*)sWl)[t + 512 * i] = ((const float4*)Wlf)[t + 512 * i];
    }
    __syncthreads();

    const int w = t >> 6, l = t & 63;
    const int lr = l & 15, lk = l >> 4;

    for (int r = 0; r < rtiles; ++r) {
        const int row0 = (blockIdx.x * rtiles + r) * 128;
        int arow = row0 + w * 16 + lr;
        if (arow >= nrows) arow = nrows - 1;
        const float* inrow = in + (size_t)arow * 128 + lk * 8;

        bf16x8 ah[4], al[4];
        #pragma unroll
        for (int ks = 0; ks < 4; ++ks) {
            float4 p0 = *(const float4*)(inrow + ks * 32);
            float4 p1 = *(const float4*)(inrow + ks * 32 + 4);
            float z[8] = {p0.x, p0.y, p0.z, p0.w, p1.x, p1.y, p1.z, p1.w};
            #pragma unroll
            for (int e = 0; e < 8; ++e) {
                unsigned short hu = bf16_of(z[e]);
                ah[ks][e] = (short)hu;
                al[ks][e] = (short)bf16_of(z[e] - f32_of(hu));
            }
        }

        f32x4 acc[8];
        #pragma unroll
        for (int ct = 0; ct < 8; ++ct) { f32x4 zz = {0.f, 0.f, 0.f, 0.f}; acc[ct] = zz; }

        #pragma unroll
        for (int ct = 0; ct < 8; ++ct) {
            #pragma unroll
            for (int ks = 0; ks < 4; ++ks) {
                const bf16x8 bh = *(const bf16x8*)(sWh + ((ks * 8 + ct) * 64 + l) * 8);
                const bf16x8 bl = *(const bf16x8*)(sWl + ((ks * 8 + ct) * 64 + l) * 8);
                acc[ct] = __builtin_amdgcn_mfma_f32_16x16x32_bf16(ah[ks], bh, acc[ct], 0, 0, 0);
                acc[ct] = __builtin_amdgcn_mfma_f32_16x16x32_bf16(ah[ks], bl, acc[ct], 0, 0, 0);
                acc[ct] = __builtin_amdgcn_mfma_f32_16x16x32_bf16(al[ks], bh, acc[ct], 0, 0, 0);
            }
        }

        #pragma unroll
        for (int j = 0; j < 4; ++j) {
            int m = row0 + w * 16 + lk * 4 + j;
            if (m < nrows) {
                #pragma unroll
                for (int ct = 0; ct < 8; ++ct)
                    outp[(size_t)m * 128 + ct * 16 + lr] = bf16_of(acc[ct][j]);
            }
        }
    }
}

// ================= MFMA node GEMM (bf16 input + relu, 2-term): out_bf16 = relu(in)@W ===
__global__ __launch_bounds__(512) void k_gemm_mfma_bf16(
    const unsigned short* __restrict__ in,
    const unsigned short* __restrict__ Whf, const unsigned short* __restrict__ Wlf,
    unsigned short* __restrict__ outp, int nrows, int rtiles)
{
    __shared__ __align__(16) unsigned short sWh[16384];
    __shared__ __align__(16) unsigned short sWl[16384];
    const int t = threadIdx.x;

    #pragma unroll
    for (int i = 0; i < 4; ++i) {
        ((float4*)sWh)[t + 512 * i] = ((const float4*)Whf)[t + 512 * i];
        ((float4*)sWl)[t + 512 * i] = ((const float4*)Wlf)[t + 512 * i];
    }
    __syncthreads();

    const int w = t >> 6, l = t & 63;
    const int lr = l & 15, lk = l >> 4;

    for (int r = 0; r < rtiles; ++r) {
        const int row0 = (blockIdx.x * rtiles + r) * 128;
        int arow = row0 + w * 16 + lr;
        if (arow >= nrows) arow = nrows - 1;
        const unsigned short* inrow = in + (size_t)arow * 128 + lk * 8;

        bf16x8 ah[4];
        #pragma unroll
        for (int ks = 0; ks < 4; ++ks) {
            bf16x8 v = *(const bf16x8*)(inrow + ks * 32);
            #pragma unroll
            for (int e = 0; e < 8; ++e) {
                unsigned short u = (unsigned short)v[e];
                ah[ks][e] = (short)((u & 0x8000) ? 0 : u);   // relu on bf16 bits
            }
        }

        f32x4 acc[8];
        #pragma unroll
        for (int ct = 0; ct < 8; ++ct) { f32x4 zz = {0.f, 0.f, 0.f, 0.f}; acc[ct] = zz; }

        #pragma unroll
        for (int ct = 0; ct < 8; ++ct) {
            #pragma unroll
            for (int ks = 0; ks < 4; ++ks) {
                const bf16x8 bh = *(const bf16x8*)(sWh + ((ks * 8 + ct) * 64 + l) * 8);
                const bf16x8 bl = *(const bf16x8*)(sWl + ((ks * 8 + ct) * 64 + l) * 8);
                acc[ct] = __builtin_amdgcn_mfma_f32_16x16x32_bf16(ah[ks], bh, acc[ct], 0, 0, 0);
                acc[ct] = __builtin_amdgcn_mfma_f32_16x16x32_bf16(ah[ks], bl, acc[ct], 0, 0, 0);
            }
        }

        #pragma unroll
        for (int j = 0; j < 4; ++j) {
            int m = row0 + w * 16 + lk * 4 + j;
            if (m < nrows) {
                #pragma unroll
                for (int ct = 0; ct < 8; ++ct)
                    outp[(size_t)m * 128 + ct * 16 + lr] = bf16_of(acc[ct][j]);
            }
        }
    }
}

// ================= MFMA P/Q GEMM (bf16 input + relu, 2-term) -> bf16 P,Q ==============
__global__ __launch_bounds__(512) void k_gemm_pq_mfma(
    const unsigned short* __restrict__ in,
    const unsigned short* __restrict__ Wh0, const unsigned short* __restrict__ Wl0,
    const unsigned short* __restrict__ Wh1, const unsigned short* __restrict__ Wl1,
    unsigned short* __restrict__ P, unsigned short* __restrict__ Q, int nrows, int rtiles)
{
    __shared__ __align__(16) unsigned short sWh[16384];
    __shared__ __align__(16) unsigned short sWl[16384];
    const int t = threadIdx.x;
    const int w = t >> 6, l = t & 63;
    const int lr = l & 15, lk = l >> 4;

    #pragma unroll
    for (int half = 0; half < 2; ++half) {
        const unsigned short* Whf = half ? Wh1 : Wh0;
        const unsigned short* Wlf = half ? Wl1 : Wl0;
        unsigned short* outp = half ? Q : P;
        if (half) __syncthreads();
        #pragma unroll
        for (int i = 0; i < 4; ++i) {
            ((float4*)sWh)[t + 512 * i] = ((const float4*)Whf)[t + 512 * i];
            ((float4*)sWl)[t + 512 * i] = ((const float4*)Wlf)[t + 512 * i];
        }
        __syncthreads();

        for (int r = 0; r < rtiles; ++r) {
            const int row0 = (blockIdx.x * rtiles + r) * 128;
            int arow = row0 + w * 16 + lr;
            if (arow >= nrows) arow = nrows - 1;
            const unsigned short* inrow = in + (size_t)arow * 128 + lk * 8;

            bf16x8 ah[4];
            #pragma unroll
            for (int ks = 0; ks < 4; ++ks) {
                bf16x8 v = *(const bf16x8*)(inrow + ks * 32);
                #pragma unroll
                for (int e = 0; e < 8; ++e) {
                    unsigned short u = (unsigned short)v[e];
                    ah[ks][e] = (short)((u & 0x8000) ? 0 : u);
                }
            }

            f32x4 acc[8];
            #pragma unroll
            for (int ct = 0; ct < 8; ++ct) { f32x4 zz = {0.f, 0.f, 0.f, 0.f}; acc[ct] = zz; }

            #pragma unroll
            for (int ct = 0; ct < 8; ++ct) {
                #pragma unroll
                for (int ks = 0; ks < 4; ++ks) {
                    const bf16x8 bh = *(const bf16x8*)(sWh + ((ks * 8 + ct) * 64 + l) * 8);
                    const bf16x8 bl = *(const bf16x8*)(sWl + ((ks * 8 + ct) * 64 + l) * 8);
                    acc[ct] = __builtin_amdgcn_mfma_f32_16x16x32_bf16(ah[ks], bh, acc[ct], 0, 0, 0);
                    acc[ct] = __builtin_amdgcn_mfma_f32_16x16x32_bf16(ah[ks], bl, acc[ct], 0, 0, 0);
                }
            }

            #pragma unroll
            for (int j = 0; j < 4; ++j) {
                int m = row0 + w * 16 + lk * 4 + j;
                if (m < nrows) {
                    #pragma unroll
                    for (int ct = 0; ct < 8; ++ct)
                        outp[(size_t)m * 128 + ct * 16 + lr] = bf16_of(acc[ct][j]);
                }
            }
        }
    }
}

// ================= CSR aggregation (bf16 in, bf16 out, f32 accumulate) =================
__global__ __launch_bounds__(256) void k_agg_csr(
    const unsigned short* __restrict__ raw, const float* __restrict__ dinv,
    const int* __restrict__ off, const int4* __restrict__ csr_pack,
    const float* __restrict__ bias, unsigned short* __restrict__ outp)
{
    const int t = threadIdx.x;
    const int node = blockIdx.x * 8 + (t >> 5);
    const int lane = t & 31;
    if (node >= N_NODES) return;

    float di = dinv[node];
    float w0 = di * di;
    float4 acc = ((const float4*)bias)[lane];
    {
        ushort4 v = ((const ushort4*)raw)[(size_t)node * 32 + lane];
        acc.x += w0 * f32_of(v.x); acc.y += w0 * f32_of(v.y);
        acc.z += w0 * f32_of(v.z); acc.w += w0 * f32_of(v.w);
    }

    const int beg = off[node], end = off[node + 1];
    for (int base = beg; base < end; base += 32) {
        int cnt = end - base;
        if (cnt > 32) cnt = 32;
        int sj = 0;
        float wj = 0.f;
        if (lane < cnt) {
            int4 p = csr_pack[base + lane];
            sj = p.x;
            wj = __int_as_float(p.z);
        }
        for (int j = 0; j < cnt; ++j) {
            int s = __shfl(sj, j, 32);
            float w = __shfl(wj, j, 32);
            ushort4 u = ((const ushort4*)raw)[(size_t)s * 32 + lane];
            acc.x += w * f32_of(u.x); acc.y += w * f32_of(u.y);
            acc.z += w * f32_of(u.z); acc.w += w * f32_of(u.w);
        }
    }
    ushort4 o;
    o.x = bf16_of(acc.x); o.y = bf16_of(acc.y);
    o.z = bf16_of(acc.z); o.w = bf16_of(acc.w);
    ((ushort4*)outp)[(size_t)node * 32 + lane] = o;
}

// ================= fused edge MLP (MFMA 2-term, CSR order, phase-split weights) ========
// Weight LDS halved to 32 KB by processing ct-tiles in 2 phases of 4 (stage 16 h +
// 16 l fragment tiles per phase) -> 4 blocks/CU = 32 waves/CU for gather latency hiding.
__global__ __launch_bounds__(512) void k_edge_mlp_mfma(
    const int4* __restrict__ csr_pack,
    const unsigned short* __restrict__ P, const unsigned short* __restrict__ Q,
    const float* __restrict__ bm1,
    const unsigned short* __restrict__ Whf, const unsigned short* __restrict__ Wlf,
    const float* __restrict__ bm2,
    const float* __restrict__ Wm3, const float* __restrict__ bm3,
    float* __restrict__ outp)
{
    __shared__ __align__(16) unsigned short sW[16384];   // 32 KB: [0,8192)=h, [8192,16384)=l
    __shared__ int sIdx[3][128];

    const int t = threadIdx.x;
    const int e0 = blockIdx.x * 128;

    if (t < 128) {
        int4 p = csr_pack[e0 + t];
        sIdx[0][t] = p.x;
        sIdx[1][t] = p.y;
        sIdx[2][t] = p.w;
    }
    __syncthreads();

    const int w = t >> 6;          // wave id 0..7: rows w*16 .. w*16+15
    const int l = t & 63;
    const int lr = l & 15;         // A row within tile / D col
    const int lk = l >> 4;         // k-block
    const int row = w * 16 + lr;
    const int s = sIdx[0][row], d = sIdx[1][row];
    const unsigned short* prow = P + (size_t)s * 128 + lk * 8;
    const unsigned short* qrow = Q + (size_t)d * 128 + lk * 8;
    const float* brow = bm1 + lk * 8;

    // build A-fragments z1 = bf16(relu(P+Q+bm1)) in registers (gathers overlap staging)
    bf16x8 ah[4];
    #pragma unroll
    for (int ks = 0; ks < 4; ++ks) {
        bf16x8 pv = *(const bf16x8*)(prow + ks * 32);
        bf16x8 qv = *(const bf16x8*)(qrow + ks * 32);
        float4 b0 = *(const float4*)(brow + ks * 32);
        float4 b1 = *(const float4*)(brow + ks * 32 + 4);
        float bb[8] = {b0.x, b0.y, b0.z, b0.w, b1.x, b1.y, b1.z, b1.w};
        #pragma unroll
        for (int e = 0; e < 8; ++e) {
            float zv = fmaxf(f32_of((unsigned short)pv[e]) +
                             f32_of((unsigned short)qv[e]) + bb[e], 0.f);
            ah[ks][e] = (short)bf16_of(zv);
        }
    }

    f32x4 acc[8];
    #pragma unroll
    for (int ct = 0; ct < 8; ++ct) {
        float bv = bm2[ct * 16 + lr];
        f32x4 a = {bv, bv, bv, bv};
        acc[ct] = a;
    }

    // two phases: ct in [0,4) then [4,8); each stages 16 h-tiles + 16 l-tiles (32 KB)
    #pragma unroll
    for (int ph = 0; ph < 2; ++ph) {
        if (ph) __syncthreads();       // all waves done reading phase-0 weights
        #pragma unroll
        for (int i = 0; i < 2; ++i) {
            int li = t + 512 * i;      // [0,1024) float4 per half
            int tl = li >> 6, off = li & 63;
            int gtile = (tl >> 2) * 8 + ph * 4 + (tl & 3);   // tl = ks*4 + ctl
            ((float4*)sW)[li] = ((const float4*)Whf)[gtile * 64 + off];
            ((float4*)(sW + 8192))[li] = ((const float4*)Wlf)[gtile * 64 + off];
        }
        __syncthreads();
        #pragma unroll
        for (int ct4 = 0; ct4 < 4; ++ct4) {
            int ct = ph * 4 + ct4;
            #pragma unroll
            for (int ks = 0; ks < 4; ++ks) {
                int tl = ks * 4 + ct4;
                const bf16x8 bh = *(const bf16x8*)(sW + (tl * 64 + l) * 8);
                const bf16x8 bl = *(const bf16x8*)(sW + 8192 + (tl * 64 + l) * 8);
                acc[ct] = __builtin_amdgcn_mfma_f32_16x16x32_bf16(ah[ks], bh, acc[ct], 0, 0, 0);
                acc[ct] = __builtin_amdgcn_mfma_f32_16x16x32_bf16(ah[ks], bl, acc[ct], 0, 0, 0);
            }
        }
    }

    // out = sigmoid(relu(C) @ Wm3 + bm3); D layout: col = lr, row = lk*4 + reg
    float w3v[8];
    #pragma unroll
    for (int ct = 0; ct < 8; ++ct) w3v[ct] = Wm3[ct * 16 + lr];
    float b3 = bm3[0];
    #pragma unroll
    for (int j = 0; j < 4; ++j) {
        float pj = 0.f;
        #pragma unroll
        for (int ct = 0; ct < 8; ++ct) pj += fmaxf(acc[ct][j], 0.f) * w3v[ct];
        pj += __shfl_xor(pj, 1);
        pj += __shfl_xor(pj, 2);
        pj += __shfl_xor(pj, 4);
        pj += __shfl_xor(pj, 8);
        if (lr == 0)
            outp[sIdx[2][w * 16 + lk * 4 + j]] = 1.f / (1.f + expf(-(pj + b3)));
    }
}

// ================= launch =================
extern "C" void kernel_launch(void* const* d_in, const int* in_sizes, int n_in,
                              void* d_out, int out_size, void* d_ws, size_t ws_size,
                              hipStream_t stream) {
    const float* x   = (const float*)d_in[0];
    const int*   ei  = (const int*)d_in[1];
    const float* W1  = (const float*)d_in[2];
    const float* b1  = (const float*)d_in[3];
    const float* W2  = (const float*)d_in[4];
    const float* b2  = (const float*)d_in[5];
    const float* Wm1 = (const float*)d_in[6];
    const float* bm1 = (const float*)d_in[7];
    const float* Wm2 = (const float*)d_in[8];
    const float* bm2 = (const float*)d_in[9];
    const float* Wm3 = (const float*)d_in[10];
    const float* bm3 = (const float*)d_in[11];
    const int* esrc = ei;
    const int* edst = ei + N_EDGES;
    float* outp = (float*)d_out;

    // workspace layout
    float* ws = (float*)d_ws;
    float* dinv = ws;                                   // 100096 floats
    float* A = ws + 100096;                             // N*128 f32 region
    float* B = A + (size_t)N_NODES * 128;               // N*128 f32 region
    int* deg     = (int*)(B + (size_t)N_NODES * 128);   // N
    int* off     = deg + N_NODES;                       // N+1
    int* cur     = off + N_NODES + 1;                   // N
    int* bsum    = cur + N_NODES;                       // 512
    // align to 16 B for int4
    size_t ioff = (size_t)(bsum + 512 - (int*)d_ws);
    ioff = (ioff + 3) & ~(size_t)3;
    int4* csr_pack = (int4*)((int*)d_ws + ioff);        // E int4
    unsigned short* frag = (unsigned short*)(csr_pack + N_EDGES);
    unsigned short* W1h   = frag;                 unsigned short* W1l   = frag + 16384;
    unsigned short* W2h   = frag + 2 * 16384;     unsigned short* W2l   = frag + 3 * 16384;
    unsigned short* Wm1ah = frag + 4 * 16384;     unsigned short* Wm1al = frag + 5 * 16384;
    unsigned short* Wm1bh = frag + 6 * 16384;     unsigned short* Wm1bl = frag + 7 * 16384;
    unsigned short* Wm2h  = frag + 8 * 16384;     unsigned short* Wm2l  = frag + 9 * 16384;
    // bf16 views: Ab (GEMM out / agg in) in A region; Bb (agg out / GEMM in) in B region;
    // Pb/Qb reuse A region for the edge phase (A dead after layer-2 agg).
    unsigned short* Ab = (unsigned short*)A;
    unsigned short* Bb = (unsigned short*)B;
    unsigned short* Pb = (unsigned short*)A;
    unsigned short* Qb = (unsigned short*)A + (size_t)N_NODES * 128;

    const int nb = (N_NODES + 255) / 256;               // 391 scan blocks

    // ---- CSR build + W splits ----
    k_zero_deg<<<nb, 256, 0, stream>>>(deg);
    k_hist<<<(N_EDGES + 255) / 256, 256, 0, stream>>>(edst, deg);
    k_scan1<<<nb, 256, 0, stream>>>(deg, off, bsum, dinv, N_NODES);
    k_scan2<<<1, 512, 0, stream>>>(bsum, nb);
    k_scan3<<<(N_NODES + 256) / 256, 256, 0, stream>>>(off, bsum, cur, N_NODES);
    k_scatter<<<(N_EDGES + 255) / 256, 256, 0, stream>>>(esrc, edst, dinv, cur, csr_pack);

    SplitArgs sa;
    sa.W[0] = W1;  sa.Wh[0] = W1h;   sa.Wl[0] = W1l;
    sa.W[1] = W2;  sa.Wh[1] = W2h;   sa.Wl[1] = W2l;
    sa.W[2] = Wm1; sa.Wh[2] = Wm1ah; sa.Wl[2] = Wm1al;
    sa.W[3] = Wm1 + 128 * 128; sa.Wh[3] = Wm1bh; sa.Wl[3] = Wm1bl;
    sa.W[4] = Wm2; sa.Wh[4] = Wm2h;  sa.Wl[4] = Wm2l;
    k_split_all<<<5 * 64, 256, 0, stream>>>(sa);

    const int RT = 4;                                   // row tiles per block (128 rows each)
    const int gemm_blocks = (N_NODES + 128 * RT - 1) / (128 * RT);   // 196
    const int agg_blocks = (N_NODES + 7) / 8;

    // ---- layer 1: Ab = bf16(x @ W1) ; Bb = bf16(b1 + norm-agg(Ab)) ----
    k_gemm_mfma_f32<<<gemm_blocks, 512, 0, stream>>>(x, W1h, W1l, Ab, N_NODES, RT);
    k_agg_csr<<<agg_blocks, 256, 0, stream>>>(Ab, dinv, off, csr_pack, b1, Bb);

    // ---- layer 2: Ab = bf16(relu(Bb) @ W2) ; Bb = bf16(b2 + norm-agg(Ab)) ----
    k_gemm_mfma_bf16<<<gemm_blocks, 512, 0, stream>>>(Bb, W2h, W2l, Ab, N_NODES, RT);
    k_agg_csr<<<agg_blocks, 256, 0, stream>>>(Ab, dinv, off, csr_pack, b2, Bb);

    // ---- edge-MLP layer-1 decomposition: Pb/Qb (bf16) from relu(Bb) ----
    k_gemm_pq_mfma<<<gemm_blocks, 512, 0, stream>>>(Bb, Wm1ah, Wm1al, Wm1bh, Wm1bl,
                                                    Pb, Qb, N_NODES, RT);

    // ---- fused edge MLP on MFMA, CSR order, phase-split weight LDS ----
    k_edge_mlp_mfma<<<N_EDGES / 128, 512, 0, stream>>>(csr_pack, Pb, Qb, bm1,
                                                       Wm2h, Wm2l, bm2, Wm3, bm3, outp);
}

// Round 17
// 373.734 us; speedup vs baseline: 1.6400x; 1.1031x over previous
//
#include <hip/hip_runtime.h>
#include <hip/hip_bf16.h>
#include <math.h>

#define N_NODES 100000
#define N_EDGES 800000

typedef float f32x4 __attribute__((ext_vector_type(4)));
typedef short bf16x8 __attribute__((ext_vector_type(8)));

__device__ inline unsigned short bf16_of(float f) {
    union { __hip_bfloat16 b; unsigned short u; } cv;
    cv.b = __float2bfloat16(f);
    return cv.u;
}
__device__ inline float f32_of(unsigned short u) {
    union { __hip_bfloat16 b; unsigned short u; } cv;
    cv.u = u;
    return __bfloat162float(cv.b);
}

// ================= degree / CSR build =================
__global__ void k_zero_deg(int* __restrict__ deg) {
    int i = blockIdx.x * blockDim.x + threadIdx.x;
    if (i < N_NODES) deg[i] = 0;
}

__global__ void k_hist(const int* __restrict__ edst, int* __restrict__ deg) {
    int e = blockIdx.x * blockDim.x + threadIdx.x;
    if (e < N_EDGES) atomicAdd(&deg[edst[e]], 1);
}

// exclusive scan + dinv fused, 256/block
__global__ void k_scan1(const int* __restrict__ deg, int* __restrict__ off,
                        int* __restrict__ bsum, float* __restrict__ dinv, int n) {
    __shared__ int s[256];
    int t = threadIdx.x;
    int i = blockIdx.x * 256 + t;
    int v = (i < n) ? deg[i] : 0;
    if (i < n) dinv[i] = rsqrtf((float)(v + 1));   // +1 self-loop
    s[t] = v;
    __syncthreads();
    #pragma unroll
    for (int d = 1; d < 256; d <<= 1) {
        int x = (t >= d) ? s[t - d] : 0;
        __syncthreads();
        s[t] += x;
        __syncthreads();
    }
    if (i < n) off[i] = s[t] - v;            // exclusive within block
    if (t == 255) bsum[blockIdx.x] = s[255];
}

__global__ void k_scan2(int* __restrict__ bsum, int nb) {
    __shared__ int s[512];
    int t = threadIdx.x;
    int v = (t < nb) ? bsum[t] : 0;
    s[t] = v;
    __syncthreads();
    #pragma unroll
    for (int d = 1; d < 512; d <<= 1) {
        int x = (t >= d) ? s[t - d] : 0;
        __syncthreads();
        s[t] += x;
        __syncthreads();
    }
    if (t < nb) bsum[t] = s[t] - v;          // exclusive block offsets
}

__global__ void k_scan3(int* __restrict__ off, const int* __restrict__ bsum,
                        int* __restrict__ cur, int n) {
    int i = blockIdx.x * blockDim.x + threadIdx.x;
    if (i < n) {
        int o = off[i] + bsum[i >> 8];
        off[i] = o;
        cur[i] = o;
    }
    if (i == n) off[n] = N_EDGES;
}

// scatter edges into dst-grouped CSR: ONE packed int4 {src, dst, w_bits, eid} per edge
__global__ void k_scatter(const int* __restrict__ esrc, const int* __restrict__ edst,
                          const float* __restrict__ dinv,
                          int* __restrict__ cur, int4* __restrict__ csr_pack) {
    int e = blockIdx.x * blockDim.x + threadIdx.x;
    if (e >= N_EDGES) return;
    int s = esrc[e], d = edst[e];
    int pos = atomicAdd(&cur[d], 1);
    float w = dinv[s] * dinv[d];
    csr_pack[pos] = make_int4(s, d, __float_as_int(w), e);
}

// ================= bf16 hi/lo split of 5 x (128x128) W into MFMA fragment layout ====
// frag index for (k, c): lane = ((k>>3)&3)*16 + (c&15), elem = k&7, tile = (k>>5)*8 + (c>>4)
struct SplitArgs {
    const float* W[5];
    unsigned short* Wh[5];
    unsigned short* Wl[5];
};
__global__ void k_split_all(SplitArgs a) {
    int which = blockIdx.x >> 6;                    // 64 blocks per matrix
    int idx = (blockIdx.x & 63) * 256 + threadIdx.x;
    if (idx >= 128 * 128) return;
    int k = idx >> 7, c = idx & 127;
    float wv = a.W[which][idx];
    unsigned short h = bf16_of(wv);
    unsigned short lo = bf16_of(wv - f32_of(h));
    int fi = (((k >> 5) * 8 + (c >> 4)) * 64 + (((k >> 3) & 3) * 16 + (c & 15))) * 8 + (k & 7);
    a.Wh[which][fi] = h;
    a.Wl[which][fi] = lo;
}

// ================= MFMA node GEMM (f32 input, 3-term): out_bf16 = in @ W ==============
__global__ __launch_bounds__(512) void k_gemm_mfma_f32(
    const float* __restrict__ in,
    const unsigned short* __restrict__ Whf, const unsigned short* __restrict__ Wlf,
    unsigned short* __restrict__ outp, int nrows, int rtiles)
{
    __shared__ __align__(16) unsigned short sWh[16384];
    __shared__ __align__(16) unsigned short sWl[16384];
    const int t = threadIdx.x;

    #pragma unroll
    for (int i = 0; i < 4; ++i) {
        ((float4*)sWh)[t + 512 * i] = ((const float4*)Whf)[t + 512 * i];
        ((float4*)sWl)[t + 512 * i] = ((const float4*)Wlf)[t + 512 * i];
    }
    __syncthreads();

    const int w = t >> 6, l = t & 63;
    const int lr = l & 15, lk = l >> 4;

    for (int r = 0; r < rtiles; ++r) {
        const int row0 = (blockIdx.x * rtiles + r) * 128;
        int arow = row0 + w * 16 + lr;
        if (arow >= nrows) arow = nrows - 1;
        const float* inrow = in + (size_t)arow * 128 + lk * 8;

        bf16x8 ah[4], al[4];
        #pragma unroll
        for (int ks = 0; ks < 4; ++ks) {
            float4 p0 = *(const float4*)(inrow + ks * 32);
            float4 p1 = *(const float4*)(inrow + ks * 32 + 4);
            float z[8] = {p0.x, p0.y, p0.z, p0.w, p1.x, p1.y, p1.z, p1.w};
            #pragma unroll
            for (int e = 0; e < 8; ++e) {
                unsigned short hu = bf16_of(z[e]);
                ah[ks][e] = (short)hu;
                al[ks][e] = (short)bf16_of(z[e] - f32_of(hu));
            }
        }

        f32x4 acc[8];
        #pragma unroll
        for (int ct = 0; ct < 8; ++ct) { f32x4 zz = {0.f, 0.f, 0.f, 0.f}; acc[ct] = zz; }

        #pragma unroll
        for (int ct = 0; ct < 8; ++ct) {
            #pragma unroll
            for (int ks = 0; ks < 4; ++ks) {
                const bf16x8 bh = *(const bf16x8*)(sWh + ((ks * 8 + ct) * 64 + l) * 8);
                const bf16x8 bl = *(const bf16x8*)(sWl + ((ks * 8 + ct) * 64 + l) * 8);
                acc[ct] = __builtin_amdgcn_mfma_f32_16x16x32_bf16(ah[ks], bh, acc[ct], 0, 0, 0);
                acc[ct] = __builtin_amdgcn_mfma_f32_16x16x32_bf16(ah[ks], bl, acc[ct], 0, 0, 0);
                acc[ct] = __builtin_amdgcn_mfma_f32_16x16x32_bf16(al[ks], bh, acc[ct], 0, 0, 0);
            }
        }

        #pragma unroll
        for (int j = 0; j < 4; ++j) {
            int m = row0 + w * 16 + lk * 4 + j;
            if (m < nrows) {
                #pragma unroll
                for (int ct = 0; ct < 8; ++ct)
                    outp[(size_t)m * 128 + ct * 16 + lr] = bf16_of(acc[ct][j]);
            }
        }
    }
}

// ================= FUSED agg + GEMM: out = bf16( relu(bias + norm-agg(raw)) @ W ) ======
// Per thread: aggregate its 32 fragment elements in f32 registers (coalesced bf16 row
// gathers, record loads broadcast across the 4 lanes sharing a row), relu -> A-frags,
// then 2-term MFMA with LDS-staged weights. One 128-row tile per block.
__global__ __launch_bounds__(512) void k_fused_agg_gemm(
    const unsigned short* __restrict__ raw, const float* __restrict__ dinv,
    const int* __restrict__ off, const int4* __restrict__ csr_pack,
    const float* __restrict__ bias,
    const unsigned short* __restrict__ Whf, const unsigned short* __restrict__ Wlf,
    unsigned short* __restrict__ outp, int nrows)
{
    __shared__ __align__(16) unsigned short sWh[16384];
    __shared__ __align__(16) unsigned short sWl[16384];
    const int t = threadIdx.x;

    // issue weight staging first; agg gathers below overlap its latency
    #pragma unroll
    for (int i = 0; i < 4; ++i) {
        ((float4*)sWh)[t + 512 * i] = ((const float4*)Whf)[t + 512 * i];
        ((float4*)sWl)[t + 512 * i] = ((const float4*)Wlf)[t + 512 * i];
    }

    const int w = t >> 6, l = t & 63;
    const int lr = l & 15, lk = l >> 4;
    const int row0 = blockIdx.x * 128;
    int arow = row0 + w * 16 + lr;
    if (arow >= nrows) arow = nrows - 1;

    const unsigned short* self = raw + (size_t)arow * 128 + lk * 8;
    const float* brow = bias + lk * 8;
    float di = dinv[arow];
    float w0 = di * di;

    float facc[4][8];
    #pragma unroll
    for (int ks = 0; ks < 4; ++ks) {
        bf16x8 v = *(const bf16x8*)(self + ks * 32);
        float4 b0 = *(const float4*)(brow + ks * 32);
        float4 b1v = *(const float4*)(brow + ks * 32 + 4);
        float bb[8] = {b0.x, b0.y, b0.z, b0.w, b1v.x, b1v.y, b1v.z, b1v.w};
        #pragma unroll
        for (int e = 0; e < 8; ++e)
            facc[ks][e] = bb[e] + w0 * f32_of((unsigned short)v[e]);
    }

    const int beg = off[arow], end = off[arow + 1];
    for (int j = beg; j < end; ++j) {
        int4 p = csr_pack[j];                        // 4 lanes same addr -> broadcast
        float wg = __int_as_float(p.z);
        const unsigned short* nrow = raw + (size_t)p.x * 128 + lk * 8;
        #pragma unroll
        for (int ks = 0; ks < 4; ++ks) {
            bf16x8 u = *(const bf16x8*)(nrow + ks * 32);
            #pragma unroll
            for (int e = 0; e < 8; ++e)
                facc[ks][e] += wg * f32_of((unsigned short)u[e]);
        }
    }

    bf16x8 ah[4];
    #pragma unroll
    for (int ks = 0; ks < 4; ++ks)
        #pragma unroll
        for (int e = 0; e < 8; ++e)
            ah[ks][e] = (short)bf16_of(fmaxf(facc[ks][e], 0.f));

    __syncthreads();                                 // weights staged

    f32x4 acc[8];
    #pragma unroll
    for (int ct = 0; ct < 8; ++ct) { f32x4 zz = {0.f, 0.f, 0.f, 0.f}; acc[ct] = zz; }
    #pragma unroll
    for (int ct = 0; ct < 8; ++ct) {
        #pragma unroll
        for (int ks = 0; ks < 4; ++ks) {
            const bf16x8 bh = *(const bf16x8*)(sWh + ((ks * 8 + ct) * 64 + l) * 8);
            const bf16x8 bl = *(const bf16x8*)(sWl + ((ks * 8 + ct) * 64 + l) * 8);
            acc[ct] = __builtin_amdgcn_mfma_f32_16x16x32_bf16(ah[ks], bh, acc[ct], 0, 0, 0);
            acc[ct] = __builtin_amdgcn_mfma_f32_16x16x32_bf16(ah[ks], bl, acc[ct], 0, 0, 0);
        }
    }

    #pragma unroll
    for (int j = 0; j < 4; ++j) {
        int m = row0 + w * 16 + lk * 4 + j;
        if (m < nrows) {
            #pragma unroll
            for (int ct = 0; ct < 8; ++ct)
                outp[(size_t)m * 128 + ct * 16 + lr] = bf16_of(acc[ct][j]);
        }
    }
}

// ================= FUSED agg + P/Q GEMMs: z=relu(bias+agg(raw)); P=z@Wa; Q=z@Wb ========
// agg once, two MFMA passes re-staging weights (64 KB each set).
__global__ __launch_bounds__(512) void k_fused_agg_pq(
    const unsigned short* __restrict__ raw, const float* __restrict__ dinv,
    const int* __restrict__ off, const int4* __restrict__ csr_pack,
    const float* __restrict__ bias,
    const unsigned short* __restrict__ Wh0, const unsigned short* __restrict__ Wl0,
    const unsigned short* __restrict__ Wh1, const unsigned short* __restrict__ Wl1,
    unsigned short* __restrict__ P, unsigned short* __restrict__ Q, int nrows)
{
    __shared__ __align__(16) unsigned short sWh[16384];
    __shared__ __align__(16) unsigned short sWl[16384];
    const int t = threadIdx.x;

    #pragma unroll
    for (int i = 0; i < 4; ++i) {
        ((float4*)sWh)[t + 512 * i] = ((const float4*)Wh0)[t + 512 * i];
        ((float4*)sWl)[t + 512 * i] = ((const float4*)Wl0)[t + 512 * i];
    }

    const int w = t >> 6, l = t & 63;
    const int lr = l & 15, lk = l >> 4;
    const int row0 = blockIdx.x * 128;
    int arow = row0 + w * 16 + lr;
    if (arow >= nrows) arow = nrows - 1;

    const unsigned short* self = raw + (size_t)arow * 128 + lk * 8;
    const float* brow = bias + lk * 8;
    float di = dinv[arow];
    float w0 = di * di;

    float facc[4][8];
    #pragma unroll
    for (int ks = 0; ks < 4; ++ks) {
        bf16x8 v = *(const bf16x8*)(self + ks * 32);
        float4 b0 = *(const float4*)(brow + ks * 32);
        float4 b1v = *(const float4*)(brow + ks * 32 + 4);
        float bb[8] = {b0.x, b0.y, b0.z, b0.w, b1v.x, b1v.y, b1v.z, b1v.w};
        #pragma unroll
        for (int e = 0; e < 8; ++e)
            facc[ks][e] = bb[e] + w0 * f32_of((unsigned short)v[e]);
    }

    const int beg = off[arow], end = off[arow + 1];
    for (int j = beg; j < end; ++j) {
        int4 p = csr_pack[j];
        float wg = __int_as_float(p.z);
        const unsigned short* nrow = raw + (size_t)p.x * 128 + lk * 8;
        #pragma unroll
        for (int ks = 0; ks < 4; ++ks) {
            bf16x8 u = *(const bf16x8*)(nrow + ks * 32);
            #pragma unroll
            for (int e = 0; e < 8; ++e)
                facc[ks][e] += wg * f32_of((unsigned short)u[e]);
        }
    }

    bf16x8 ah[4];
    #pragma unroll
    for (int ks = 0; ks < 4; ++ks)
        #pragma unroll
        for (int e = 0; e < 8; ++e)
            ah[ks][e] = (short)bf16_of(fmaxf(facc[ks][e], 0.f));

    __syncthreads();                                 // W0 staged

    {
        f32x4 acc[8];
        #pragma unroll
        for (int ct = 0; ct < 8; ++ct) { f32x4 zz = {0.f, 0.f, 0.f, 0.f}; acc[ct] = zz; }
        #pragma unroll
        for (int ct = 0; ct < 8; ++ct) {
            #pragma unroll
            for (int ks = 0; ks < 4; ++ks) {
                const bf16x8 bh = *(const bf16x8*)(sWh + ((ks * 8 + ct) * 64 + l) * 8);
                const bf16x8 bl = *(const bf16x8*)(sWl + ((ks * 8 + ct) * 64 + l) * 8);
                acc[ct] = __builtin_amdgcn_mfma_f32_16x16x32_bf16(ah[ks], bh, acc[ct], 0, 0, 0);
                acc[ct] = __builtin_amdgcn_mfma_f32_16x16x32_bf16(ah[ks], bl, acc[ct], 0, 0, 0);
            }
        }
        #pragma unroll
        for (int j = 0; j < 4; ++j) {
            int m = row0 + w * 16 + lk * 4 + j;
            if (m < nrows) {
                #pragma unroll
                for (int ct = 0; ct < 8; ++ct)
                    P[(size_t)m * 128 + ct * 16 + lr] = bf16_of(acc[ct][j]);
            }
        }
    }

    __syncthreads();                                 // all reads of W0 done
    #pragma unroll
    for (int i = 0; i < 4; ++i) {
        ((float4*)sWh)[t + 512 * i] = ((const float4*)Wh1)[t + 512 * i];
        ((float4*)sWl)[t + 512 * i] = ((const float4*)Wl1)[t + 512 * i];
    }
    __syncthreads();                                 // W1 staged

    {
        f32x4 acc[8];
        #pragma unroll
        for (int ct = 0; ct < 8; ++ct) { f32x4 zz = {0.f, 0.f, 0.f, 0.f}; acc[ct] = zz; }
        #pragma unroll
        for (int ct = 0; ct < 8; ++ct) {
            #pragma unroll
            for (int ks = 0; ks < 4; ++ks) {
                const bf16x8 bh = *(const bf16x8*)(sWh + ((ks * 8 + ct) * 64 + l) * 8);
                const bf16x8 bl = *(const bf16x8*)(sWl + ((ks * 8 + ct) * 64 + l) * 8);
                acc[ct] = __builtin_amdgcn_mfma_f32_16x16x32_bf16(ah[ks], bh, acc[ct], 0, 0, 0);
                acc[ct] = __builtin_amdgcn_mfma_f32_16x16x32_bf16(ah[ks], bl, acc[ct], 0, 0, 0);
            }
        }
        #pragma unroll
        for (int j = 0; j < 4; ++j) {
            int m = row0 + w * 16 + lk * 4 + j;
            if (m < nrows) {
                #pragma unroll
                for (int ct = 0; ct < 8; ++ct)
                    Q[(size_t)m * 128 + ct * 16 + lr] = bf16_of(acc[ct][j]);
            }
        }
    }
}

// ================= fused edge MLP (MFMA 2-term, CSR order, phase-split weights) ========
__global__ __launch_bounds__(512) void k_edge_mlp_mfma(
    const int4* __restrict__ csr_pack,
    const unsigned short* __restrict__ P, const unsigned short* __restrict__ Q,
    const float* __restrict__ bm1,
    const unsigned short* __restrict__ Whf, const unsigned short* __restrict__ Wlf,
    const float* __restrict__ bm2,
    const float* __restrict__ Wm3, const float* __restrict__ bm3,
    float* __restrict__ outp)
{
    __shared__ __align__(16) unsigned short sW[16384];   // 32 KB: [0,8192)=h, [8192,16384)=l
    __shared__ int sIdx[3][128];

    const int t = threadIdx.x;
    const int e0 = blockIdx.x * 128;

    if (t < 128) {
        int4 p = csr_pack[e0 + t];
        sIdx[0][t] = p.x;
        sIdx[1][t] = p.y;
        sIdx[2][t] = p.w;
    }
    __syncthreads();

    const int w = t >> 6;          // wave id 0..7: rows w*16 .. w*16+15
    const int l = t & 63;
    const int lr = l & 15;         // A row within tile / D col
    const int lk = l >> 4;         // k-block
    const int row = w * 16 + lr;
    const int s = sIdx[0][row], d = sIdx[1][row];
    const unsigned short* prow = P + (size_t)s * 128 + lk * 8;
    const unsigned short* qrow = Q + (size_t)d * 128 + lk * 8;
    const float* brow = bm1 + lk * 8;

    bf16x8 ah[4];
    #pragma unroll
    for (int ks = 0; ks < 4; ++ks) {
        bf16x8 pv = *(const bf16x8*)(prow + ks * 32);
        bf16x8 qv = *(const bf16x8*)(qrow + ks * 32);
        float4 b0 = *(const float4*)(brow + ks * 32);
        float4 b1 = *(const float4*)(brow + ks * 32 + 4);
        float bb[8] = {b0.x, b0.y, b0.z, b0.w, b1.x, b1.y, b1.z, b1.w};
        #pragma unroll
        for (int e = 0; e < 8; ++e) {
            float zv = fmaxf(f32_of((unsigned short)pv[e]) +
                             f32_of((unsigned short)qv[e]) + bb[e], 0.f);
            ah[ks][e] = (short)bf16_of(zv);
        }
    }

    f32x4 acc[8];
    #pragma unroll
    for (int ct = 0; ct < 8; ++ct) {
        float bv = bm2[ct * 16 + lr];
        f32x4 a = {bv, bv, bv, bv};
        acc[ct] = a;
    }

    // two phases: ct in [0,4) then [4,8); each stages 16 h-tiles + 16 l-tiles (32 KB)
    #pragma unroll
    for (int ph = 0; ph < 2; ++ph) {
        if (ph) __syncthreads();
        #pragma unroll
        for (int i = 0; i < 2; ++i) {
            int li = t + 512 * i;
            int tl = li >> 6, off = li & 63;
            int gtile = (tl >> 2) * 8 + ph * 4 + (tl & 3);
            ((float4*)sW)[li] = ((const float4*)Whf)[gtile * 64 + off];
            ((float4*)(sW + 8192))[li] = ((const float4*)Wlf)[gtile * 64 + off];
        }
        __syncthreads();
        #pragma unroll
        for (int ct4 = 0; ct4 < 4; ++ct4) {
            int ct = ph * 4 + ct4;
            #pragma unroll
            for (int ks = 0; ks < 4; ++ks) {
                int tl = ks * 4 + ct4;
                const bf16x8 bh = *(const bf16x8*)(sW + (tl * 64 + l) * 8);
                const bf16x8 bl = *(const bf16x8*)(sW + 8192 + (tl * 64 + l) * 8);
                acc[ct] = __builtin_amdgcn_mfma_f32_16x16x32_bf16(ah[ks], bh, acc[ct], 0, 0, 0);
                acc[ct] = __builtin_amdgcn_mfma_f32_16x16x32_bf16(ah[ks], bl, acc[ct], 0, 0, 0);
            }
        }
    }

    float w3v[8];
    #pragma unroll
    for (int ct = 0; ct < 8; ++ct) w3v[ct] = Wm3[ct * 16 + lr];
    float b3 = bm3[0];
    #pragma unroll
    for (int j = 0; j < 4; ++j) {
        float pj = 0.f;
        #pragma unroll
        for (int ct = 0; ct < 8; ++ct) pj += fmaxf(acc[ct][j], 0.f) * w3v[ct];
        pj += __shfl_xor(pj, 1);
        pj += __shfl_xor(pj, 2);
        pj += __shfl_xor(pj, 4);
        pj += __shfl_xor(pj, 8);
        if (lr == 0)
            outp[sIdx[2][w * 16 + lk * 4 + j]] = 1.f / (1.f + expf(-(pj + b3)));
    }
}

// ================= launch =================
extern "C" void kernel_launch(void* const* d_in, const int* in_sizes, int n_in,
                              void* d_out, int out_size, void* d_ws, size_t ws_size,
                              hipStream_t stream) {
    const float* x   = (const float*)d_in[0];
    const int*   ei  = (const int*)d_in[1];
    const float* W1  = (const float*)d_in[2];
    const float* b1  = (const float*)d_in[3];
    const float* W2  = (const float*)d_in[4];
    const float* b2  = (const float*)d_in[5];
    const float* Wm1 = (const float*)d_in[6];
    const float* bm1 = (const float*)d_in[7];
    const float* Wm2 = (const float*)d_in[8];
    const float* bm2 = (const float*)d_in[9];
    const float* Wm3 = (const float*)d_in[10];
    const float* bm3 = (const float*)d_in[11];
    const int* esrc = ei;
    const int* edst = ei + N_EDGES;
    float* outp = (float*)d_out;

    // workspace layout
    float* ws = (float*)d_ws;
    float* dinv = ws;                                   // 100096 floats
    float* A = ws + 100096;                             // N*128 f32 region
    float* B = A + (size_t)N_NODES * 128;               // N*128 f32 region
    int* deg     = (int*)(B + (size_t)N_NODES * 128);   // N
    int* off     = deg + N_NODES;                       // N+1
    int* cur     = off + N_NODES + 1;                   // N
    int* bsum    = cur + N_NODES;                       // 512
    // align to 16 B for int4
    size_t ioff = (size_t)(bsum + 512 - (int*)d_ws);
    ioff = (ioff + 3) & ~(size_t)3;
    int4* csr_pack = (int4*)((int*)d_ws + ioff);        // E int4
    unsigned short* frag = (unsigned short*)(csr_pack + N_EDGES);
    unsigned short* W1h   = frag;                 unsigned short* W1l   = frag + 16384;
    unsigned short* W2h   = frag + 2 * 16384;     unsigned short* W2l   = frag + 3 * 16384;
    unsigned short* Wm1ah = frag + 4 * 16384;     unsigned short* Wm1al = frag + 5 * 16384;
    unsigned short* Wm1bh = frag + 6 * 16384;     unsigned short* Wm1bl = frag + 7 * 16384;
    unsigned short* Wm2h  = frag + 8 * 16384;     unsigned short* Wm2l  = frag + 9 * 16384;
    // bf16 views: Ab = layer-1 product (region A); Cb = layer-2 product (region B);
    // Pb overwrites Ab (dead once fused_pq reads only Cb); Qb after Pb in region A.
    unsigned short* Ab = (unsigned short*)A;
    unsigned short* Cb = (unsigned short*)B;
    unsigned short* Pb = (unsigned short*)A;
    unsigned short* Qb = (unsigned short*)A + (size_t)N_NODES * 128;

    const int nb = (N_NODES + 255) / 256;               // 391 scan blocks

    // ---- CSR build + W splits ----
    k_zero_deg<<<nb, 256, 0, stream>>>(deg);
    k_hist<<<(N_EDGES + 255) / 256, 256, 0, stream>>>(edst, deg);
    k_scan1<<<nb, 256, 0, stream>>>(deg, off, bsum, dinv, N_NODES);
    k_scan2<<<1, 512, 0, stream>>>(bsum, nb);
    k_scan3<<<(N_NODES + 256) / 256, 256, 0, stream>>>(off, bsum, cur, N_NODES);
    k_scatter<<<(N_EDGES + 255) / 256, 256, 0, stream>>>(esrc, edst, dinv, cur, csr_pack);

    SplitArgs sa;
    sa.W[0] = W1;  sa.Wh[0] = W1h;   sa.Wl[0] = W1l;
    sa.W[1] = W2;  sa.Wh[1] = W2h;   sa.Wl[1] = W2l;
    sa.W[2] = Wm1; sa.Wh[2] = Wm1ah; sa.Wl[2] = Wm1al;
    sa.W[3] = Wm1 + 128 * 128; sa.Wh[3] = Wm1bh; sa.Wl[3] = Wm1bl;
    sa.W[4] = Wm2; sa.Wh[4] = Wm2h;  sa.Wl[4] = Wm2l;
    k_split_all<<<5 * 64, 256, 0, stream>>>(sa);

    const int RT = 4;
    const int gemm_blocks = (N_NODES + 128 * RT - 1) / (128 * RT);   // 196
    const int node_tiles = (N_NODES + 127) / 128;                    // 782

    // ---- layer 1 product: Ab = bf16(x @ W1) ----
    k_gemm_mfma_f32<<<gemm_blocks, 512, 0, stream>>>(x, W1h, W1l, Ab, N_NODES, RT);

    // ---- fused: Cb = bf16( relu(b1 + agg(Ab)) @ W2 ) ----
    k_fused_agg_gemm<<<node_tiles, 512, 0, stream>>>(Ab, dinv, off, csr_pack, b1,
                                                     W2h, W2l, Cb, N_NODES);

    // ---- fused: z2 = relu(b2 + agg(Cb)); Pb = z2@Wm1_top; Qb = z2@Wm1_bot ----
    k_fused_agg_pq<<<node_tiles, 512, 0, stream>>>(Cb, dinv, off, csr_pack, b2,
                                                   Wm1ah, Wm1al, Wm1bh, Wm1bl,
                                                   Pb, Qb, N_NODES);

    // ---- fused edge MLP on MFMA, CSR order, phase-split weight LDS ----
    k_edge_mlp_mfma<<<N_EDGES / 128, 512, 0, stream>>>(csr_pack, Pb, Qb, bm1,
                                                       Wm2h, Wm2l, bm2, Wm3, bm3, outp);
}

// Round 18
// 356.996 us; speedup vs baseline: 1.7169x; 1.0469x over previous
//
#include <hip/hip_runtime.h>
#include <hip/hip_bf16.h>
#include <math.h>

#define N_NODES 100000
#define N_EDGES 800000

typedef float f32x4 __attribute__((ext_vector_type(4)));
typedef short bf16x8 __attribute__((ext_vector_type(8)));

__device__ inline unsigned short bf16_of(float f) {
    union { __hip_bfloat16 b; unsigned short u; } cv;
    cv.b = __float2bfloat16(f);
    return cv.u;
}
__device__ inline float f32_of(unsigned short u) {
    union { __hip_bfloat16 b; unsigned short u; } cv;
    cv.u = u;
    return __bfloat162float(cv.b);
}

// ================= degree / CSR build =================
__global__ void k_zero_deg(int* __restrict__ deg) {
    int i = blockIdx.x * blockDim.x + threadIdx.x;
    if (i < N_NODES) deg[i] = 0;
}

__global__ void k_hist(const int* __restrict__ edst, int* __restrict__ deg) {
    int e = blockIdx.x * blockDim.x + threadIdx.x;
    if (e < N_EDGES) atomicAdd(&deg[edst[e]], 1);
}

// exclusive scan + dinv fused, 256/block
__global__ void k_scan1(const int* __restrict__ deg, int* __restrict__ off,
                        int* __restrict__ bsum, float* __restrict__ dinv, int n) {
    __shared__ int s[256];
    int t = threadIdx.x;
    int i = blockIdx.x * 256 + t;
    int v = (i < n) ? deg[i] : 0;
    if (i < n) dinv[i] = rsqrtf((float)(v + 1));   // +1 self-loop
    s[t] = v;
    __syncthreads();
    #pragma unroll
    for (int d = 1; d < 256; d <<= 1) {
        int x = (t >= d) ? s[t - d] : 0;
        __syncthreads();
        s[t] += x;
        __syncthreads();
    }
    if (i < n) off[i] = s[t] - v;            // exclusive within block
    if (t == 255) bsum[blockIdx.x] = s[255];
}

__global__ void k_scan2(int* __restrict__ bsum, int nb) {
    __shared__ int s[512];
    int t = threadIdx.x;
    int v = (t < nb) ? bsum[t] : 0;
    s[t] = v;
    __syncthreads();
    #pragma unroll
    for (int d = 1; d < 512; d <<= 1) {
        int x = (t >= d) ? s[t - d] : 0;
        __syncthreads();
        s[t] += x;
        __syncthreads();
    }
    if (t < nb) bsum[t] = s[t] - v;          // exclusive block offsets
}

__global__ void k_scan3(int* __restrict__ off, const int* __restrict__ bsum,
                        int* __restrict__ cur, int n) {
    int i = blockIdx.x * blockDim.x + threadIdx.x;
    if (i < n) {
        int o = off[i] + bsum[i >> 8];
        off[i] = o;
        cur[i] = o;
    }
    if (i == n) off[n] = N_EDGES;
}

// scatter edges into dst-grouped CSR: ONE packed int4 {src, dst, w_bits, eid} per edge
__global__ void k_scatter(const int* __restrict__ esrc, const int* __restrict__ edst,
                          const float* __restrict__ dinv,
                          int* __restrict__ cur, int4* __restrict__ csr_pack) {
    int e = blockIdx.x * blockDim.x + threadIdx.x;
    if (e >= N_EDGES) return;
    int s = esrc[e], d = edst[e];
    int pos = atomicAdd(&cur[d], 1);
    float w = dinv[s] * dinv[d];
    csr_pack[pos] = make_int4(s, d, __float_as_int(w), e);
}

// ================= bf16 hi/lo split of 5 x (128x128) W into MFMA fragment layout ====
// frag index for (k, c): lane = ((k>>3)&3)*16 + (c&15), elem = k&7, tile = (k>>5)*8 + (c>>4)
struct SplitArgs {
    const float* W[5];
    unsigned short* Wh[5];
    unsigned short* Wl[5];
};
__global__ void k_split_all(SplitArgs a) {
    int which = blockIdx.x >> 6;                    // 64 blocks per matrix
    int idx = (blockIdx.x & 63) * 256 + threadIdx.x;
    if (idx >= 128 * 128) return;
    int k = idx >> 7, c = idx & 127;
    float wv = a.W[which][idx];
    unsigned short h = bf16_of(wv);
    unsigned short lo = bf16_of(wv - f32_of(h));
    int fi = (((k >> 5) * 8 + (c >> 4)) * 64 + (((k >> 3) & 3) * 16 + (c & 15))) * 8 + (k & 7);
    a.Wh[which][fi] = h;
    a.Wl[which][fi] = lo;
}

// ================= MFMA node GEMM (f32 input, 3-term): out_bf16 = in @ W ==============
__global__ __launch_bounds__(512) void k_gemm_mfma_f32(
    const float* __restrict__ in,
    const unsigned short* __restrict__ Whf, const unsigned short* __restrict__ Wlf,
    unsigned short* __restrict__ outp, int nrows, int rtiles)
{
    __shared__ __align__(16) unsigned short sWh[16384];
    __shared__ __align__(16) unsigned short sWl[16384];
    const int t = threadIdx.x;

    #pragma unroll
    for (int i = 0; i < 4; ++i) {
        ((float4*)sWh)[t + 512 * i] = ((const float4*)Whf)[t + 512 * i];
        ((float4*)sWl)[t + 512 * i] = ((const float4*)Wlf)[t + 512 * i];
    }
    __syncthreads();

    const int w = t >> 6, l = t & 63;
    const int lr = l & 15, lk = l >> 4;

    for (int r = 0; r < rtiles; ++r) {
        const int row0 = (blockIdx.x * rtiles + r) * 128;
        int arow = row0 + w * 16 + lr;
        if (arow >= nrows) arow = nrows - 1;
        const float* inrow = in + (size_t)arow * 128 + lk * 8;

        bf16x8 ah[4], al[4];
        #pragma unroll
        for (int ks = 0; ks < 4; ++ks) {
            float4 p0 = *(const float4*)(inrow + ks * 32);
            float4 p1 = *(const float4*)(inrow + ks * 32 + 4);
            float z[8] = {p0.x, p0.y, p0.z, p0.w, p1.x, p1.y, p1.z, p1.w};
            #pragma unroll
            for (int e = 0; e < 8; ++e) {
                unsigned short hu = bf16_of(z[e]);
                ah[ks][e] = (short)hu;
                al[ks][e] = (short)bf16_of(z[e] - f32_of(hu));
            }
        }

        f32x4 acc[8];
        #pragma unroll
        for (int ct = 0; ct < 8; ++ct) { f32x4 zz = {0.f, 0.f, 0.f, 0.f}; acc[ct] = zz; }

        #pragma unroll
        for (int ct = 0; ct < 8; ++ct) {
            #pragma unroll
            for (int ks = 0; ks < 4; ++ks) {
                const bf16x8 bh = *(const bf16x8*)(sWh + ((ks * 8 + ct) * 64 + l) * 8);
                const bf16x8 bl = *(const bf16x8*)(sWl + ((ks * 8 + ct) * 64 + l) * 8);
                acc[ct] = __builtin_amdgcn_mfma_f32_16x16x32_bf16(ah[ks], bh, acc[ct], 0, 0, 0);
                acc[ct] = __builtin_amdgcn_mfma_f32_16x16x32_bf16(ah[ks], bl, acc[ct], 0, 0, 0);
                acc[ct] = __builtin_amdgcn_mfma_f32_16x16x32_bf16(al[ks], bh, acc[ct], 0, 0, 0);
            }
        }

        #pragma unroll
        for (int j = 0; j < 4; ++j) {
            int m = row0 + w * 16 + lk * 4 + j;
            if (m < nrows) {
                #pragma unroll
                for (int ct = 0; ct < 8; ++ct)
                    outp[(size_t)m * 128 + ct * 16 + lr] = bf16_of(acc[ct][j]);
            }
        }
    }
}

// ===== shared agg helper pattern (ILP-4): 4 lanes of a row load 4 records at once,
// shfl-broadcast within the 16-stride lane group, then 4 independent row gathers. =====

// ================= FUSED agg + GEMM: out = bf16( relu(bias + norm-agg(raw)) @ W ) ======
__global__ __launch_bounds__(512) void k_fused_agg_gemm(
    const unsigned short* __restrict__ raw, const float* __restrict__ dinv,
    const int* __restrict__ off, const int4* __restrict__ csr_pack,
    const float* __restrict__ bias,
    const unsigned short* __restrict__ Whf, const unsigned short* __restrict__ Wlf,
    unsigned short* __restrict__ outp, int nrows)
{
    __shared__ __align__(16) unsigned short sWh[16384];
    __shared__ __align__(16) unsigned short sWl[16384];
    const int t = threadIdx.x;

    // issue weight staging first; agg gathers below overlap its latency
    #pragma unroll
    for (int i = 0; i < 4; ++i) {
        ((float4*)sWh)[t + 512 * i] = ((const float4*)Whf)[t + 512 * i];
        ((float4*)sWl)[t + 512 * i] = ((const float4*)Wlf)[t + 512 * i];
    }

    const int w = t >> 6, l = t & 63;
    const int lr = l & 15, lk = l >> 4;
    const int row0 = blockIdx.x * 128;
    int arow = row0 + w * 16 + lr;
    if (arow >= nrows) arow = nrows - 1;

    const unsigned short* self = raw + (size_t)arow * 128 + lk * 8;
    const float* brow = bias + lk * 8;
    float di = dinv[arow];
    float w0 = di * di;

    float facc[4][8];
    #pragma unroll
    for (int ks = 0; ks < 4; ++ks) {
        bf16x8 v = *(const bf16x8*)(self + ks * 32);
        float4 b0 = *(const float4*)(brow + ks * 32);
        float4 b1v = *(const float4*)(brow + ks * 32 + 4);
        float bb[8] = {b0.x, b0.y, b0.z, b0.w, b1v.x, b1v.y, b1v.z, b1v.w};
        #pragma unroll
        for (int e = 0; e < 8; ++e)
            facc[ks][e] = bb[e] + w0 * f32_of((unsigned short)v[e]);
    }

    const int beg = off[arow], end = off[arow + 1];
    for (int j = beg; j < end; j += 4) {
        int4 p = make_int4(0, 0, 0, 0);
        if (j + lk < end) p = csr_pack[j + lk];     // 4 records, one per lane
        #pragma unroll
        for (int k = 0; k < 4; ++k) {
            if (j + k < end) {                       // row-uniform predicate
                int si = __shfl(p.x, lr + 16 * k, 64);
                float wg = __int_as_float(__shfl(p.z, lr + 16 * k, 64));
                const unsigned short* nrow = raw + (size_t)si * 128 + lk * 8;
                #pragma unroll
                for (int ks = 0; ks < 4; ++ks) {
                    bf16x8 u = *(const bf16x8*)(nrow + ks * 32);
                    #pragma unroll
                    for (int e = 0; e < 8; ++e)
                        facc[ks][e] += wg * f32_of((unsigned short)u[e]);
                }
            }
        }
    }

    bf16x8 ah[4];
    #pragma unroll
    for (int ks = 0; ks < 4; ++ks)
        #pragma unroll
        for (int e = 0; e < 8; ++e)
            ah[ks][e] = (short)bf16_of(fmaxf(facc[ks][e], 0.f));

    __syncthreads();                                 // weights staged

    f32x4 acc[8];
    #pragma unroll
    for (int ct = 0; ct < 8; ++ct) { f32x4 zz = {0.f, 0.f, 0.f, 0.f}; acc[ct] = zz; }
    #pragma unroll
    for (int ct = 0; ct < 8; ++ct) {
        #pragma unroll
        for (int ks = 0; ks < 4; ++ks) {
            const bf16x8 bh = *(const bf16x8*)(sWh + ((ks * 8 + ct) * 64 + l) * 8);
            const bf16x8 bl = *(const bf16x8*)(sWl + ((ks * 8 + ct) * 64 + l) * 8);
            acc[ct] = __builtin_amdgcn_mfma_f32_16x16x32_bf16(ah[ks], bh, acc[ct], 0, 0, 0);
            acc[ct] = __builtin_amdgcn_mfma_f32_16x16x32_bf16(ah[ks], bl, acc[ct], 0, 0, 0);
        }
    }

    #pragma unroll
    for (int j = 0; j < 4; ++j) {
        int m = row0 + w * 16 + lk * 4 + j;
        if (m < nrows) {
            #pragma unroll
            for (int ct = 0; ct < 8; ++ct)
                outp[(size_t)m * 128 + ct * 16 + lr] = bf16_of(acc[ct][j]);
        }
    }
}

// ================= FUSED agg + P/Q GEMMs: z=relu(bias+agg); P=z@Wa + bm1; Q=z@Wb =======
__global__ __launch_bounds__(512) void k_fused_agg_pq(
    const unsigned short* __restrict__ raw, const float* __restrict__ dinv,
    const int* __restrict__ off, const int4* __restrict__ csr_pack,
    const float* __restrict__ bias, const float* __restrict__ bm1,
    const unsigned short* __restrict__ Wh0, const unsigned short* __restrict__ Wl0,
    const unsigned short* __restrict__ Wh1, const unsigned short* __restrict__ Wl1,
    unsigned short* __restrict__ P, unsigned short* __restrict__ Q, int nrows)
{
    __shared__ __align__(16) unsigned short sWh[16384];
    __shared__ __align__(16) unsigned short sWl[16384];
    const int t = threadIdx.x;

    #pragma unroll
    for (int i = 0; i < 4; ++i) {
        ((float4*)sWh)[t + 512 * i] = ((const float4*)Wh0)[t + 512 * i];
        ((float4*)sWl)[t + 512 * i] = ((const float4*)Wl0)[t + 512 * i];
    }

    const int w = t >> 6, l = t & 63;
    const int lr = l & 15, lk = l >> 4;
    const int row0 = blockIdx.x * 128;
    int arow = row0 + w * 16 + lr;
    if (arow >= nrows) arow = nrows - 1;

    const unsigned short* self = raw + (size_t)arow * 128 + lk * 8;
    const float* brow = bias + lk * 8;
    float di = dinv[arow];
    float w0 = di * di;

    float facc[4][8];
    #pragma unroll
    for (int ks = 0; ks < 4; ++ks) {
        bf16x8 v = *(const bf16x8*)(self + ks * 32);
        float4 b0 = *(const float4*)(brow + ks * 32);
        float4 b1v = *(const float4*)(brow + ks * 32 + 4);
        float bb[8] = {b0.x, b0.y, b0.z, b0.w, b1v.x, b1v.y, b1v.z, b1v.w};
        #pragma unroll
        for (int e = 0; e < 8; ++e)
            facc[ks][e] = bb[e] + w0 * f32_of((unsigned short)v[e]);
    }

    const int beg = off[arow], end = off[arow + 1];
    for (int j = beg; j < end; j += 4) {
        int4 p = make_int4(0, 0, 0, 0);
        if (j + lk < end) p = csr_pack[j + lk];
        #pragma unroll
        for (int k = 0; k < 4; ++k) {
            if (j + k < end) {
                int si = __shfl(p.x, lr + 16 * k, 64);
                float wg = __int_as_float(__shfl(p.z, lr + 16 * k, 64));
                const unsigned short* nrow = raw + (size_t)si * 128 + lk * 8;
                #pragma unroll
                for (int ks = 0; ks < 4; ++ks) {
                    bf16x8 u = *(const bf16x8*)(nrow + ks * 32);
                    #pragma unroll
                    for (int e = 0; e < 8; ++e)
                        facc[ks][e] += wg * f32_of((unsigned short)u[e]);
                }
            }
        }
    }

    bf16x8 ah[4];
    #pragma unroll
    for (int ks = 0; ks < 4; ++ks)
        #pragma unroll
        for (int e = 0; e < 8; ++e)
            ah[ks][e] = (short)bf16_of(fmaxf(facc[ks][e], 0.f));

    // bm1 folded into P: bmv[ct] = bm1[ct*16+lr]
    float bmv[8];
    #pragma unroll
    for (int ct = 0; ct < 8; ++ct) bmv[ct] = bm1[ct * 16 + lr];

    __syncthreads();                                 // W0 staged

    {
        f32x4 acc[8];
        #pragma unroll
        for (int ct = 0; ct < 8; ++ct) { f32x4 zz = {0.f, 0.f, 0.f, 0.f}; acc[ct] = zz; }
        #pragma unroll
        for (int ct = 0; ct < 8; ++ct) {
            #pragma unroll
            for (int ks = 0; ks < 4; ++ks) {
                const bf16x8 bh = *(const bf16x8*)(sWh + ((ks * 8 + ct) * 64 + l) * 8);
                const bf16x8 bl = *(const bf16x8*)(sWl + ((ks * 8 + ct) * 64 + l) * 8);
                acc[ct] = __builtin_amdgcn_mfma_f32_16x16x32_bf16(ah[ks], bh, acc[ct], 0, 0, 0);
                acc[ct] = __builtin_amdgcn_mfma_f32_16x16x32_bf16(ah[ks], bl, acc[ct], 0, 0, 0);
            }
        }
        #pragma unroll
        for (int j = 0; j < 4; ++j) {
            int m = row0 + w * 16 + lk * 4 + j;
            if (m < nrows) {
                #pragma unroll
                for (int ct = 0; ct < 8; ++ct)
                    P[(size_t)m * 128 + ct * 16 + lr] = bf16_of(acc[ct][j] + bmv[ct]);
            }
        }
    }

    __syncthreads();                                 // all reads of W0 done
    #pragma unroll
    for (int i = 0; i < 4; ++i) {
        ((float4*)sWh)[t + 512 * i] = ((const float4*)Wh1)[t + 512 * i];
        ((float4*)sWl)[t + 512 * i] = ((const float4*)Wl1)[t + 512 * i];
    }
    __syncthreads();                                 // W1 staged

    {
        f32x4 acc[8];
        #pragma unroll
        for (int ct = 0; ct < 8; ++ct) { f32x4 zz = {0.f, 0.f, 0.f, 0.f}; acc[ct] = zz; }
        #pragma unroll
        for (int ct = 0; ct < 8; ++ct) {
            #pragma unroll
            for (int ks = 0; ks < 4; ++ks) {
                const bf16x8 bh = *(const bf16x8*)(sWh + ((ks * 8 + ct) * 64 + l) * 8);
                const bf16x8 bl = *(const bf16x8*)(sWl + ((ks * 8 + ct) * 64 + l) * 8);
                acc[ct] = __builtin_amdgcn_mfma_f32_16x16x32_bf16(ah[ks], bh, acc[ct], 0, 0, 0);
                acc[ct] = __builtin_amdgcn_mfma_f32_16x16x32_bf16(ah[ks], bl, acc[ct], 0, 0, 0);
            }
        }
        #pragma unroll
        for (int j = 0; j < 4; ++j) {
            int m = row0 + w * 16 + lk * 4 + j;
            if (m < nrows) {
                #pragma unroll
                for (int ct = 0; ct < 8; ++ct)
                    Q[(size_t)m * 128 + ct * 16 + lr] = bf16_of(acc[ct][j]);
            }
        }
    }
}

// ================= fused edge MLP (MFMA 2-term, CSR order, phase-split weights) ========
// bm1 already folded into P -> z1 = relu(P[s] + Q[d]).
__global__ __launch_bounds__(512) void k_edge_mlp_mfma(
    const int4* __restrict__ csr_pack,
    const unsigned short* __restrict__ P, const unsigned short* __restrict__ Q,
    const unsigned short* __restrict__ Whf, const unsigned short* __restrict__ Wlf,
    const float* __restrict__ bm2,
    const float* __restrict__ Wm3, const float* __restrict__ bm3,
    float* __restrict__ outp)
{
    __shared__ __align__(16) unsigned short sW[16384];   // 32 KB: [0,8192)=h, [8192,16384)=l
    __shared__ int sIdx[3][128];

    const int t = threadIdx.x;
    const int e0 = blockIdx.x * 128;

    if (t < 128) {
        int4 p = csr_pack[e0 + t];
        sIdx[0][t] = p.x;
        sIdx[1][t] = p.y;
        sIdx[2][t] = p.w;
    }
    __syncthreads();

    const int w = t >> 6;          // wave id 0..7: rows w*16 .. w*16+15
    const int l = t & 63;
    const int lr = l & 15;         // A row within tile / D col
    const int lk = l >> 4;         // k-block
    const int row = w * 16 + lr;
    const int s = sIdx[0][row], d = sIdx[1][row];
    const unsigned short* prow = P + (size_t)s * 128 + lk * 8;
    const unsigned short* qrow = Q + (size_t)d * 128 + lk * 8;

    bf16x8 ah[4];
    #pragma unroll
    for (int ks = 0; ks < 4; ++ks) {
        bf16x8 pv = *(const bf16x8*)(prow + ks * 32);
        bf16x8 qv = *(const bf16x8*)(qrow + ks * 32);
        #pragma unroll
        for (int e = 0; e < 8; ++e) {
            float zv = fmaxf(f32_of((unsigned short)pv[e]) +
                             f32_of((unsigned short)qv[e]), 0.f);
            ah[ks][e] = (short)bf16_of(zv);
        }
    }

    f32x4 acc[8];
    #pragma unroll
    for (int ct = 0; ct < 8; ++ct) {
        float bv = bm2[ct * 16 + lr];
        f32x4 a = {bv, bv, bv, bv};
        acc[ct] = a;
    }

    // two phases: ct in [0,4) then [4,8); each stages 16 h-tiles + 16 l-tiles (32 KB)
    #pragma unroll
    for (int ph = 0; ph < 2; ++ph) {
        if (ph) __syncthreads();
        #pragma unroll
        for (int i = 0; i < 2; ++i) {
            int li = t + 512 * i;
            int tl = li >> 6, off = li & 63;
            int gtile = (tl >> 2) * 8 + ph * 4 + (tl & 3);
            ((float4*)sW)[li] = ((const float4*)Whf)[gtile * 64 + off];
            ((float4*)(sW + 8192))[li] = ((const float4*)Wlf)[gtile * 64 + off];
        }
        __syncthreads();
        #pragma unroll
        for (int ct4 = 0; ct4 < 4; ++ct4) {
            int ct = ph * 4 + ct4;
            #pragma unroll
            for (int ks = 0; ks < 4; ++ks) {
                int tl = ks * 4 + ct4;
                const bf16x8 bh = *(const bf16x8*)(sW + (tl * 64 + l) * 8);
                const bf16x8 bl = *(const bf16x8*)(sW + 8192 + (tl * 64 + l) * 8);
                acc[ct] = __builtin_amdgcn_mfma_f32_16x16x32_bf16(ah[ks], bh, acc[ct], 0, 0, 0);
                acc[ct] = __builtin_amdgcn_mfma_f32_16x16x32_bf16(ah[ks], bl, acc[ct], 0, 0, 0);
            }
        }
    }

    float w3v[8];
    #pragma unroll
    for (int ct = 0; ct < 8; ++ct) w3v[ct] = Wm3[ct * 16 + lr];
    float b3 = bm3[0];
    #pragma unroll
    for (int j = 0; j < 4; ++j) {
        float pj = 0.f;
        #pragma unroll
        for (int ct = 0; ct < 8; ++ct) pj += fmaxf(acc[ct][j], 0.f) * w3v[ct];
        pj += __shfl_xor(pj, 1);
        pj += __shfl_xor(pj, 2);
        pj += __shfl_xor(pj, 4);
        pj += __shfl_xor(pj, 8);
        if (lr == 0)
            outp[sIdx[2][w * 16 + lk * 4 + j]] = 1.f / (1.f + expf(-(pj + b3)));
    }
}

// ================= launch =================
extern "C" void kernel_launch(void* const* d_in, const int* in_sizes, int n_in,
                              void* d_out, int out_size, void* d_ws, size_t ws_size,
                              hipStream_t stream) {
    const float* x   = (const float*)d_in[0];
    const int*   ei  = (const int*)d_in[1];
    const float* W1  = (const float*)d_in[2];
    const float* b1  = (const float*)d_in[3];
    const float* W2  = (const float*)d_in[4];
    const float* b2  = (const float*)d_in[5];
    const float* Wm1 = (const float*)d_in[6];
    const float* bm1 = (const float*)d_in[7];
    const float* Wm2 = (const float*)d_in[8];
    const float* bm2 = (const float*)d_in[9];
    const float* Wm3 = (const float*)d_in[10];
    const float* bm3 = (const float*)d_in[11];
    const int* esrc = ei;
    const int* edst = ei + N_EDGES;
    float* outp = (float*)d_out;

    // workspace layout
    float* ws = (float*)d_ws;
    float* dinv = ws;                                   // 100096 floats
    float* A = ws + 100096;                             // N*128 f32 region
    float* B = A + (size_t)N_NODES * 128;               // N*128 f32 region
    int* deg     = (int*)(B + (size_t)N_NODES * 128);   // N
    int* off     = deg + N_NODES;                       // N+1
    int* cur     = off + N_NODES + 1;                   // N
    int* bsum    = cur + N_NODES;                       // 512
    // align to 16 B for int4
    size_t ioff = (size_t)(bsum + 512 - (int*)d_ws);
    ioff = (ioff + 3) & ~(size_t)3;
    int4* csr_pack = (int4*)((int*)d_ws + ioff);        // E int4
    unsigned short* frag = (unsigned short*)(csr_pack + N_EDGES);
    unsigned short* W1h   = frag;                 unsigned short* W1l   = frag + 16384;
    unsigned short* W2h   = frag + 2 * 16384;     unsigned short* W2l   = frag + 3 * 16384;
    unsigned short* Wm1ah = frag + 4 * 16384;     unsigned short* Wm1al = frag + 5 * 16384;
    unsigned short* Wm1bh = frag + 6 * 16384;     unsigned short* Wm1bl = frag + 7 * 16384;
    unsigned short* Wm2h  = frag + 8 * 16384;     unsigned short* Wm2l  = frag + 9 * 16384;
    // bf16 views: Ab = layer-1 product (region A); Cb = layer-2 product (region B);
    // Pb overwrites Ab (dead once fused_pq reads only Cb); Qb after Pb in region A.
    unsigned short* Ab = (unsigned short*)A;
    unsigned short* Cb = (unsigned short*)B;
    unsigned short* Pb = (unsigned short*)A;
    unsigned short* Qb = (unsigned short*)A + (size_t)N_NODES * 128;

    const int nb = (N_NODES + 255) / 256;               // 391 scan blocks

    // ---- CSR build + W splits ----
    k_zero_deg<<<nb, 256, 0, stream>>>(deg);
    k_hist<<<(N_EDGES + 255) / 256, 256, 0, stream>>>(edst, deg);
    k_scan1<<<nb, 256, 0, stream>>>(deg, off, bsum, dinv, N_NODES);
    k_scan2<<<1, 512, 0, stream>>>(bsum, nb);
    k_scan3<<<(N_NODES + 256) / 256, 256, 0, stream>>>(off, bsum, cur, N_NODES);
    k_scatter<<<(N_EDGES + 255) / 256, 256, 0, stream>>>(esrc, edst, dinv, cur, csr_pack);

    SplitArgs sa;
    sa.W[0] = W1;  sa.Wh[0] = W1h;   sa.Wl[0] = W1l;
    sa.W[1] = W2;  sa.Wh[1] = W2h;   sa.Wl[1] = W2l;
    sa.W[2] = Wm1; sa.Wh[2] = Wm1ah; sa.Wl[2] = Wm1al;
    sa.W[3] = Wm1 + 128 * 128; sa.Wh[3] = Wm1bh; sa.Wl[3] = Wm1bl;
    sa.W[4] = Wm2; sa.Wh[4] = Wm2h;  sa.Wl[4] = Wm2l;
    k_split_all<<<5 * 64, 256, 0, stream>>>(sa);

    const int RT = 4;
    const int gemm_blocks = (N_NODES + 128 * RT - 1) / (128 * RT);   // 196
    const int node_tiles = (N_NODES + 127) / 128;                    // 782

    // ---- layer 1 product: Ab = bf16(x @ W1) ----
    k_gemm_mfma_f32<<<gemm_blocks, 512, 0, stream>>>(x, W1h, W1l, Ab, N_NODES, RT);

    // ---- fused: Cb = bf16( relu(b1 + agg(Ab)) @ W2 ) ----
    k_fused_agg_gemm<<<node_tiles, 512, 0, stream>>>(Ab, dinv, off, csr_pack, b1,
                                                     W2h, W2l, Cb, N_NODES);

    // ---- fused: z2 = relu(b2 + agg(Cb)); Pb = z2@Wm1_top + bm1; Qb = z2@Wm1_bot ----
    k_fused_agg_pq<<<node_tiles, 512, 0, stream>>>(Cb, dinv, off, csr_pack, b2, bm1,
                                                   Wm1ah, Wm1al, Wm1bh, Wm1bl,
                                                   Pb, Qb, N_NODES);

    // ---- fused edge MLP on MFMA, CSR order, phase-split weight LDS ----
    k_edge_mlp_mfma<<<N_EDGES / 128, 512, 0, stream>>>(csr_pack, Pb, Qb,
                                                       Wm2h, Wm2l, bm2, Wm3, bm3, outp);
}